// Round 1
// baseline (262.560 us; speedup 1.0000x reference)
//
#include <hip/hip_runtime.h>
#include <math.h>

#define NQ   10
#define NST  1024
#define TPB  256
#define TWO_PI_F 6.283185307179586f

// ---------- helpers ----------

__device__ __forceinline__ int ins0(int p, int bp) {
    // insert a 0 bit at position bp of p
    return ((p >> bp) << (bp + 1)) | (p & ((1 << bp) - 1));
}

// ry: [[c,-s],[s,c]] (real)
__device__ __forceinline__ void g_ry(float* re, float* im, float c, float s, int w) {
    const int bp = 9 - w, mk = 1 << bp;
    const int t = threadIdx.x;
#pragma unroll
    for (int rep = 0; rep < 2; ++rep) {
        int p = t + rep * TPB;
        int s0 = ins0(p, bp), s1 = s0 | mk;
        float r0 = re[s0], i0 = im[s0], r1 = re[s1], i1 = im[s1];
        re[s0] = c * r0 - s * r1;  im[s0] = c * i0 - s * i1;
        re[s1] = s * r0 + c * r1;  im[s1] = s * i0 + c * i1;
    }
    __syncthreads();
}

// rx: [[c,-is],[-is,c]]
__device__ __forceinline__ void g_rx(float* re, float* im, float c, float s, int w) {
    const int bp = 9 - w, mk = 1 << bp;
    const int t = threadIdx.x;
#pragma unroll
    for (int rep = 0; rep < 2; ++rep) {
        int p = t + rep * TPB;
        int s0 = ins0(p, bp), s1 = s0 | mk;
        float r0 = re[s0], i0 = im[s0], r1 = re[s1], i1 = im[s1];
        re[s0] = c * r0 + s * i1;  im[s0] = c * i0 - s * r1;
        re[s1] = s * i0 + c * r1;  im[s1] = -s * r0 + c * i1;
    }
    __syncthreads();
}

// rz: diag(e^{-it}, e^{+it}), t = theta/2 (c=cos t, s=sin t)
__device__ __forceinline__ void g_rz(float* re, float* im, float c, float s, int w) {
    const int bp = 9 - w;
    const int t = threadIdx.x;
#pragma unroll
    for (int rep = 0; rep < 4; ++rep) {
        int st = t + rep * TPB;
        float sp = ((st >> bp) & 1) ? s : -s;   // sin(phase)
        float r = re[st], i_ = im[st];
        re[st] = r * c - i_ * sp;
        im[st] = i_ * c + r * sp;
    }
    __syncthreads();
}

// crz: states with ctrl=1 get phase e^{-it} (tgt=0) / e^{+it} (tgt=1)
__device__ __forceinline__ void g_crz(float* re, float* im, float c, float s, int ctrl, int tgt) {
    const int bc = 9 - ctrl, bt = 9 - tgt;
    const int t = threadIdx.x;
#pragma unroll
    for (int rep = 0; rep < 4; ++rep) {
        int st = t + rep * TPB;
        if ((st >> bc) & 1) {
            float sp = ((st >> bt) & 1) ? s : -s;
            float r = re[st], i_ = im[st];
            re[st] = r * c - i_ * sp;
            im[st] = i_ * c + r * sp;
        }
    }
    __syncthreads();
}

// ising_xx: out[s] = c*psi[s] - i*s*psi[s ^ (ma|mb)]
__device__ __forceinline__ void g_xx(float* re, float* im, float c, float s, int a, int b) {
    const int bpa = 9 - a, bpb = 9 - b;
    const int m = (1 << bpa) | (1 << bpb);
    const int hb = (bpa > bpb) ? bpa : bpb;
    const int t = threadIdx.x;
#pragma unroll
    for (int rep = 0; rep < 2; ++rep) {
        int p = t + rep * TPB;
        int s0 = ins0(p, hb), s1 = s0 ^ m;
        float r0 = re[s0], i0 = im[s0], r1 = re[s1], i1 = im[s1];
        re[s0] = c * r0 + s * i1;  im[s0] = c * i0 - s * r1;
        re[s1] = c * r1 + s * i0;  im[s1] = c * i1 - s * r0;
    }
    __syncthreads();
}

// ising_yy: out[s] = c*psi[s] - i*s*sigma(s)*psi[s^m], sigma=-1 if bits equal
__device__ __forceinline__ void g_yy(float* re, float* im, float c, float s, int a, int b) {
    const int bpa = 9 - a, bpb = 9 - b;
    const int m = (1 << bpa) | (1 << bpb);
    const int hb = (bpa > bpb) ? bpa : bpb;
    const int lb = (bpa > bpb) ? bpb : bpa;
    const int t = threadIdx.x;
#pragma unroll
    for (int rep = 0; rep < 2; ++rep) {
        int p = t + rep * TPB;
        int s0 = ins0(p, hb), s1 = s0 ^ m;
        // s0 has hb-bit == 0; bits equal iff lb-bit == 0 -> sigma = -1
        float sg = ((s0 >> lb) & 1) ? s : -s;   // sigma * s
        float r0 = re[s0], i0 = im[s0], r1 = re[s1], i1 = im[s1];
        re[s0] = c * r0 + sg * i1;  im[s0] = c * i0 - sg * r1;
        re[s1] = c * r1 + sg * i0;  im[s1] = c * i1 - sg * r0;
    }
    __syncthreads();
}

// measurement: m[0..9]=X, m[10..19]=Y, m[20..29]=Z
__device__ void measure_all(const float* re, const float* im, float* m, float* red) {
    const int t = threadIdx.x;
    for (int w = 0; w < NQ; ++w) {
        const int bp = 9 - w, mk = 1 << bp;
        float ar = 0.f, ai = 0.f, az = 0.f;
#pragma unroll
        for (int rep = 0; rep < 2; ++rep) {
            int p = t + rep * TPB;
            int s0 = ins0(p, bp), s1 = s0 | mk;
            float r0 = re[s0], i0 = im[s0], r1 = re[s1], i1 = im[s1];
            ar += r0 * r1 + i0 * i1;
            ai += r0 * i1 - i0 * r1;
            az += (r0 * r0 + i0 * i0) - (r1 * r1 + i1 * i1);
        }
#pragma unroll
        for (int off = 32; off > 0; off >>= 1) {
            ar += __shfl_down(ar, off);
            ai += __shfl_down(ai, off);
            az += __shfl_down(az, off);
        }
        int lane = t & 63, wv = t >> 6;
        if (lane == 0) { red[wv] = ar; red[4 + wv] = ai; red[8 + wv] = az; }
        __syncthreads();
        if (t == 0) {
            float A = 0.f, Bv = 0.f, C = 0.f;
#pragma unroll
            for (int i = 0; i < 4; ++i) { A += red[i]; Bv += red[4 + i]; C += red[8 + i]; }
            m[w] = 2.f * A; m[10 + w] = 2.f * Bv; m[20 + w] = C;
        }
        __syncthreads();
    }
}

__device__ __forceinline__ void init_psi(float* re, float* im) {
    const int t = threadIdx.x;
    for (int s = t; s < NST; s += TPB) { re[s] = 0.f; im[s] = 0.f; }
    if (t == 0) re[0] = 1.f;
    __syncthreads();
}

// ---------- batch-element SSM sim ----------

__device__ void sim_batch(int b, const float* x, const float* Wp, const float* bp_,
                          const float* qb, const float* bpar, const float* cpar, const float* dtpar,
                          float* re, float* im, float* xrow,
                          float* qc, float* qs, float* sc, float* ss,
                          float* m1, float* red) {
    const int t = threadIdx.x;
    xrow[t] = x[b * 256 + t];
    for (int s = t; s < NST; s += TPB) { re[s] = 0.f; im[s] = 0.f; }
    if (t == 0) re[0] = 1.f;
    __syncthreads();
    if (t < 80) {
        float d = bp_[t];
        const float* wr = Wp + t * 256;
        for (int k = 0; k < 256; ++k) d += xrow[k] * wr[k];
        float ang = TWO_PI_F / (1.f + expf(-d)) + qb[t];   // sigmoid*2pi + base
        sincosf(0.5f * ang, &qs[t], &qc[t]);
    } else if (t < 110) {
        int i = t - 80;
        float th = (i < 10) ? bpar[i] : (i < 20 ? cpar[i - 10] : dtpar[i - 20]);
        sincosf(0.5f * th, &ss[i], &sc[i]);
    }
    __syncthreads();
    for (int L = 0; L < 2; ++L) {
        const int q = L * 40;
        for (int i = 0; i < NQ; ++i) g_ry(re, im, qc[q + i], qs[q + i], i);
        for (int i = 0; i < NQ; ++i) g_xx(re, im, qc[q + 10 + i], qs[q + 10 + i], i, (i + 1 == NQ) ? 0 : i + 1);
        for (int i = 0; i < NQ; ++i) g_ry(re, im, sc[i], ss[i], i);
        for (int i = 0; i < NQ; ++i) g_ry(re, im, qc[q + 20 + i], qs[q + 20 + i], i);
        for (int i = 0; i < NQ; ++i) g_yy(re, im, qc[q + 30 + i], qs[q + 30 + i], i, (i + 1 == NQ) ? 0 : i + 1);
        for (int i = 0; i < NQ; ++i) g_rz(re, im, sc[10 + i], ss[10 + i], i);
        for (int i = 0; i < NQ; ++i) g_rx(re, im, sc[20 + i], ss[20 + i], i);
    }
    measure_all(re, im, m1, red);
}

// ---------- branch circuits (batch-independent) -> u[0..29], c0 at u[30] ----------

__device__ void sim_branches(const float* gate_base, const float* skip_base,
                             const float* W1, const float* b1,
                             const float* W2, const float* b2,
                             const float* W3, const float* b3,
                             const float* w1p, const float* w2p, const float* w3p,
                             const float* Wout, const float* bout,
                             float* re, float* im, float* m2, float* m3, float* red,
                             float* ws_u) {
    const int t = threadIdx.x;
    // gating circuit
    init_psi(re, im);
    for (int L = 0; L < 2; ++L) {
        const int g0 = L * 30;
        for (int i = 0; i < NQ; ++i)     { float s, c; sincosf(0.5f * gate_base[g0 + i], &s, &c); g_rx(re, im, c, s, i); }
        for (int i = 0; i < NQ - 1; ++i) { float s, c; sincosf(0.5f * gate_base[g0 + 10 + i], &s, &c); g_crz(re, im, c, s, i, i + 1); }
        for (int i = 0; i < NQ; ++i)     { float s, c; sincosf(0.5f * gate_base[g0 + 19 + i], &s, &c); g_ry(re, im, c, s, i); }
        { float s, c; sincosf(0.5f * gate_base[g0 + 29], &s, &c); g_crz(re, im, c, s, NQ - 1, 0); }
    }
    measure_all(re, im, m2, red);
    // skip circuit
    init_psi(re, im);
    for (int i = 0; i < NQ; ++i) { float s, c; sincosf(0.5f * skip_base[i], &s, &c);      g_rx(re, im, c, s, i); }
    for (int i = 0; i < NQ; ++i) { float s, c; sincosf(0.5f * skip_base[10 + i], &s, &c); g_ry(re, im, c, s, i); }
    for (int i = 0; i < NQ; ++i) { float s, c; sincosf(0.5f * skip_base[20 + i], &s, &c); g_rz(re, im, c, s, i); }
    measure_all(re, im, m3, red);
    // fold the linear tail: u[j] = w1 * sum_k Wout[k] W1[k,j];
    // c0 = b_out + sum_k Wout[k]*(w1*b1[k] + w2*y2[k] + w3*y3[k])
    if (t < 30) {
        float u = 0.f;
        for (int k = 0; k < 30; ++k) u += Wout[k] * W1[k * 30 + t];
        ws_u[t] = w1p[0] * u;
    }
    if (t == 0) {
        float w1 = w1p[0], w2 = w2p[0], w3 = w3p[0];
        float c0 = bout[0];
        for (int k = 0; k < 30; ++k) {
            float y2 = b2[k], y3 = b3[k];
            for (int j = 0; j < 30; ++j) { y2 += m2[j] * W2[k * 30 + j]; y3 += m3[j] * W3[k * 30 + j]; }
            c0 += Wout[k] * (w1 * b1[k] + w2 * y2 + w3 * y3);
        }
        ws_u[30] = c0;
    }
}

// ---------- kernels ----------

// fused: blocks 0..B-1 write m1 rows (stride 32) to ws; block B writes u/c0 at ws+B*32
__global__ void __launch_bounds__(TPB) k_fused(
    const float* x, const float* Wp, const float* bp_, const float* qb,
    const float* bpar, const float* cpar, const float* dtpar,
    const float* gate_base, const float* skip_base,
    const float* W1, const float* b1, const float* W2, const float* b2,
    const float* W3, const float* b3, const float* w1p, const float* w2p, const float* w3p,
    const float* Wout, const float* bout,
    float* ws, int B) {
    __shared__ float re[NST], im[NST];
    __shared__ float xrow[256], qc[80], qs[80], sc[30], ss[30], mA[30], mB2[30], red[12];
    const int b = blockIdx.x;
    if (b < B) {
        sim_batch(b, x, Wp, bp_, qb, bpar, cpar, dtpar, re, im, xrow, qc, qs, sc, ss, mA, red);
        if (threadIdx.x < 30) ws[b * 32 + threadIdx.x] = mA[threadIdx.x];
    } else {
        sim_branches(gate_base, skip_base, W1, b1, W2, b2, W3, b3, w1p, w2p, w3p,
                     Wout, bout, re, im, mA, mB2, red, ws + (size_t)B * 32);
    }
}

__global__ void k_out(const float* ws, float* out, int B) {
    int i = blockIdx.x * blockDim.x + threadIdx.x;
    if (i < B) {
        const float* u = ws + (size_t)B * 32;
        const float* m = ws + (size_t)i * 32;
        float o = u[30];
#pragma unroll
        for (int j = 0; j < 30; ++j) o += m[j] * u[j];
        out[i] = o;
    }
}

// fallback serial path (tiny ws): branches first, then batch kernel reads u/c0
__global__ void __launch_bounds__(TPB) k_branches_only(
    const float* gate_base, const float* skip_base,
    const float* W1, const float* b1, const float* W2, const float* b2,
    const float* W3, const float* b3, const float* w1p, const float* w2p, const float* w3p,
    const float* Wout, const float* bout, float* ws_u) {
    __shared__ float re[NST], im[NST];
    __shared__ float mA[30], mB2[30], red[12];
    sim_branches(gate_base, skip_base, W1, b1, W2, b2, W3, b3, w1p, w2p, w3p,
                 Wout, bout, re, im, mA, mB2, red, ws_u);
}

__global__ void __launch_bounds__(TPB) k_serial(
    const float* x, const float* Wp, const float* bp_, const float* qb,
    const float* bpar, const float* cpar, const float* dtpar,
    const float* ws_u, float* out) {
    __shared__ float re[NST], im[NST];
    __shared__ float xrow[256], qc[80], qs[80], sc[30], ss[30], mA[30], red[12];
    const int b = blockIdx.x;
    sim_batch(b, x, Wp, bp_, qb, bpar, cpar, dtpar, re, im, xrow, qc, qs, sc, ss, mA, red);
    if (threadIdx.x == 0) {
        float o = ws_u[30];
        for (int j = 0; j < 30; ++j) o += mA[j] * ws_u[j];
        out[b] = o;
    }
}

extern "C" void kernel_launch(void* const* d_in, const int* in_sizes, int n_in,
                              void* d_out, int out_size, void* d_ws, size_t ws_size,
                              hipStream_t stream) {
    const float* x         = (const float*)d_in[0];
    const float* W_proj    = (const float*)d_in[1];
    const float* b_proj    = (const float*)d_in[2];
    const float* qlcu_base = (const float*)d_in[3];
    const float* gate_base = (const float*)d_in[4];
    const float* skip_base = (const float*)d_in[5];
    const float* b_params  = (const float*)d_in[6];
    const float* c_params  = (const float*)d_in[7];
    const float* dt_params = (const float*)d_in[8];
    const float* W1    = (const float*)d_in[9];
    const float* b1    = (const float*)d_in[10];
    const float* W2    = (const float*)d_in[11];
    const float* b2    = (const float*)d_in[12];
    const float* W3    = (const float*)d_in[13];
    const float* b3    = (const float*)d_in[14];
    const float* w1    = (const float*)d_in[15];
    const float* w2    = (const float*)d_in[16];
    const float* w3    = (const float*)d_in[17];
    const float* W_out = (const float*)d_in[18];
    const float* b_out = (const float*)d_in[19];
    float* out = (float*)d_out;
    float* ws  = (float*)d_ws;

    const int B = in_sizes[0] / 256;   // FEATURE_DIM = 256
    const size_t need = ((size_t)B * 32 + 32) * sizeof(float);

    if (ws_size >= need) {
        hipLaunchKernelGGL(k_fused, dim3(B + 1), dim3(TPB), 0, stream,
                           x, W_proj, b_proj, qlcu_base, b_params, c_params, dt_params,
                           gate_base, skip_base, W1, b1, W2, b2, W3, b3, w1, w2, w3,
                           W_out, b_out, ws, B);
        hipLaunchKernelGGL(k_out, dim3((B + 255) / 256), dim3(256), 0, stream, ws, out, B);
    } else {
        hipLaunchKernelGGL(k_branches_only, dim3(1), dim3(TPB), 0, stream,
                           gate_base, skip_base, W1, b1, W2, b2, W3, b3, w1, w2, w3,
                           W_out, b_out, ws);
        hipLaunchKernelGGL(k_serial, dim3(B), dim3(TPB), 0, stream,
                           x, W_proj, b_proj, qlcu_base, b_params, c_params, dt_params,
                           ws, out);
    }
}

// Round 2
// 152.104 us; speedup vs baseline: 1.7262x; 1.7262x over previous
//
#include <hip/hip_runtime.h>
#include <math.h>

#define NQ 10
#define TPB 256
#define TWO_PI_F 6.283185307179586f

// State layout: one wave (64 lanes) holds 1024 amplitudes.
// s = (lane << 4) | r,  r = 0..15 in registers re[16], im[16].
// Qubit w -> state bit (9-w).  w <= 5: lane bit (5-w).  w >= 6: local bit (9-w).
// All register indexing is compile-time (templates + full unroll).

#define ALLQ(OP) OP(0) OP(1) OP(2) OP(3) OP(4) OP(5) OP(6) OP(7) OP(8) OP(9)
#define ALLQ9(OP) OP(0) OP(1) OP(2) OP(3) OP(4) OP(5) OP(6) OP(7) OP(8)

// ---------------- gates ----------------

template<int W>
__device__ __forceinline__ void g_ry(float (&re)[16], float (&im)[16], float c, float s, int lane) {
    if constexpr (W <= 5) {
        constexpr int LM = 1 << (5 - W);
        const float ss = ((lane >> (5 - W)) & 1) ? s : -s;
#pragma unroll
        for (int r = 0; r < 16; ++r) {
            float pr = __shfl_xor(re[r], LM);
            float pi = __shfl_xor(im[r], LM);
            re[r] = fmaf(ss, pr, c * re[r]);
            im[r] = fmaf(ss, pi, c * im[r]);
        }
    } else {
        constexpr int MK = 1 << (9 - W);
#pragma unroll
        for (int r = 0; r < 16; ++r) {
            if ((r & MK) == 0) {
                const int r1 = r | MK;
                float r0 = re[r], i0 = im[r], r1v = re[r1], i1 = im[r1];
                re[r]  = fmaf(-s, r1v, c * r0);
                im[r]  = fmaf(-s, i1,  c * i0);
                re[r1] = fmaf( s, r0,  c * r1v);
                im[r1] = fmaf( s, i0,  c * i1);
            }
        }
    }
}

template<int W>
__device__ __forceinline__ void g_rx(float (&re)[16], float (&im)[16], float c, float s, int lane) {
    if constexpr (W <= 5) {
        constexpr int LM = 1 << (5 - W);
#pragma unroll
        for (int r = 0; r < 16; ++r) {
            float pr = __shfl_xor(re[r], LM);
            float pi = __shfl_xor(im[r], LM);
            re[r] = fmaf( s, pi, c * re[r]);
            im[r] = fmaf(-s, pr, c * im[r]);
        }
    } else {
        constexpr int MK = 1 << (9 - W);
#pragma unroll
        for (int r = 0; r < 16; ++r) {
            if ((r & MK) == 0) {
                const int r1 = r | MK;
                float r0 = re[r], i0 = im[r], r1v = re[r1], i1 = im[r1];
                re[r]  = fmaf( s, i1,  c * r0);
                im[r]  = fmaf(-s, r1v, c * i0);
                re[r1] = fmaf( s, i0,  c * r1v);
                im[r1] = fmaf(-s, r0,  c * i1);
            }
        }
    }
}

template<int W>
__device__ __forceinline__ void g_rz(float (&re)[16], float (&im)[16], float c, float s, int lane) {
    if constexpr (W <= 5) {
        const float sp = ((lane >> (5 - W)) & 1) ? s : -s;
#pragma unroll
        for (int r = 0; r < 16; ++r) {
            float rr = re[r], ii = im[r];
            re[r] = rr * c - ii * sp;
            im[r] = ii * c + rr * sp;
        }
    } else {
        constexpr int MK = 1 << (9 - W);
#pragma unroll
        for (int r = 0; r < 16; ++r) {
            const float sp = (r & MK) ? s : -s;
            float rr = re[r], ii = im[r];
            re[r] = rr * c - ii * sp;
            im[r] = ii * c + rr * sp;
        }
    }
}

template<int C, int T>
__device__ __forceinline__ void g_crz(float (&re)[16], float (&im)[16], float c, float s, int lane) {
#pragma unroll
    for (int r = 0; r < 16; ++r) {
        const int cb = (C <= 5) ? ((lane >> (5 - C)) & 1) : ((r >> (9 - C)) & 1);
        const int tb = (T <= 5) ? ((lane >> (5 - T)) & 1) : ((r >> (9 - T)) & 1);
        const float cc  = cb ? c : 1.f;
        const float sp2 = cb ? (tb ? s : -s) : 0.f;
        float rr = re[r], ii = im[r];
        re[r] = cc * rr - sp2 * ii;
        im[r] = cc * ii + sp2 * rr;
    }
}

// XX / YY:  out[s] = c*psi[s] + sg*i_part ... partner at s ^ m
template<int A, int Bq, bool YY>
__device__ __forceinline__ void g_xy(float (&re)[16], float (&im)[16], float c, float s, int lane) {
    constexpr int bpA = 9 - A, bpB = 9 - Bq;
    constexpr int LM   = ((bpA >= 4) ? (1 << (bpA - 4)) : 0) | ((bpB >= 4) ? (1 << (bpB - 4)) : 0);
    constexpr int LOCM = ((bpA < 4) ? (1 << bpA) : 0) | ((bpB < 4) ? (1 << bpB) : 0);
    float pr[16], pi[16];
#pragma unroll
    for (int r = 0; r < 16; ++r) {
        float vr = re[r ^ LOCM], vi = im[r ^ LOCM];
        if constexpr (LM != 0) { pr[r] = __shfl_xor(vr, LM); pi[r] = __shfl_xor(vi, LM); }
        else                   { pr[r] = vr; pi[r] = vi; }
    }
#pragma unroll
    for (int r = 0; r < 16; ++r) {
        float sg;
        if constexpr (YY) {
            const int bA = (A  <= 5) ? ((lane >> (5 - A )) & 1) : ((r >> (9 - A )) & 1);
            const int bB = (Bq <= 5) ? ((lane >> (5 - Bq)) & 1) : ((r >> (9 - Bq)) & 1);
            sg = (bA == bB) ? -s : s;
        } else sg = s;
        float rr = re[r], ii = im[r];
        re[r] = fmaf( sg, pi[r], c * rr);
        im[r] = fmaf(-sg, pr[r], c * ii);
    }
}

// measurement of qubit W: X, Y, Z broadcast to all lanes
template<int W>
__device__ __forceinline__ void meas_q(const float (&re)[16], const float (&im)[16], int lane,
                                       float& X, float& Y, float& Z) {
    float xa = 0.f, ya = 0.f, za = 0.f;
    if constexpr (W <= 5) {
        constexpr int LM = 1 << (5 - W);
        const float sg = ((lane >> (5 - W)) & 1) ? -1.f : 1.f;
#pragma unroll
        for (int r = 0; r < 16; ++r) {
            float pr = __shfl_xor(re[r], LM);
            float pi = __shfl_xor(im[r], LM);
            xa = fmaf(re[r], pr, xa); xa = fmaf(im[r], pi, xa);
            ya = fmaf(re[r], pi, ya); ya = fmaf(-im[r], pr, ya);
            za = fmaf(re[r], re[r], za); za = fmaf(im[r], im[r], za);
        }
        ya *= sg; za *= sg;
    } else {
        constexpr int MK = 1 << (9 - W);
#pragma unroll
        for (int r = 0; r < 16; ++r) {
            if ((r & MK) == 0) {
                const int r1 = r | MK;
                xa += 2.f * (re[r] * re[r1] + im[r] * im[r1]);
                ya += 2.f * (re[r] * im[r1] - im[r] * re[r1]);
                za += (re[r] * re[r] + im[r] * im[r]) - (re[r1] * re[r1] + im[r1] * im[r1]);
            }
        }
    }
#pragma unroll
    for (int off = 1; off < 64; off <<= 1) {
        xa += __shfl_xor(xa, off);
        ya += __shfl_xor(ya, off);
        za += __shfl_xor(za, off);
    }
    X = xa; Y = ya; Z = za;
}

__device__ __forceinline__ void init_state(float (&re)[16], float (&im)[16], int lane) {
#pragma unroll
    for (int r = 0; r < 16; ++r) { re[r] = 0.f; im[r] = 0.f; }
    if (lane == 0) re[0] = 1.f;
}

// ---------------- branch circuits (batch-independent), one wave ----------------

__device__ void branch_sim(const float* __restrict__ gb, const float* __restrict__ sp,
                           const float* __restrict__ W1, const float* __restrict__ b1,
                           const float* __restrict__ W2, const float* __restrict__ b2,
                           const float* __restrict__ W3, const float* __restrict__ b3,
                           const float* __restrict__ w1p, const float* __restrict__ w2p,
                           const float* __restrict__ w3p,
                           const float* __restrict__ Wout, const float* __restrict__ bout,
                           float* __restrict__ ws_u, int lane) {
    float re[16], im[16];
    const bool act = lane < 30;
    const int kk = act ? lane : 0;
    float y2 = 0.f, y3 = 0.f;

    // gating circuit
    init_state(re, im, lane);
    for (int L = 0; L < 2; ++L) {
        const int g0 = L * 30;
#define G_RX(i) { float s_, c_; sincosf(0.5f * gb[g0 + i], &s_, &c_); g_rx<i>(re, im, c_, s_, lane); }
        ALLQ(G_RX)
#undef G_RX
#define G_CRZ(i) { float s_, c_; sincosf(0.5f * gb[g0 + 10 + i], &s_, &c_); g_crz<i, i + 1>(re, im, c_, s_, lane); }
        ALLQ9(G_CRZ)
#undef G_CRZ
#define G_RY(i) { float s_, c_; sincosf(0.5f * gb[g0 + 19 + i], &s_, &c_); g_ry<i>(re, im, c_, s_, lane); }
        ALLQ(G_RY)
#undef G_RY
        { float s_, c_; sincosf(0.5f * gb[g0 + 29], &s_, &c_); g_crz<9, 0>(re, im, c_, s_, lane); }
    }
#define G_M2(w) { float X, Y, Z; meas_q<w>(re, im, lane, X, Y, Z); \
        y2 = fmaf(X, W2[kk * 30 + w], y2); y2 = fmaf(Y, W2[kk * 30 + 10 + w], y2); y2 = fmaf(Z, W2[kk * 30 + 20 + w], y2); }
    ALLQ(G_M2)
#undef G_M2

    // skip circuit
    init_state(re, im, lane);
#define G_RXS(i) { float s_, c_; sincosf(0.5f * sp[i], &s_, &c_); g_rx<i>(re, im, c_, s_, lane); }
    ALLQ(G_RXS)
#undef G_RXS
#define G_RYS(i) { float s_, c_; sincosf(0.5f * sp[10 + i], &s_, &c_); g_ry<i>(re, im, c_, s_, lane); }
    ALLQ(G_RYS)
#undef G_RYS
#define G_RZS(i) { float s_, c_; sincosf(0.5f * sp[20 + i], &s_, &c_); g_rz<i>(re, im, c_, s_, lane); }
    ALLQ(G_RZS)
#undef G_RZS
#define G_M3(w) { float X, Y, Z; meas_q<w>(re, im, lane, X, Y, Z); \
        y3 = fmaf(X, W3[kk * 30 + w], y3); y3 = fmaf(Y, W3[kk * 30 + 10 + w], y3); y3 = fmaf(Z, W3[kk * 30 + 20 + w], y3); }
    ALLQ(G_M3)
#undef G_M3

    const float w1v = w1p[0], w2v = w2p[0], w3v = w3p[0];
    float ut = 0.f;
    for (int k = 0; k < 30; ++k) ut = fmaf(Wout[k], W1[k * 30 + kk], ut);
    float vk = act ? Wout[kk] * (w1v * b1[kk] + w2v * (b2[kk] + y2) + w3v * (b3[kk] + y3)) : 0.f;
#pragma unroll
    for (int off = 1; off < 64; off <<= 1) vk += __shfl_xor(vk, off);
    if (act) ws_u[lane] = w1v * ut;
    if (lane == 0) ws_u[30] = vk + bout[0];
}

// ---------------- main kernel ----------------

__global__ void __launch_bounds__(TPB) k_main(
    const float* __restrict__ x, const float* __restrict__ Wp,
    const float* __restrict__ bp_, const float* __restrict__ qb,
    const float* __restrict__ bpar, const float* __restrict__ cpar, const float* __restrict__ dtpar,
    const float* __restrict__ gb, const float* __restrict__ sp,
    const float* __restrict__ W1, const float* __restrict__ b1,
    const float* __restrict__ W2, const float* __restrict__ b2,
    const float* __restrict__ W3, const float* __restrict__ b3,
    const float* __restrict__ w1p, const float* __restrict__ w2p, const float* __restrict__ w3p,
    const float* __restrict__ Wout, const float* __restrict__ bout,
    float* __restrict__ ws, float* __restrict__ out, int B, int fused) {

    const int wv = threadIdx.x >> 6, lane = threadIdx.x & 63;

    if (fused && blockIdx.x == gridDim.x - 1) {
        if (wv == 0)
            branch_sim(gb, sp, W1, b1, W2, b2, W3, b3, w1p, w2p, w3p, Wout, bout,
                       ws + (size_t)B * 32, lane);
        return;
    }

    const int b = blockIdx.x * 4 + wv;
    const int bb = (b < B) ? b : (B - 1);

    __shared__ float qc[4][80], qs[4][80], scs[4][32], sss[4][32];

    // ---- projection: qlcu angles ----
    const float4 xv = reinterpret_cast<const float4*>(x + (size_t)bb * 256)[lane];
    float d0 = 0.f, d1 = 0.f;
    for (int t = 0; t < 80; t += 2) {
        float4 wr0 = reinterpret_cast<const float4*>(Wp + (size_t)t * 256)[lane];
        float4 wr1 = reinterpret_cast<const float4*>(Wp + (size_t)(t + 1) * 256)[lane];
        float p0 = xv.x * wr0.x; p0 = fmaf(xv.y, wr0.y, p0); p0 = fmaf(xv.z, wr0.z, p0); p0 = fmaf(xv.w, wr0.w, p0);
        float p1 = xv.x * wr1.x; p1 = fmaf(xv.y, wr1.y, p1); p1 = fmaf(xv.z, wr1.z, p1); p1 = fmaf(xv.w, wr1.w, p1);
#pragma unroll
        for (int off = 1; off < 64; off <<= 1) {
            p0 += __shfl_xor(p0, off);
            p1 += __shfl_xor(p1, off);
        }
        if (t == lane)          d0 = p0;
        if (t + 1 == lane)      d0 = p1;
        if (t == lane + 64)     d1 = p0;
        if (t + 1 == lane + 64) d1 = p1;
    }
    {
        float s_, c_;
        float dd = d0 + bp_[lane];
        float ang = TWO_PI_F / (1.f + expf(-dd)) + qb[lane];
        sincosf(0.5f * ang, &s_, &c_);
        qc[wv][lane] = c_; qs[wv][lane] = s_;
        if (lane < 16) {
            float dd1 = d1 + bp_[64 + lane];
            float a1 = TWO_PI_F / (1.f + expf(-dd1)) + qb[64 + lane];
            sincosf(0.5f * a1, &s_, &c_);
            qc[wv][64 + lane] = c_; qs[wv][64 + lane] = s_;
        }
        if (lane < 30) {
            float th = (lane < 10) ? bpar[lane] : ((lane < 20) ? cpar[lane - 10] : dtpar[lane - 20]);
            sincosf(0.5f * th, &s_, &c_);
            scs[wv][lane] = c_; sss[wv][lane] = s_;
        }
    }
    __syncthreads();

    // ---- state-vector simulation in registers ----
    float re[16], im[16];
    init_state(re, im, lane);
    const float* QC = qc[wv]; const float* QS = qs[wv];
    const float* SC = scs[wv]; const float* SS = sss[wv];

    for (int L = 0; L < 2; ++L) {
        const int q0 = L * 40;
#define G_RYQ(i) g_ry<i>(re, im, QC[q0 + i], QS[q0 + i], lane);
        ALLQ(G_RYQ)
#undef G_RYQ
#define G_XXQ(i) g_xy<i, (i + 1) % 10, false>(re, im, QC[q0 + 10 + i], QS[q0 + 10 + i], lane);
        ALLQ(G_XXQ)
#undef G_XXQ
#define G_RYB(i) g_ry<i>(re, im, SC[i], SS[i], lane);
        ALLQ(G_RYB)
#undef G_RYB
#define G_RYQ2(i) g_ry<i>(re, im, QC[q0 + 20 + i], QS[q0 + 20 + i], lane);
        ALLQ(G_RYQ2)
#undef G_RYQ2
#define G_YYQ(i) g_xy<i, (i + 1) % 10, true>(re, im, QC[q0 + 30 + i], QS[q0 + 30 + i], lane);
        ALLQ(G_YYQ)
#undef G_YYQ
#define G_RZC(i) g_rz<i>(re, im, SC[10 + i], SS[10 + i], lane);
        ALLQ(G_RZC)
#undef G_RZC
#define G_RXD(i) g_rx<i>(re, im, SC[20 + i], SS[20 + i], lane);
        ALLQ(G_RXD)
#undef G_RXD
    }

    // ---- measurement ----
    if (fused) {
        float* mrow = ws + (size_t)bb * 32;
#define G_M(w) { float X, Y, Z; meas_q<w>(re, im, lane, X, Y, Z); \
        if (lane == 0 && b < B) { mrow[w] = X; mrow[10 + w] = Y; mrow[20 + w] = Z; } }
        ALLQ(G_M)
#undef G_M
    } else {
        const float* uu = ws;   // serial mode: u[0..30] at ws base
        float oacc = 0.f;
#define G_M(w) { float X, Y, Z; meas_q<w>(re, im, lane, X, Y, Z); \
        oacc = fmaf(X, uu[w], oacc); oacc = fmaf(Y, uu[10 + w], oacc); oacc = fmaf(Z, uu[20 + w], oacc); }
        ALLQ(G_M)
#undef G_M
        if (lane == 0 && b < B) out[b] = uu[30] + oacc;
    }
}

__global__ void k_branches(const float* __restrict__ gb, const float* __restrict__ sp,
                           const float* __restrict__ W1, const float* __restrict__ b1,
                           const float* __restrict__ W2, const float* __restrict__ b2,
                           const float* __restrict__ W3, const float* __restrict__ b3,
                           const float* __restrict__ w1p, const float* __restrict__ w2p,
                           const float* __restrict__ w3p,
                           const float* __restrict__ Wout, const float* __restrict__ bout,
                           float* __restrict__ ws_u) {
    branch_sim(gb, sp, W1, b1, W2, b2, W3, b3, w1p, w2p, w3p, Wout, bout, ws_u, threadIdx.x & 63);
}

__global__ void k_out(const float* __restrict__ ws, float* __restrict__ out, int B) {
    int i = blockIdx.x * blockDim.x + threadIdx.x;
    if (i < B) {
        const float* u = ws + (size_t)B * 32;
        const float* m = ws + (size_t)i * 32;
        float o = u[30];
#pragma unroll
        for (int j = 0; j < 30; ++j) o = fmaf(m[j], u[j], o);
        out[i] = o;
    }
}

extern "C" void kernel_launch(void* const* d_in, const int* in_sizes, int n_in,
                              void* d_out, int out_size, void* d_ws, size_t ws_size,
                              hipStream_t stream) {
    const float* x         = (const float*)d_in[0];
    const float* W_proj    = (const float*)d_in[1];
    const float* b_proj    = (const float*)d_in[2];
    const float* qlcu_base = (const float*)d_in[3];
    const float* gate_base = (const float*)d_in[4];
    const float* skip_base = (const float*)d_in[5];
    const float* b_params  = (const float*)d_in[6];
    const float* c_params  = (const float*)d_in[7];
    const float* dt_params = (const float*)d_in[8];
    const float* W1    = (const float*)d_in[9];
    const float* b1    = (const float*)d_in[10];
    const float* W2    = (const float*)d_in[11];
    const float* b2    = (const float*)d_in[12];
    const float* W3    = (const float*)d_in[13];
    const float* b3    = (const float*)d_in[14];
    const float* w1    = (const float*)d_in[15];
    const float* w2    = (const float*)d_in[16];
    const float* w3    = (const float*)d_in[17];
    const float* W_out = (const float*)d_in[18];
    const float* b_out = (const float*)d_in[19];
    float* out = (float*)d_out;
    float* ws  = (float*)d_ws;

    const int B = in_sizes[0] / 256;   // FEATURE_DIM = 256
    const size_t need = ((size_t)B * 32 + 32) * sizeof(float);

    if (ws_size >= need && (B % 4) == 0) {
        hipLaunchKernelGGL(k_main, dim3(B / 4 + 1), dim3(TPB), 0, stream,
                           x, W_proj, b_proj, qlcu_base, b_params, c_params, dt_params,
                           gate_base, skip_base, W1, b1, W2, b2, W3, b3, w1, w2, w3,
                           W_out, b_out, ws, out, B, 1);
        hipLaunchKernelGGL(k_out, dim3((B + 255) / 256), dim3(256), 0, stream, ws, out, B);
    } else {
        hipLaunchKernelGGL(k_branches, dim3(1), dim3(64), 0, stream,
                           gate_base, skip_base, W1, b1, W2, b2, W3, b3, w1, w2, w3,
                           W_out, b_out, ws);
        hipLaunchKernelGGL(k_main, dim3((B + 3) / 4), dim3(TPB), 0, stream,
                           x, W_proj, b_proj, qlcu_base, b_params, c_params, dt_params,
                           gate_base, skip_base, W1, b1, W2, b2, W3, b3, w1, w2, w3,
                           W_out, b_out, ws, out, B, 0);
    }
}

// Round 3
// 100.375 us; speedup vs baseline: 2.6158x; 1.5153x over previous
//
#include <hip/hip_runtime.h>
#include <math.h>

#define TPB 256
#define TWO_PI_F 6.283185307179586f

// State layout: one wave (64 lanes) holds 1024 amplitudes.
// s = (lane << 4) | r,  r = 0..15 in registers re[16], im[16].
// Qubit w -> state bit (9-w).  w <= 5: lane bit (5-w).  w >= 6: local bit (9-w).

#define ALLQ(OP) OP(0) OP(1) OP(2) OP(3) OP(4) OP(5) OP(6) OP(7) OP(8) OP(9)
#define ALLQ9(OP) OP(0) OP(1) OP(2) OP(3) OP(4) OP(5) OP(6) OP(7) OP(8)

// ---------------- cross-lane primitives ----------------
// xor 1/2/3 via DPP quad_perm (VALU pipe, low latency); others via ds ops.

template<int CTRL>
__device__ __forceinline__ float dppmv(float v) {
    return __builtin_bit_cast(float,
        __builtin_amdgcn_update_dpp(0, __builtin_bit_cast(int, v), CTRL, 0xF, 0xF, true));
}

template<int LM>
__device__ __forceinline__ float lx(float v) {
    if constexpr (LM == 1)      return dppmv<0xB1>(v);   // quad_perm [1,0,3,2]
    else if constexpr (LM == 2) return dppmv<0x4E>(v);   // quad_perm [2,3,0,1]
    else if constexpr (LM == 3) return dppmv<0x1B>(v);   // quad_perm [3,2,1,0]
    else return __shfl_xor(v, LM);
}

// ---------------- gates ----------------

template<int W>
__device__ __forceinline__ void g_ry(float (&re)[16], float (&im)[16], float c, float s, int lane) {
    if constexpr (W <= 5) {
        constexpr int LM = 1 << (5 - W);
        const float ss = ((lane >> (5 - W)) & 1) ? s : -s;
#pragma unroll
        for (int r = 0; r < 16; ++r) {
            float pr = lx<LM>(re[r]);
            float pi = lx<LM>(im[r]);
            re[r] = fmaf(ss, pr, c * re[r]);
            im[r] = fmaf(ss, pi, c * im[r]);
        }
    } else {
        constexpr int MK = 1 << (9 - W);
#pragma unroll
        for (int r = 0; r < 16; ++r) {
            if ((r & MK) == 0) {
                const int r1 = r | MK;
                float r0 = re[r], i0 = im[r], r1v = re[r1], i1 = im[r1];
                re[r]  = fmaf(-s, r1v, c * r0);
                im[r]  = fmaf(-s, i1,  c * i0);
                re[r1] = fmaf( s, r0,  c * r1v);
                im[r1] = fmaf( s, i0,  c * i1);
            }
        }
    }
}

template<int W>
__device__ __forceinline__ void g_rx(float (&re)[16], float (&im)[16], float c, float s, int lane) {
    if constexpr (W <= 5) {
        constexpr int LM = 1 << (5 - W);
#pragma unroll
        for (int r = 0; r < 16; ++r) {
            float pr = lx<LM>(re[r]);
            float pi = lx<LM>(im[r]);
            re[r] = fmaf( s, pi, c * re[r]);
            im[r] = fmaf(-s, pr, c * im[r]);
        }
    } else {
        constexpr int MK = 1 << (9 - W);
#pragma unroll
        for (int r = 0; r < 16; ++r) {
            if ((r & MK) == 0) {
                const int r1 = r | MK;
                float r0 = re[r], i0 = im[r], r1v = re[r1], i1 = im[r1];
                re[r]  = fmaf( s, i1,  c * r0);
                im[r]  = fmaf(-s, r1v, c * i0);
                re[r1] = fmaf( s, i0,  c * r1v);
                im[r1] = fmaf(-s, r0,  c * i1);
            }
        }
    }
}

template<int W>
__device__ __forceinline__ void g_rz(float (&re)[16], float (&im)[16], float c, float s, int lane) {
    if constexpr (W <= 5) {
        const float sp = ((lane >> (5 - W)) & 1) ? s : -s;
#pragma unroll
        for (int r = 0; r < 16; ++r) {
            float rr = re[r], ii = im[r];
            re[r] = rr * c - ii * sp;
            im[r] = ii * c + rr * sp;
        }
    } else {
        constexpr int MK = 1 << (9 - W);
#pragma unroll
        for (int r = 0; r < 16; ++r) {
            const float sp = (r & MK) ? s : -s;
            float rr = re[r], ii = im[r];
            re[r] = rr * c - ii * sp;
            im[r] = ii * c + rr * sp;
        }
    }
}

template<int C, int T>
__device__ __forceinline__ void g_crz(float (&re)[16], float (&im)[16], float c, float s, int lane) {
#pragma unroll
    for (int r = 0; r < 16; ++r) {
        const int cb = (C <= 5) ? ((lane >> (5 - C)) & 1) : ((r >> (9 - C)) & 1);
        const int tb = (T <= 5) ? ((lane >> (5 - T)) & 1) : ((r >> (9 - T)) & 1);
        const float cc  = cb ? c : 1.f;
        const float sp2 = cb ? (tb ? s : -s) : 0.f;
        float rr = re[r], ii = im[r];
        re[r] = cc * rr - sp2 * ii;
        im[r] = cc * ii + sp2 * rr;
    }
}

template<int A, int Bq, bool YY>
__device__ __forceinline__ void g_xy(float (&re)[16], float (&im)[16], float c, float s, int lane) {
    constexpr int bpA = 9 - A, bpB = 9 - Bq;
    constexpr int LM   = ((bpA >= 4) ? (1 << (bpA - 4)) : 0) | ((bpB >= 4) ? (1 << (bpB - 4)) : 0);
    constexpr int LOCM = ((bpA < 4) ? (1 << bpA) : 0) | ((bpB < 4) ? (1 << bpB) : 0);
    float pr[16], pi[16];
#pragma unroll
    for (int r = 0; r < 16; ++r) {
        float vr = re[r ^ LOCM], vi = im[r ^ LOCM];
        if constexpr (LM != 0) { pr[r] = lx<LM>(vr); pi[r] = lx<LM>(vi); }
        else                   { pr[r] = vr; pi[r] = vi; }
    }
#pragma unroll
    for (int r = 0; r < 16; ++r) {
        float sg;
        if constexpr (YY) {
            const int bA = (A  <= 5) ? ((lane >> (5 - A )) & 1) : ((r >> (9 - A )) & 1);
            const int bB = (Bq <= 5) ? ((lane >> (5 - Bq)) & 1) : ((r >> (9 - Bq)) & 1);
            sg = (bA == bB) ? -s : s;
        } else sg = s;
        float rr = re[r], ii = im[r];
        re[r] = fmaf( sg, pi[r], c * rr);
        im[r] = fmaf(-sg, pr[r], c * ii);
    }
}

// broadcast-style measurement (branch circuits only)
template<int W>
__device__ __forceinline__ void meas_q(const float (&re)[16], const float (&im)[16], int lane,
                                       float& X, float& Y, float& Z) {
    float xa = 0.f, ya = 0.f, za = 0.f;
    if constexpr (W <= 5) {
        constexpr int LM = 1 << (5 - W);
        const float sg = ((lane >> (5 - W)) & 1) ? -1.f : 1.f;
#pragma unroll
        for (int r = 0; r < 16; ++r) {
            float pr = lx<LM>(re[r]);
            float pi = lx<LM>(im[r]);
            xa = fmaf(re[r], pr, xa); xa = fmaf(im[r], pi, xa);
            ya = fmaf(re[r], pi, ya); ya = fmaf(-im[r], pr, ya);
            za = fmaf(re[r], re[r], za); za = fmaf(im[r], im[r], za);
        }
        ya *= sg; za *= sg;
    } else {
        constexpr int MK = 1 << (9 - W);
#pragma unroll
        for (int r = 0; r < 16; ++r) {
            if ((r & MK) == 0) {
                const int r1 = r | MK;
                xa += 2.f * (re[r] * re[r1] + im[r] * im[r1]);
                ya += 2.f * (re[r] * im[r1] - im[r] * re[r1]);
                za += (re[r] * re[r] + im[r] * im[r]) - (re[r1] * re[r1] + im[r1] * im[r1]);
            }
        }
    }
    xa += lx<1>(xa); xa += lx<2>(xa); xa += lx<4>(xa); xa += lx<8>(xa); xa += lx<16>(xa); xa += lx<32>(xa);
    ya += lx<1>(ya); ya += lx<2>(ya); ya += lx<4>(ya); ya += lx<8>(ya); ya += lx<16>(ya); ya += lx<32>(ya);
    za += lx<1>(za); za += lx<2>(za); za += lx<4>(za); za += lx<8>(za); za += lx<16>(za); za += lx<32>(za);
    X = xa; Y = ya; Z = za;
}

__device__ __forceinline__ void init_state(float (&re)[16], float (&im)[16], int lane) {
#pragma unroll
    for (int r = 0; r < 16; ++r) { re[r] = 0.f; im[r] = 0.f; }
    if (lane == 0) re[0] = 1.f;
}

// ---------------- branch circuits -> c0 scalar ----------------

__device__ void branch_sim(const float* __restrict__ gb, const float* __restrict__ sp,
                           const float* __restrict__ b1,
                           const float* __restrict__ W2, const float* __restrict__ b2,
                           const float* __restrict__ W3, const float* __restrict__ b3,
                           const float* __restrict__ w1p, const float* __restrict__ w2p,
                           const float* __restrict__ w3p,
                           const float* __restrict__ Wout, const float* __restrict__ bout,
                           float* __restrict__ ws_c0, int lane) {
    float re[16], im[16];
    const bool act = lane < 30;
    const int kk = act ? lane : 0;
    float y2 = 0.f, y3 = 0.f;

    init_state(re, im, lane);
    for (int L = 0; L < 2; ++L) {
        const int g0 = L * 30;
#define G_RX(i) { float s_, c_; sincosf(0.5f * gb[g0 + i], &s_, &c_); g_rx<i>(re, im, c_, s_, lane); }
        ALLQ(G_RX)
#undef G_RX
#define G_CRZ(i) { float s_, c_; sincosf(0.5f * gb[g0 + 10 + i], &s_, &c_); g_crz<i, i + 1>(re, im, c_, s_, lane); }
        ALLQ9(G_CRZ)
#undef G_CRZ
#define G_RY(i) { float s_, c_; sincosf(0.5f * gb[g0 + 19 + i], &s_, &c_); g_ry<i>(re, im, c_, s_, lane); }
        ALLQ(G_RY)
#undef G_RY
        { float s_, c_; sincosf(0.5f * gb[g0 + 29], &s_, &c_); g_crz<9, 0>(re, im, c_, s_, lane); }
    }
#define G_M2(w) { float X, Y, Z; meas_q<w>(re, im, lane, X, Y, Z); \
        y2 = fmaf(X, W2[kk * 30 + w], y2); y2 = fmaf(Y, W2[kk * 30 + 10 + w], y2); y2 = fmaf(Z, W2[kk * 30 + 20 + w], y2); }
    ALLQ(G_M2)
#undef G_M2

    init_state(re, im, lane);
#define G_RXS(i) { float s_, c_; sincosf(0.5f * sp[i], &s_, &c_); g_rx<i>(re, im, c_, s_, lane); }
    ALLQ(G_RXS)
#undef G_RXS
#define G_RYS(i) { float s_, c_; sincosf(0.5f * sp[10 + i], &s_, &c_); g_ry<i>(re, im, c_, s_, lane); }
    ALLQ(G_RYS)
#undef G_RYS
#define G_RZS(i) { float s_, c_; sincosf(0.5f * sp[20 + i], &s_, &c_); g_rz<i>(re, im, c_, s_, lane); }
    ALLQ(G_RZS)
#undef G_RZS
#define G_M3(w) { float X, Y, Z; meas_q<w>(re, im, lane, X, Y, Z); \
        y3 = fmaf(X, W3[kk * 30 + w], y3); y3 = fmaf(Y, W3[kk * 30 + 10 + w], y3); y3 = fmaf(Z, W3[kk * 30 + 20 + w], y3); }
    ALLQ(G_M3)
#undef G_M3

    const float w1v = w1p[0], w2v = w2p[0], w3v = w3p[0];
    float vk = act ? Wout[kk] * (w1v * b1[kk] + w2v * (b2[kk] + y2) + w3v * (b3[kk] + y3)) : 0.f;
    vk += lx<1>(vk); vk += lx<2>(vk); vk += lx<4>(vk); vk += lx<8>(vk); vk += lx<16>(vk); vk += lx<32>(vk);
    if (lane == 0) ws_c0[0] = vk + bout[0];
}

// ---------------- main kernel ----------------
// blocks 0..NB-1: 4 waves, one batch element each; writes ws[b] = sum_j m1[b,j]*u[j]
// block NB: wave 0 runs branch circuits, writes ws[B] = c0

__global__ void __launch_bounds__(TPB) k_main(
    const float* __restrict__ x, const float* __restrict__ Wp,
    const float* __restrict__ bp_, const float* __restrict__ qb,
    const float* __restrict__ bpar, const float* __restrict__ cpar, const float* __restrict__ dtpar,
    const float* __restrict__ gb, const float* __restrict__ sp,
    const float* __restrict__ W1, const float* __restrict__ b1,
    const float* __restrict__ W2, const float* __restrict__ b2,
    const float* __restrict__ W3, const float* __restrict__ b3,
    const float* __restrict__ w1p, const float* __restrict__ w2p, const float* __restrict__ w3p,
    const float* __restrict__ Wout, const float* __restrict__ bout,
    float* __restrict__ ws, int B) {

    const int wv = threadIdx.x >> 6, lane = threadIdx.x & 63;

    if (blockIdx.x == gridDim.x - 1) {
        if (wv == 0)
            branch_sim(gb, sp, b1, W2, b2, W3, b3, w1p, w2p, w3p, Wout, bout, ws + B, lane);
        return;
    }

    const int b = blockIdx.x * 4 + wv;
    const int bb = (b < B) ? b : (B - 1);

    // per-wave LDS only -> no barriers anywhere
    __shared__ float qc[4][80], qs[4][80], scs[4][32], sss[4][32], proj[4][80], uu[4][32];

    // ---- projection (16-lane groups, 4 rows/pass) ----
    const int sub = lane & 15, grp = lane >> 4;
    float4 xv[4];
    {
        const float* xr = x + (size_t)bb * 256 + sub * 16;
#pragma unroll
        for (int j = 0; j < 4; ++j) xv[j] = reinterpret_cast<const float4*>(xr)[j];
    }
    for (int p = 0; p < 20; ++p) {
        const int row = p * 4 + grp;
        const float* wr = Wp + (size_t)row * 256 + sub * 16;
        float acc = 0.f;
#pragma unroll
        for (int j = 0; j < 4; ++j) {
            float4 w4 = reinterpret_cast<const float4*>(wr)[j];
            acc = fmaf(xv[j].x, w4.x, acc); acc = fmaf(xv[j].y, w4.y, acc);
            acc = fmaf(xv[j].z, w4.z, acc); acc = fmaf(xv[j].w, w4.w, acc);
        }
        acc += lx<1>(acc); acc += lx<2>(acc); acc += lx<4>(acc); acc += lx<8>(acc);
        if (sub == 0) proj[wv][row] = acc;
    }

    // ---- angles + folded output vector u ----
    {
        float s_, c_;
        float dd = proj[wv][lane] + bp_[lane];
        float ang = TWO_PI_F / (1.f + __expf(-dd)) + qb[lane];
        __sincosf(0.5f * ang, &s_, &c_);
        qc[wv][lane] = c_; qs[wv][lane] = s_;
        if (lane < 16) {
            float dd1 = proj[wv][64 + lane] + bp_[64 + lane];
            float a1 = TWO_PI_F / (1.f + __expf(-dd1)) + qb[64 + lane];
            __sincosf(0.5f * a1, &s_, &c_);
            qc[wv][64 + lane] = c_; qs[wv][64 + lane] = s_;
        }
        if (lane < 30) {
            float th = (lane < 10) ? bpar[lane] : ((lane < 20) ? cpar[lane - 10] : dtpar[lane - 20]);
            __sincosf(0.5f * th, &s_, &c_);
            scs[wv][lane] = c_; sss[wv][lane] = s_;
            float ut = 0.f;
            for (int k = 0; k < 30; ++k) ut = fmaf(Wout[k], W1[k * 30 + lane], ut);
            uu[wv][lane] = w1p[0] * ut;
        }
    }

    // ---- state-vector simulation in registers ----
    float re[16], im[16];
    init_state(re, im, lane);
    const float* QC = qc[wv]; const float* QS = qs[wv];
    const float* SC = scs[wv]; const float* SS = sss[wv];

    for (int L = 0; L < 2; ++L) {
        const int q0 = L * 40;
#define G_RYQ(i) g_ry<i>(re, im, QC[q0 + i], QS[q0 + i], lane);
        ALLQ(G_RYQ)
#undef G_RYQ
#define G_XXQ(i) g_xy<i, (i + 1) % 10, false>(re, im, QC[q0 + 10 + i], QS[q0 + 10 + i], lane);
        ALLQ(G_XXQ)
#undef G_XXQ
#define G_RYB(i) g_ry<i>(re, im, SC[i], SS[i], lane);
        ALLQ(G_RYB)
#undef G_RYB
#define G_RYQ2(i) g_ry<i>(re, im, QC[q0 + 20 + i], QS[q0 + 20 + i], lane);
        ALLQ(G_RYQ2)
#undef G_RYQ2
#define G_YYQ(i) g_xy<i, (i + 1) % 10, true>(re, im, QC[q0 + 30 + i], QS[q0 + 30 + i], lane);
        ALLQ(G_YYQ)
#undef G_YYQ
#define G_RZC(i) g_rz<i>(re, im, SC[10 + i], SS[10 + i], lane);
        ALLQ(G_RZC)
#undef G_RZC
#define G_RXD(i) g_rx<i>(re, im, SC[20 + i], SS[20 + i], lane);
        ALLQ(G_RXD)
#undef G_RXD
    }

    // ---- measurement: per-lane partial of sum_w (X_w u_w + Y_w u_{10+w} + Z_w u_{20+w}) ----
    float n2[16], n2s = 0.f;
#pragma unroll
    for (int r = 0; r < 16; ++r) { n2[r] = fmaf(re[r], re[r], im[r] * im[r]); n2s += n2[r]; }

    const float* U = uu[wv];
    float oacc = 0.f;

#define M_LANE(w, LM_) { \
        float xa = 0.f, ya = 0.f; \
        _Pragma("unroll") \
        for (int r = 0; r < 16; ++r) { \
            float pr = lx<LM_>(re[r]); \
            float pi = lx<LM_>(im[r]); \
            xa = fmaf(re[r], pr, xa); xa = fmaf(im[r], pi, xa); \
            ya = fmaf(re[r], pi, ya); ya = fmaf(-im[r], pr, ya); \
        } \
        const float sg = ((lane >> (5 - w)) & 1) ? -1.f : 1.f; \
        oacc = fmaf(xa, U[w], oacc); \
        oacc = fmaf(sg * ya, U[10 + w], oacc); \
        oacc = fmaf(sg * n2s, U[20 + w], oacc); }
    M_LANE(0, 32) M_LANE(1, 16) M_LANE(2, 8) M_LANE(3, 4) M_LANE(4, 2) M_LANE(5, 1)
#undef M_LANE

#define M_REG(w, MK) { \
        float xa = 0.f, ya = 0.f, za = 0.f; \
        _Pragma("unroll") \
        for (int r = 0; r < 16; ++r) { \
            if ((r & MK) == 0) { \
                const int r1 = r | MK; \
                xa = fmaf(re[r], re[r1], xa); xa = fmaf(im[r], im[r1], xa); \
                ya = fmaf(re[r], im[r1], ya); ya = fmaf(-im[r], re[r1], ya); \
                za += n2[r] - n2[r1]; \
            } } \
        oacc = fmaf(2.f * xa, U[w], oacc); \
        oacc = fmaf(2.f * ya, U[10 + w], oacc); \
        oacc = fmaf(za, U[20 + w], oacc); }
    M_REG(6, 8) M_REG(7, 4) M_REG(8, 2) M_REG(9, 1)
#undef M_REG

    oacc += lx<1>(oacc); oacc += lx<2>(oacc); oacc += lx<4>(oacc);
    oacc += lx<8>(oacc); oacc += lx<16>(oacc); oacc += lx<32>(oacc);
    if (lane == 0 && b < B) ws[b] = oacc;
}

__global__ void k_out(const float* __restrict__ ws, float* __restrict__ out, int B) {
    int i = blockIdx.x * blockDim.x + threadIdx.x;
    if (i < B) out[i] = ws[i] + ws[B];
}

extern "C" void kernel_launch(void* const* d_in, const int* in_sizes, int n_in,
                              void* d_out, int out_size, void* d_ws, size_t ws_size,
                              hipStream_t stream) {
    const float* x         = (const float*)d_in[0];
    const float* W_proj    = (const float*)d_in[1];
    const float* b_proj    = (const float*)d_in[2];
    const float* qlcu_base = (const float*)d_in[3];
    const float* gate_base = (const float*)d_in[4];
    const float* skip_base = (const float*)d_in[5];
    const float* b_params  = (const float*)d_in[6];
    const float* c_params  = (const float*)d_in[7];
    const float* dt_params = (const float*)d_in[8];
    const float* W1    = (const float*)d_in[9];
    const float* b1    = (const float*)d_in[10];
    const float* W2    = (const float*)d_in[11];
    const float* b2    = (const float*)d_in[12];
    const float* W3    = (const float*)d_in[13];
    const float* b3    = (const float*)d_in[14];
    const float* w1    = (const float*)d_in[15];
    const float* w2    = (const float*)d_in[16];
    const float* w3    = (const float*)d_in[17];
    const float* W_out = (const float*)d_in[18];
    const float* b_out = (const float*)d_in[19];
    float* out = (float*)d_out;
    float* ws  = (float*)d_ws;

    const int B = in_sizes[0] / 256;   // FEATURE_DIM = 256
    const int nb = (B + 3) / 4;

    hipLaunchKernelGGL(k_main, dim3(nb + 1), dim3(TPB), 0, stream,
                       x, W_proj, b_proj, qlcu_base, b_params, c_params, dt_params,
                       gate_base, skip_base, W1, b1, W2, b2, W3, b3, w1, w2, w3,
                       W_out, b_out, ws, B);
    hipLaunchKernelGGL(k_out, dim3((B + 255) / 256), dim3(256), 0, stream, ws, out, B);
}

// Round 6
// 73.441 us; speedup vs baseline: 3.5751x; 1.3668x over previous
//
#include <hip/hip_runtime.h>
#include <math.h>

#define TPB 256
#define TWO_PI_F 6.283185307179586f

// State layout: one wave (64 lanes) holds 1024 amplitudes.
// s = (lane << 4) | r,  r = 0..15 in registers re[16], im[16].
// Qubit w -> state bit (9-w).  w <= 5: lane bit (5-w).  w >= 6: local bit (9-w).

#define ALLQ(OP) OP(0) OP(1) OP(2) OP(3) OP(4) OP(5) OP(6) OP(7) OP(8) OP(9)
#define ALLQ9(OP) OP(0) OP(1) OP(2) OP(3) OP(4) OP(5) OP(6) OP(7) OP(8)

// ---------------- cross-lane primitives ----------------
// DPP (VALU pipe): quad_perm xor1=0xB1 xor2=0x4E xor3=0x1B;
// xor4 = half_mirror(7)^3, xor6 = half_mirror(7)^1, xor8 = row_ror:8,
// xor12 = mirror(15)^3.  Masks >=16: __shfl_xor (ds pipe, proven correct).

template<int CTRL>
__device__ __forceinline__ float dppmv(float v) {
    return __builtin_bit_cast(float,
        __builtin_amdgcn_update_dpp(0, __builtin_bit_cast(int, v), CTRL, 0xF, 0xF, true));
}

template<int LM>
__device__ __forceinline__ float lx(float v, int lane) {
    (void)lane;
    if constexpr (LM == 1)       return dppmv<0xB1>(v);
    else if constexpr (LM == 2)  return dppmv<0x4E>(v);
    else if constexpr (LM == 3)  return dppmv<0x1B>(v);
    else if constexpr (LM == 4)  return dppmv<0x1B>(dppmv<0x141>(v));   // 7^3
    else if constexpr (LM == 6)  return dppmv<0xB1>(dppmv<0x141>(v));   // 7^1
    else if constexpr (LM == 8)  return dppmv<0x128>(v);                // ror 8
    else if constexpr (LM == 12) return dppmv<0x1B>(dppmv<0x140>(v));   // 15^3
    else                         return __shfl_xor(v, LM);              // 16,24,32,48
}

// ---------------- gates ----------------

template<int W>
__device__ __forceinline__ void g_ry(float (&re)[16], float (&im)[16], float c, float s, int lane) {
    if constexpr (W <= 5) {
        constexpr int LM = 1 << (5 - W);
        const float ss = ((lane >> (5 - W)) & 1) ? s : -s;
#pragma unroll
        for (int r = 0; r < 16; ++r) {
            float pr = lx<LM>(re[r], lane);
            float pi = lx<LM>(im[r], lane);
            re[r] = fmaf(ss, pr, c * re[r]);
            im[r] = fmaf(ss, pi, c * im[r]);
        }
    } else {
        constexpr int MK = 1 << (9 - W);
#pragma unroll
        for (int r = 0; r < 16; ++r) {
            if ((r & MK) == 0) {
                const int r1 = r | MK;
                float r0 = re[r], i0 = im[r], r1v = re[r1], i1 = im[r1];
                re[r]  = fmaf(-s, r1v, c * r0);
                im[r]  = fmaf(-s, i1,  c * i0);
                re[r1] = fmaf( s, r0,  c * r1v);
                im[r1] = fmaf( s, i0,  c * i1);
            }
        }
    }
}

template<int W>
__device__ __forceinline__ void g_rx(float (&re)[16], float (&im)[16], float c, float s, int lane) {
    if constexpr (W <= 5) {
        constexpr int LM = 1 << (5 - W);
#pragma unroll
        for (int r = 0; r < 16; ++r) {
            float pr = lx<LM>(re[r], lane);
            float pi = lx<LM>(im[r], lane);
            re[r] = fmaf( s, pi, c * re[r]);
            im[r] = fmaf(-s, pr, c * im[r]);
        }
    } else {
        constexpr int MK = 1 << (9 - W);
#pragma unroll
        for (int r = 0; r < 16; ++r) {
            if ((r & MK) == 0) {
                const int r1 = r | MK;
                float r0 = re[r], i0 = im[r], r1v = re[r1], i1 = im[r1];
                re[r]  = fmaf( s, i1,  c * r0);
                im[r]  = fmaf(-s, r1v, c * i0);
                re[r1] = fmaf( s, i0,  c * r1v);
                im[r1] = fmaf(-s, r0,  c * i1);
            }
        }
    }
}

template<int W>
__device__ __forceinline__ void g_rz(float (&re)[16], float (&im)[16], float c, float s, int lane) {
    if constexpr (W <= 5) {
        const float sp = ((lane >> (5 - W)) & 1) ? s : -s;
#pragma unroll
        for (int r = 0; r < 16; ++r) {
            float rr = re[r], ii = im[r];
            re[r] = rr * c - ii * sp;
            im[r] = ii * c + rr * sp;
        }
    } else {
        constexpr int MK = 1 << (9 - W);
#pragma unroll
        for (int r = 0; r < 16; ++r) {
            const float sp = (r & MK) ? s : -s;
            float rr = re[r], ii = im[r];
            re[r] = rr * c - ii * sp;
            im[r] = ii * c + rr * sp;
        }
    }
}

template<int C, int T>
__device__ __forceinline__ void g_crz(float (&re)[16], float (&im)[16], float c, float s, int lane) {
#pragma unroll
    for (int r = 0; r < 16; ++r) {
        const int cb = (C <= 5) ? ((lane >> (5 - C)) & 1) : ((r >> (9 - C)) & 1);
        const int tb = (T <= 5) ? ((lane >> (5 - T)) & 1) : ((r >> (9 - T)) & 1);
        const float cc  = cb ? c : 1.f;
        const float sp2 = cb ? (tb ? s : -s) : 0.f;
        float rr = re[r], ii = im[r];
        re[r] = cc * rr - sp2 * ii;
        im[r] = cc * ii + sp2 * rr;
    }
}

template<int A, int Bq, bool YY>
__device__ __forceinline__ void g_xy(float (&re)[16], float (&im)[16], float c, float s, int lane) {
    constexpr int bpA = 9 - A, bpB = 9 - Bq;
    constexpr int LM   = ((bpA >= 4) ? (1 << (bpA - 4)) : 0) | ((bpB >= 4) ? (1 << (bpB - 4)) : 0);
    constexpr int LOCM = ((bpA < 4) ? (1 << bpA) : 0) | ((bpB < 4) ? (1 << bpB) : 0);
    float pr[16], pi[16];
#pragma unroll
    for (int r = 0; r < 16; ++r) {
        float vr = re[r ^ LOCM], vi = im[r ^ LOCM];
        if constexpr (LM != 0) { pr[r] = lx<LM>(vr, lane); pi[r] = lx<LM>(vi, lane); }
        else                   { pr[r] = vr; pi[r] = vi; }
    }
#pragma unroll
    for (int r = 0; r < 16; ++r) {
        float sg;
        if constexpr (YY) {
            const int bA = (A  <= 5) ? ((lane >> (5 - A )) & 1) : ((r >> (9 - A )) & 1);
            const int bB = (Bq <= 5) ? ((lane >> (5 - Bq)) & 1) : ((r >> (9 - Bq)) & 1);
            sg = (bA == bB) ? -s : s;
        } else sg = s;
        float rr = re[r], ii = im[r];
        re[r] = fmaf( sg, pi[r], c * rr);
        im[r] = fmaf(-sg, pr[r], c * ii);
    }
}

// full-wave reduce (sum)
__device__ __forceinline__ float wred(float v, int lane) {
    v += lx<1>(v, lane); v += lx<2>(v, lane); v += lx<4>(v, lane);
    v += lx<8>(v, lane); v += lx<16>(v, lane); v += lx<32>(v, lane);
    return v;
}

// broadcast-style measurement (branch circuits only)
template<int W>
__device__ __forceinline__ void meas_q(const float (&re)[16], const float (&im)[16], int lane,
                                       float& X, float& Y, float& Z) {
    float xa = 0.f, ya = 0.f, za = 0.f;
    if constexpr (W <= 5) {
        constexpr int LM = 1 << (5 - W);
        const float sg = ((lane >> (5 - W)) & 1) ? -1.f : 1.f;
#pragma unroll
        for (int r = 0; r < 16; ++r) {
            float pr = lx<LM>(re[r], lane);
            float pi = lx<LM>(im[r], lane);
            xa = fmaf(re[r], pr, xa); xa = fmaf(im[r], pi, xa);
            ya = fmaf(re[r], pi, ya); ya = fmaf(-im[r], pr, ya);
            za = fmaf(re[r], re[r], za); za = fmaf(im[r], im[r], za);
        }
        ya *= sg; za *= sg;
    } else {
        constexpr int MK = 1 << (9 - W);
#pragma unroll
        for (int r = 0; r < 16; ++r) {
            if ((r & MK) == 0) {
                const int r1 = r | MK;
                xa += 2.f * (re[r] * re[r1] + im[r] * im[r1]);
                ya += 2.f * (re[r] * im[r1] - im[r] * re[r1]);
                za += (re[r] * re[r] + im[r] * im[r]) - (re[r1] * re[r1] + im[r1] * im[r1]);
            }
        }
    }
    X = wred(xa, lane); Y = wred(ya, lane); Z = wred(za, lane);
}

__device__ __forceinline__ void init_state(float (&re)[16], float (&im)[16], int lane) {
#pragma unroll
    for (int r = 0; r < 16; ++r) { re[r] = 0.f; im[r] = 0.f; }
    if (lane == 0) re[0] = 1.f;
}

// ---------------- branch circuits -> c0 scalar ----------------

__device__ void branch_sim(const float* __restrict__ gb, const float* __restrict__ sp,
                           const float* __restrict__ b1,
                           const float* __restrict__ W2, const float* __restrict__ b2,
                           const float* __restrict__ W3, const float* __restrict__ b3,
                           const float* __restrict__ w1p, const float* __restrict__ w2p,
                           const float* __restrict__ w3p,
                           const float* __restrict__ Wout, const float* __restrict__ bout,
                           float* __restrict__ ws_c0, int lane) {
    float re[16], im[16];
    const bool act = lane < 30;
    const int kk = act ? lane : 0;
    float y2 = 0.f, y3 = 0.f;

    init_state(re, im, lane);
    for (int L = 0; L < 2; ++L) {
        const int g0 = L * 30;
#define G_RX(i) { float s_, c_; sincosf(0.5f * gb[g0 + i], &s_, &c_); g_rx<i>(re, im, c_, s_, lane); }
        ALLQ(G_RX)
#undef G_RX
#define G_CRZ(i) { float s_, c_; sincosf(0.5f * gb[g0 + 10 + i], &s_, &c_); g_crz<i, i + 1>(re, im, c_, s_, lane); }
        ALLQ9(G_CRZ)
#undef G_CRZ
#define G_RY(i) { float s_, c_; sincosf(0.5f * gb[g0 + 19 + i], &s_, &c_); g_ry<i>(re, im, c_, s_, lane); }
        ALLQ(G_RY)
#undef G_RY
        { float s_, c_; sincosf(0.5f * gb[g0 + 29], &s_, &c_); g_crz<9, 0>(re, im, c_, s_, lane); }
    }
#define G_M2(w) { float X, Y, Z; meas_q<w>(re, im, lane, X, Y, Z); \
        y2 = fmaf(X, W2[kk * 30 + w], y2); y2 = fmaf(Y, W2[kk * 30 + 10 + w], y2); y2 = fmaf(Z, W2[kk * 30 + 20 + w], y2); }
    ALLQ(G_M2)
#undef G_M2

    init_state(re, im, lane);
#define G_RXS(i) { float s_, c_; sincosf(0.5f * sp[i], &s_, &c_); g_rx<i>(re, im, c_, s_, lane); }
    ALLQ(G_RXS)
#undef G_RXS
#define G_RYS(i) { float s_, c_; sincosf(0.5f * sp[10 + i], &s_, &c_); g_ry<i>(re, im, c_, s_, lane); }
    ALLQ(G_RYS)
#undef G_RYS
#define G_RZS(i) { float s_, c_; sincosf(0.5f * sp[20 + i], &s_, &c_); g_rz<i>(re, im, c_, s_, lane); }
    ALLQ(G_RZS)
#undef G_RZS
#define G_M3(w) { float X, Y, Z; meas_q<w>(re, im, lane, X, Y, Z); \
        y3 = fmaf(X, W3[kk * 30 + w], y3); y3 = fmaf(Y, W3[kk * 30 + 10 + w], y3); y3 = fmaf(Z, W3[kk * 30 + 20 + w], y3); }
    ALLQ(G_M3)
#undef G_M3

    const float w1v = w1p[0], w2v = w2p[0], w3v = w3p[0];
    float vk = act ? Wout[kk] * (w1v * b1[kk] + w2v * (b2[kk] + y2) + w3v * (b3[kk] + y3)) : 0.f;
    vk = wred(vk, lane);
    if (lane == 0) ws_c0[0] = vk + bout[0];
}

// ---------------- main kernel ----------------
// blocks 0..NB-1: 4 waves, one batch element each; writes ws[b] = sum_j m1[b,j]*u[j]
// block NB: wave 0 runs branch circuits, writes ws[B] = c0

__global__ void __launch_bounds__(TPB) k_main(
    const float* __restrict__ x, const float* __restrict__ Wp,
    const float* __restrict__ bp_, const float* __restrict__ qb,
    const float* __restrict__ bpar, const float* __restrict__ cpar, const float* __restrict__ dtpar,
    const float* __restrict__ gb, const float* __restrict__ sp,
    const float* __restrict__ W1, const float* __restrict__ b1,
    const float* __restrict__ W2, const float* __restrict__ b2,
    const float* __restrict__ W3, const float* __restrict__ b3,
    const float* __restrict__ w1p, const float* __restrict__ w2p, const float* __restrict__ w3p,
    const float* __restrict__ Wout, const float* __restrict__ bout,
    float* __restrict__ ws, int B) {

    const int wv = threadIdx.x >> 6, lane = threadIdx.x & 63;

    if (blockIdx.x == gridDim.x - 1) {
        if (wv == 0)
            branch_sim(gb, sp, b1, W2, b2, W3, b3, w1p, w2p, w3p, Wout, bout, ws + B, lane);
        return;
    }

    const int b = blockIdx.x * 4 + wv;
    const int bb = (b < B) ? b : (B - 1);

    // per-wave LDS only -> no barriers anywhere
    __shared__ float qc[4][80], qs[4][80], scs[4][32], sss[4][32], proj[4][80], uu[4][32];

    // ---- projection (16-lane groups, 4 rows/pass) ----
    const int sub = lane & 15, grp = lane >> 4;
    float4 xv[4];
    {
        const float* xr = x + (size_t)bb * 256 + sub * 16;
#pragma unroll
        for (int j = 0; j < 4; ++j) xv[j] = reinterpret_cast<const float4*>(xr)[j];
    }
    for (int p = 0; p < 20; ++p) {
        const int row = p * 4 + grp;
        const float* wr = Wp + (size_t)row * 256 + sub * 16;
        float acc = 0.f;
#pragma unroll
        for (int j = 0; j < 4; ++j) {
            float4 w4 = reinterpret_cast<const float4*>(wr)[j];
            acc = fmaf(xv[j].x, w4.x, acc); acc = fmaf(xv[j].y, w4.y, acc);
            acc = fmaf(xv[j].z, w4.z, acc); acc = fmaf(xv[j].w, w4.w, acc);
        }
        acc += lx<1>(acc, lane); acc += lx<2>(acc, lane);
        acc += lx<4>(acc, lane); acc += lx<8>(acc, lane);
        if (sub == 0) proj[wv][row] = acc;
    }

    // ---- angles + folded output vector u ----
    {
        float s_, c_;
        float dd = proj[wv][lane] + bp_[lane];
        float ang = TWO_PI_F / (1.f + __expf(-dd)) + qb[lane];
        __sincosf(0.5f * ang, &s_, &c_);
        qc[wv][lane] = c_; qs[wv][lane] = s_;
        if (lane < 16) {
            float dd1 = proj[wv][64 + lane] + bp_[64 + lane];
            float a1 = TWO_PI_F / (1.f + __expf(-dd1)) + qb[64 + lane];
            __sincosf(0.5f * a1, &s_, &c_);
            qc[wv][64 + lane] = c_; qs[wv][64 + lane] = s_;
        }
        if (lane < 30) {
            float th = (lane < 10) ? bpar[lane] : ((lane < 20) ? cpar[lane - 10] : dtpar[lane - 20]);
            __sincosf(0.5f * th, &s_, &c_);
            scs[wv][lane] = c_; sss[wv][lane] = s_;
            float ut = 0.f;
            for (int k = 0; k < 30; ++k) ut = fmaf(Wout[k], W1[k * 30 + lane], ut);
            uu[wv][lane] = w1p[0] * ut;
        }
    }

    // ---- state-vector simulation in registers ----
    float re[16], im[16];
    init_state(re, im, lane);
    const float* QC = qc[wv]; const float* QS = qs[wv];
    const float* SC = scs[wv]; const float* SS = sss[wv];

    for (int L = 0; L < 2; ++L) {
        const int q0 = L * 40;
#define G_RYQ(i) g_ry<i>(re, im, QC[q0 + i], QS[q0 + i], lane);
        ALLQ(G_RYQ)
#undef G_RYQ
#define G_XXQ(i) g_xy<i, (i + 1) % 10, false>(re, im, QC[q0 + 10 + i], QS[q0 + 10 + i], lane);
        ALLQ(G_XXQ)
#undef G_XXQ
#define G_RYB(i) g_ry<i>(re, im, SC[i], SS[i], lane);
        ALLQ(G_RYB)
#undef G_RYB
#define G_RYQ2(i) g_ry<i>(re, im, QC[q0 + 20 + i], QS[q0 + 20 + i], lane);
        ALLQ(G_RYQ2)
#undef G_RYQ2
#define G_YYQ(i) g_xy<i, (i + 1) % 10, true>(re, im, QC[q0 + 30 + i], QS[q0 + 30 + i], lane);
        ALLQ(G_YYQ)
#undef G_YYQ
#define G_RZC(i) g_rz<i>(re, im, SC[10 + i], SS[10 + i], lane);
        ALLQ(G_RZC)
#undef G_RZC
#define G_RXD(i) g_rx<i>(re, im, SC[20 + i], SS[20 + i], lane);
        ALLQ(G_RXD)
#undef G_RXD
    }

    // ---- measurement: per-lane partial of sum_w (X_w u_w + Y_w u_{10+w} + Z_w u_{20+w}) ----
    float n2[16], n2s = 0.f;
#pragma unroll
    for (int r = 0; r < 16; ++r) { n2[r] = fmaf(re[r], re[r], im[r] * im[r]); n2s += n2[r]; }

    const float* U = uu[wv];
    float oacc = 0.f;

#define M_LANE(w, LM_) { \
        float xa = 0.f, ya = 0.f; \
        _Pragma("unroll") \
        for (int r = 0; r < 16; ++r) { \
            float pr = lx<LM_>(re[r], lane); \
            float pi = lx<LM_>(im[r], lane); \
            xa = fmaf(re[r], pr, xa); xa = fmaf(im[r], pi, xa); \
            ya = fmaf(re[r], pi, ya); ya = fmaf(-im[r], pr, ya); \
        } \
        const float sg = ((lane >> (5 - w)) & 1) ? -1.f : 1.f; \
        oacc = fmaf(xa, U[w], oacc); \
        oacc = fmaf(sg * ya, U[10 + w], oacc); \
        oacc = fmaf(sg * n2s, U[20 + w], oacc); }
    M_LANE(0, 32) M_LANE(1, 16) M_LANE(2, 8) M_LANE(3, 4) M_LANE(4, 2) M_LANE(5, 1)
#undef M_LANE

#define M_REG(w, MK) { \
        float xa = 0.f, ya = 0.f, za = 0.f; \
        _Pragma("unroll") \
        for (int r = 0; r < 16; ++r) { \
            if ((r & MK) == 0) { \
                const int r1 = r | MK; \
                xa = fmaf(re[r], re[r1], xa); xa = fmaf(im[r], im[r1], xa); \
                ya = fmaf(re[r], im[r1], ya); ya = fmaf(-im[r], re[r1], ya); \
                za += n2[r] - n2[r1]; \
            } } \
        oacc = fmaf(2.f * xa, U[w], oacc); \
        oacc = fmaf(2.f * ya, U[10 + w], oacc); \
        oacc = fmaf(za, U[20 + w], oacc); }
    M_REG(6, 8) M_REG(7, 4) M_REG(8, 2) M_REG(9, 1)
#undef M_REG

    oacc = wred(oacc, lane);
    if (lane == 0 && b < B) ws[b] = oacc;
}

__global__ void k_out(const float* __restrict__ ws, float* __restrict__ out, int B) {
    int i = blockIdx.x * blockDim.x + threadIdx.x;
    if (i < B) out[i] = ws[i] + ws[B];
}

extern "C" void kernel_launch(void* const* d_in, const int* in_sizes, int n_in,
                              void* d_out, int out_size, void* d_ws, size_t ws_size,
                              hipStream_t stream) {
    const float* x         = (const float*)d_in[0];
    const float* W_proj    = (const float*)d_in[1];
    const float* b_proj    = (const float*)d_in[2];
    const float* qlcu_base = (const float*)d_in[3];
    const float* gate_base = (const float*)d_in[4];
    const float* skip_base = (const float*)d_in[5];
    const float* b_params  = (const float*)d_in[6];
    const float* c_params  = (const float*)d_in[7];
    const float* dt_params = (const float*)d_in[8];
    const float* W1    = (const float*)d_in[9];
    const float* b1    = (const float*)d_in[10];
    const float* W2    = (const float*)d_in[11];
    const float* b2    = (const float*)d_in[12];
    const float* W3    = (const float*)d_in[13];
    const float* b3    = (const float*)d_in[14];
    const float* w1    = (const float*)d_in[15];
    const float* w2    = (const float*)d_in[16];
    const float* w3    = (const float*)d_in[17];
    const float* W_out = (const float*)d_in[18];
    const float* b_out = (const float*)d_in[19];
    float* out = (float*)d_out;
    float* ws  = (float*)d_ws;

    const int B = in_sizes[0] / 256;   // FEATURE_DIM = 256
    const int nb = (B + 3) / 4;

    hipLaunchKernelGGL(k_main, dim3(nb + 1), dim3(TPB), 0, stream,
                       x, W_proj, b_proj, qlcu_base, b_params, c_params, dt_params,
                       gate_base, skip_base, W1, b1, W2, b2, W3, b3, w1, w2, w3,
                       W_out, b_out, ws, B);
    hipLaunchKernelGGL(k_out, dim3((B + 255) / 256), dim3(256), 0, stream, ws, out, B);
}

// Round 7
// 67.741 us; speedup vs baseline: 3.8759x; 1.0841x over previous
//
#include <hip/hip_runtime.h>
#include <math.h>

#define TPB 256
#define TWO_PI_F 6.283185307179586f

// State layout: one wave (64 lanes) holds 1024 amplitudes.
// s = (lane << 4) | r,  r = 0..15 in registers re[16], im[16].
// Qubit w -> state bit (9-w).  w <= 5: lane bit (5-w).  w >= 6: local bit (9-w).

#define ALLQ(OP) OP(0) OP(1) OP(2) OP(3) OP(4) OP(5) OP(6) OP(7) OP(8) OP(9)
#define ALLQ9(OP) OP(0) OP(1) OP(2) OP(3) OP(4) OP(5) OP(6) OP(7) OP(8)

// ---------------- cross-lane primitives ----------------
// DPP (VALU pipe): quad_perm xor1=0xB1 xor2=0x4E xor3=0x1B;
// xor4 = half_mirror(7)^3, xor6 = half_mirror(7)^1, xor8 = row_ror:8,
// xor12 = mirror(15)^3.  Masks >=16: __shfl_xor (ds pipe, proven correct).

template<int CTRL>
__device__ __forceinline__ float dppmv(float v) {
    return __builtin_bit_cast(float,
        __builtin_amdgcn_update_dpp(0, __builtin_bit_cast(int, v), CTRL, 0xF, 0xF, true));
}

template<int LM>
__device__ __forceinline__ float lx(float v, int lane) {
    (void)lane;
    if constexpr (LM == 1)       return dppmv<0xB1>(v);
    else if constexpr (LM == 2)  return dppmv<0x4E>(v);
    else if constexpr (LM == 3)  return dppmv<0x1B>(v);
    else if constexpr (LM == 4)  return dppmv<0x1B>(dppmv<0x141>(v));   // 7^3
    else if constexpr (LM == 6)  return dppmv<0xB1>(dppmv<0x141>(v));   // 7^1
    else if constexpr (LM == 8)  return dppmv<0x128>(v);                // ror 8
    else if constexpr (LM == 12) return dppmv<0x1B>(dppmv<0x140>(v));   // 15^3
    else                         return __shfl_xor(v, LM);              // 16,24,32,48
}

// ---------------- gates ----------------

template<int W>
__device__ __forceinline__ void g_ry(float (&re)[16], float (&im)[16], float c, float s, int lane) {
    if constexpr (W <= 5) {
        constexpr int LM = 1 << (5 - W);
        const float ss = ((lane >> (5 - W)) & 1) ? s : -s;
#pragma unroll
        for (int r = 0; r < 16; ++r) {
            float pr = lx<LM>(re[r], lane);
            float pi = lx<LM>(im[r], lane);
            re[r] = fmaf(ss, pr, c * re[r]);
            im[r] = fmaf(ss, pi, c * im[r]);
        }
    } else {
        constexpr int MK = 1 << (9 - W);
#pragma unroll
        for (int r = 0; r < 16; ++r) {
            if ((r & MK) == 0) {
                const int r1 = r | MK;
                float r0 = re[r], i0 = im[r], r1v = re[r1], i1 = im[r1];
                re[r]  = fmaf(-s, r1v, c * r0);
                im[r]  = fmaf(-s, i1,  c * i0);
                re[r1] = fmaf( s, r0,  c * r1v);
                im[r1] = fmaf( s, i0,  c * i1);
            }
        }
    }
}

template<int W>
__device__ __forceinline__ void g_rx(float (&re)[16], float (&im)[16], float c, float s, int lane) {
    if constexpr (W <= 5) {
        constexpr int LM = 1 << (5 - W);
#pragma unroll
        for (int r = 0; r < 16; ++r) {
            float pr = lx<LM>(re[r], lane);
            float pi = lx<LM>(im[r], lane);
            re[r] = fmaf( s, pi, c * re[r]);
            im[r] = fmaf(-s, pr, c * im[r]);
        }
    } else {
        constexpr int MK = 1 << (9 - W);
#pragma unroll
        for (int r = 0; r < 16; ++r) {
            if ((r & MK) == 0) {
                const int r1 = r | MK;
                float r0 = re[r], i0 = im[r], r1v = re[r1], i1 = im[r1];
                re[r]  = fmaf( s, i1,  c * r0);
                im[r]  = fmaf(-s, r1v, c * i0);
                re[r1] = fmaf( s, i0,  c * r1v);
                im[r1] = fmaf(-s, r0,  c * i1);
            }
        }
    }
}

template<int W>
__device__ __forceinline__ void g_rz(float (&re)[16], float (&im)[16], float c, float s, int lane) {
    if constexpr (W <= 5) {
        const float sp = ((lane >> (5 - W)) & 1) ? s : -s;
#pragma unroll
        for (int r = 0; r < 16; ++r) {
            float rr = re[r], ii = im[r];
            re[r] = rr * c - ii * sp;
            im[r] = ii * c + rr * sp;
        }
    } else {
        constexpr int MK = 1 << (9 - W);
#pragma unroll
        for (int r = 0; r < 16; ++r) {
            const float sp = (r & MK) ? s : -s;
            float rr = re[r], ii = im[r];
            re[r] = rr * c - ii * sp;
            im[r] = ii * c + rr * sp;
        }
    }
}

template<int C, int T>
__device__ __forceinline__ void g_crz(float (&re)[16], float (&im)[16], float c, float s, int lane) {
#pragma unroll
    for (int r = 0; r < 16; ++r) {
        const int cb = (C <= 5) ? ((lane >> (5 - C)) & 1) : ((r >> (9 - C)) & 1);
        const int tb = (T <= 5) ? ((lane >> (5 - T)) & 1) : ((r >> (9 - T)) & 1);
        const float cc  = cb ? c : 1.f;
        const float sp2 = cb ? (tb ? s : -s) : 0.f;
        float rr = re[r], ii = im[r];
        re[r] = cc * rr - sp2 * ii;
        im[r] = cc * ii + sp2 * rr;
    }
}

template<int A, int Bq, bool YY>
__device__ __forceinline__ void g_xy(float (&re)[16], float (&im)[16], float c, float s, int lane) {
    constexpr int bpA = 9 - A, bpB = 9 - Bq;
    constexpr int LM   = ((bpA >= 4) ? (1 << (bpA - 4)) : 0) | ((bpB >= 4) ? (1 << (bpB - 4)) : 0);
    constexpr int LOCM = ((bpA < 4) ? (1 << bpA) : 0) | ((bpB < 4) ? (1 << bpB) : 0);
    float pr[16], pi[16];
#pragma unroll
    for (int r = 0; r < 16; ++r) {
        float vr = re[r ^ LOCM], vi = im[r ^ LOCM];
        if constexpr (LM != 0) { pr[r] = lx<LM>(vr, lane); pi[r] = lx<LM>(vi, lane); }
        else                   { pr[r] = vr; pi[r] = vi; }
    }
#pragma unroll
    for (int r = 0; r < 16; ++r) {
        float sg;
        if constexpr (YY) {
            const int bA = (A  <= 5) ? ((lane >> (5 - A )) & 1) : ((r >> (9 - A )) & 1);
            const int bB = (Bq <= 5) ? ((lane >> (5 - Bq)) & 1) : ((r >> (9 - Bq)) & 1);
            sg = (bA == bB) ? -s : s;
        } else sg = s;
        float rr = re[r], ii = im[r];
        re[r] = fmaf( sg, pi[r], c * rr);
        im[r] = fmaf(-sg, pr[r], c * ii);
    }
}

// general 1-qubit gate U = [[u00,u01],[u10,u11]] complex, entries in U[0..7]
template<int W>
__device__ __forceinline__ void g_u1(float (&re)[16], float (&im)[16], const float* U, int lane) {
    const float u00r=U[0], u00i=U[1], u01r=U[2], u01i=U[3];
    const float u10r=U[4], u10i=U[5], u11r=U[6], u11i=U[7];
    if constexpr (W <= 5) {
        constexpr int LM = 1 << (5 - W);
        const int side = (lane >> (5 - W)) & 1;
        const float aR = side ? u11r : u00r, aI = side ? u11i : u00i;   // own coef
        const float bR = side ? u10r : u01r, bI = side ? u10i : u01i;   // partner coef
#pragma unroll
        for (int r = 0; r < 16; ++r) {
            float pr = lx<LM>(re[r], lane), pi = lx<LM>(im[r], lane);
            float rr = re[r], ii = im[r];
            float nr = aR * rr; nr = fmaf(-aI, ii, nr); nr = fmaf(bR, pr, nr); nr = fmaf(-bI, pi, nr);
            float ni = aR * ii; ni = fmaf( aI, rr, ni); ni = fmaf(bR, pi, ni); ni = fmaf( bI, pr, ni);
            re[r] = nr; im[r] = ni;
        }
    } else {
        constexpr int MK = 1 << (9 - W);
#pragma unroll
        for (int r = 0; r < 16; ++r) {
            if ((r & MK) == 0) {
                const int r1 = r | MK;
                float r0 = re[r], i0 = im[r], r1v = re[r1], i1 = im[r1];
                float a = u00r*r0; a = fmaf(-u00i, i0, a); a = fmaf(u01r, r1v, a); a = fmaf(-u01i, i1, a);
                float b = u00r*i0; b = fmaf( u00i, r0, b); b = fmaf(u01r, i1,  b); b = fmaf( u01i, r1v, b);
                float c = u10r*r0; c = fmaf(-u10i, i0, c); c = fmaf(u11r, r1v, c); c = fmaf(-u11i, i1, c);
                float d = u10r*i0; d = fmaf( u10i, r0, d); d = fmaf(u11r, i1,  d); d = fmaf( u11i, r1v, d);
                re[r] = a; im[r] = b; re[r1] = c; im[r1] = d;
            }
        }
    }
}

// full-wave reduce (sum)
__device__ __forceinline__ float wred(float v, int lane) {
    v += lx<1>(v, lane); v += lx<2>(v, lane); v += lx<4>(v, lane);
    v += lx<8>(v, lane); v += lx<16>(v, lane); v += lx<32>(v, lane);
    return v;
}

// broadcast-style measurement (branch circuits only)
template<int W>
__device__ __forceinline__ void meas_q(const float (&re)[16], const float (&im)[16], int lane,
                                       float& X, float& Y, float& Z) {
    float xa = 0.f, ya = 0.f, za = 0.f;
    if constexpr (W <= 5) {
        constexpr int LM = 1 << (5 - W);
        const float sg = ((lane >> (5 - W)) & 1) ? -1.f : 1.f;
#pragma unroll
        for (int r = 0; r < 16; ++r) {
            float pr = lx<LM>(re[r], lane);
            float pi = lx<LM>(im[r], lane);
            xa = fmaf(re[r], pr, xa); xa = fmaf(im[r], pi, xa);
            ya = fmaf(re[r], pi, ya); ya = fmaf(-im[r], pr, ya);
            za = fmaf(re[r], re[r], za); za = fmaf(im[r], im[r], za);
        }
        ya *= sg; za *= sg;
    } else {
        constexpr int MK = 1 << (9 - W);
#pragma unroll
        for (int r = 0; r < 16; ++r) {
            if ((r & MK) == 0) {
                const int r1 = r | MK;
                xa += 2.f * (re[r] * re[r1] + im[r] * im[r1]);
                ya += 2.f * (re[r] * im[r1] - im[r] * re[r1]);
                za += (re[r] * re[r] + im[r] * im[r]) - (re[r1] * re[r1] + im[r1] * im[r1]);
            }
        }
    }
    X = wred(xa, lane); Y = wred(ya, lane); Z = wred(za, lane);
}

__device__ __forceinline__ void init_state(float (&re)[16], float (&im)[16], int lane) {
#pragma unroll
    for (int r = 0; r < 16; ++r) { re[r] = 0.f; im[r] = 0.f; }
    if (lane == 0) re[0] = 1.f;
}

// ---------------- branch circuits -> c0 scalar (unchanged, proven) ----------------

__device__ void branch_sim(const float* __restrict__ gb, const float* __restrict__ sp,
                           const float* __restrict__ b1,
                           const float* __restrict__ W2, const float* __restrict__ b2,
                           const float* __restrict__ W3, const float* __restrict__ b3,
                           const float* __restrict__ w1p, const float* __restrict__ w2p,
                           const float* __restrict__ w3p,
                           const float* __restrict__ Wout, const float* __restrict__ bout,
                           float* __restrict__ ws_c0, int lane) {
    float re[16], im[16];
    const bool act = lane < 30;
    const int kk = act ? lane : 0;
    float y2 = 0.f, y3 = 0.f;

    init_state(re, im, lane);
    for (int L = 0; L < 2; ++L) {
        const int g0 = L * 30;
#define G_RX(i) { float s_, c_; sincosf(0.5f * gb[g0 + i], &s_, &c_); g_rx<i>(re, im, c_, s_, lane); }
        ALLQ(G_RX)
#undef G_RX
#define G_CRZ(i) { float s_, c_; sincosf(0.5f * gb[g0 + 10 + i], &s_, &c_); g_crz<i, i + 1>(re, im, c_, s_, lane); }
        ALLQ9(G_CRZ)
#undef G_CRZ
#define G_RY(i) { float s_, c_; sincosf(0.5f * gb[g0 + 19 + i], &s_, &c_); g_ry<i>(re, im, c_, s_, lane); }
        ALLQ(G_RY)
#undef G_RY
        { float s_, c_; sincosf(0.5f * gb[g0 + 29], &s_, &c_); g_crz<9, 0>(re, im, c_, s_, lane); }
    }
#define G_M2(w) { float X, Y, Z; meas_q<w>(re, im, lane, X, Y, Z); \
        y2 = fmaf(X, W2[kk * 30 + w], y2); y2 = fmaf(Y, W2[kk * 30 + 10 + w], y2); y2 = fmaf(Z, W2[kk * 30 + 20 + w], y2); }
    ALLQ(G_M2)
#undef G_M2

    init_state(re, im, lane);
#define G_RXS(i) { float s_, c_; sincosf(0.5f * sp[i], &s_, &c_); g_rx<i>(re, im, c_, s_, lane); }
    ALLQ(G_RXS)
#undef G_RXS
#define G_RYS(i) { float s_, c_; sincosf(0.5f * sp[10 + i], &s_, &c_); g_ry<i>(re, im, c_, s_, lane); }
    ALLQ(G_RYS)
#undef G_RYS
#define G_RZS(i) { float s_, c_; sincosf(0.5f * sp[20 + i], &s_, &c_); g_rz<i>(re, im, c_, s_, lane); }
    ALLQ(G_RZS)
#undef G_RZS
#define G_M3(w) { float X, Y, Z; meas_q<w>(re, im, lane, X, Y, Z); \
        y3 = fmaf(X, W3[kk * 30 + w], y3); y3 = fmaf(Y, W3[kk * 30 + 10 + w], y3); y3 = fmaf(Z, W3[kk * 30 + 20 + w], y3); }
    ALLQ(G_M3)
#undef G_M3

    const float w1v = w1p[0], w2v = w2p[0], w3v = w3p[0];
    float vk = act ? Wout[kk] * (w1v * b1[kk] + w2v * (b2[kk] + y2) + w3v * (b3[kk] + y3)) : 0.f;
    vk = wred(vk, lane);
    if (lane == 0) ws_c0[0] = vk + bout[0];
}

// ---------------- main kernel ----------------
// Fused circuit per element (algebraically identical to reference):
//   product-init(ry A1) ; XX(B1) ; ry(bpar+D1) ; YY(E1) ;
//   U_bnd = Ry(A2)Rx(dt)Rz(c) ; XX(B2) ; ry(bpar+D2) ; YY(E2) ;
//   measurement with u' = Bloch-rotated fold vector (absorbs final rz,rx).

__global__ void __launch_bounds__(TPB) k_main(
    const float* __restrict__ x, const float* __restrict__ Wp,
    const float* __restrict__ bp_, const float* __restrict__ qb,
    const float* __restrict__ bpar, const float* __restrict__ cpar, const float* __restrict__ dtpar,
    const float* __restrict__ gb, const float* __restrict__ sp,
    const float* __restrict__ W1, const float* __restrict__ b1,
    const float* __restrict__ W2, const float* __restrict__ b2,
    const float* __restrict__ W3, const float* __restrict__ b3,
    const float* __restrict__ w1p, const float* __restrict__ w2p, const float* __restrict__ w3p,
    const float* __restrict__ Wout, const float* __restrict__ bout,
    float* __restrict__ ws, int B) {

    const int wv = threadIdx.x >> 6, lane = threadIdx.x & 63;

    if (blockIdx.x == gridDim.x - 1) {
        if (wv == 0)
            branch_sim(gb, sp, b1, W2, b2, W3, b3, w1p, w2p, w3p, Wout, bout, ws + B, lane);
        return;
    }

    const int b = blockIdx.x * 4 + wv;
    const int bb = (b < B) ? b : (B - 1);

    // per-wave LDS only -> no barriers anywhere
    __shared__ float proj[4][80];
    __shared__ float ac1[4][10], as1[4][10], ac2[4][10], as2[4][10];
    __shared__ float gc[4][60], gs[4][60];          // [B1,CD1,E1, B2,CD2,E2]
    __shared__ float ub[4][80];                      // 10 qubits x 8 floats
    __shared__ float uraw[4][32], uu[4][32];

    // ---- projection (16-lane groups, 4 rows/pass) ----
    const int sub = lane & 15, grp = lane >> 4;
    float4 xv[4];
    {
        const float* xr = x + (size_t)bb * 256 + sub * 16;
#pragma unroll
        for (int j = 0; j < 4; ++j) xv[j] = reinterpret_cast<const float4*>(xr)[j];
    }
    for (int p = 0; p < 20; ++p) {
        const int row = p * 4 + grp;
        const float* wr = Wp + (size_t)row * 256 + sub * 16;
        float acc = 0.f;
#pragma unroll
        for (int j = 0; j < 4; ++j) {
            float4 w4 = reinterpret_cast<const float4*>(wr)[j];
            acc = fmaf(xv[j].x, w4.x, acc); acc = fmaf(xv[j].y, w4.y, acc);
            acc = fmaf(xv[j].z, w4.z, acc); acc = fmaf(xv[j].w, w4.w, acc);
        }
        acc += lx<1>(acc, lane); acc += lx<2>(acc, lane);
        acc += lx<4>(acc, lane); acc += lx<8>(acc, lane);
        if (sub == 0) proj[wv][row] = acc;
    }

    // ---- angle prep ----
    {
        // classify angle idx: l = idx/40, p = idx%40:
        //  p<10: A (init factors / U_bnd alpha); 10-19: B (XX); 20-29: CD (+bpar); 30-39: E (YY)
#define DO_ANGLE(IDX) { \
        const int idx = (IDX); \
        float ang = TWO_PI_F / (1.f + __expf(-(proj[wv][idx] + bp_[idx]))) + qb[idx]; \
        const int l = (idx >= 40) ? 1 : 0; \
        const int p = idx - 40 * l; \
        float s_, c_; \
        if (p < 10) { \
            __sincosf(0.5f * ang, &s_, &c_); \
            if (l == 0) { ac1[wv][p] = c_; as1[wv][p] = s_; } \
            else        { ac2[wv][p] = c_; as2[wv][p] = s_; } \
        } else if (p < 20) { \
            __sincosf(0.5f * ang, &s_, &c_); \
            gc[wv][l * 30 + p - 10] = c_; gs[wv][l * 30 + p - 10] = s_; \
        } else if (p < 30) { \
            __sincosf(0.5f * (ang + bpar[p - 20]), &s_, &c_); \
            gc[wv][l * 30 + 10 + p - 20] = c_; gs[wv][l * 30 + 10 + p - 20] = s_; \
        } else { \
            __sincosf(0.5f * ang, &s_, &c_); \
            gc[wv][l * 30 + 20 + p - 30] = c_; gs[wv][l * 30 + 20 + p - 30] = s_; \
        } }
        DO_ANGLE(lane)
        if (lane < 16) DO_ANGLE(64 + lane)
#undef DO_ANGLE

        if (lane < 30) {
            float ut = 0.f;
            for (int k = 0; k < 30; ++k) ut = fmaf(Wout[k], W1[k * 30 + lane], ut);
            uraw[wv][lane] = w1p[0] * ut;
        }
        if (lane < 10) {
            // U_bnd = Ry(alpha) Rx(dt) Rz(c), half-angle sincos
            float ca = ac2[wv][lane], sa = as2[wv][lane];
            float cg2, sg2, cd2, sd2;
            __sincosf(0.5f * cpar[lane],  &sg2, &cg2);
            __sincosf(0.5f * dtpar[lane], &sd2, &cd2);
            float A = ca * cd2, Bv = sa * sd2;
            float C = -sa * cd2, D = -ca * sd2;
            float E = sa * cd2,  F = -ca * sd2;
            float G = ca * cd2,  H = -sa * sd2;
            float* U = &ub[wv][lane * 8];
            U[0] = cg2 * A + sg2 * Bv;  U[1] = cg2 * Bv - sg2 * A;   // U00
            U[2] = cg2 * C - sg2 * D;   U[3] = sg2 * C + cg2 * D;    // U01
            U[4] = cg2 * E + sg2 * F;   U[5] = cg2 * F - sg2 * E;    // U10
            U[6] = cg2 * G - sg2 * H;   U[7] = sg2 * G + cg2 * H;    // U11

            // u' = Bloch rotation of fold vector (full angles)
            float cg, sgf, cd, sdf;
            __sincosf(cpar[lane],  &sgf, &cg);
            __sincosf(dtpar[lane], &sdf, &cd);
            float uX = uraw[wv][lane], uY = uraw[wv][10 + lane], uZ = uraw[wv][20 + lane];
            uu[wv][lane]      =  uX * cg + uY * cd * sgf + uZ * sdf * sgf;
            uu[wv][10 + lane] = -uX * sgf + uY * cd * cg + uZ * sdf * cg;
            uu[wv][20 + lane] = -uY * sdf + uZ * cd;
        }
    }

    // ---- product initial state: amp(s) = prod_i (bit_i ? sin : cos) ----
    float re[16], im[16];
    {
        const float* AC = ac1[wv]; const float* AS = as1[wv];
        float pl = ((lane >> 5) & 1) ? AS[0] : AC[0];
        pl *= ((lane >> 4) & 1) ? AS[1] : AC[1];
        pl *= ((lane >> 3) & 1) ? AS[2] : AC[2];
        pl *= ((lane >> 2) & 1) ? AS[3] : AC[3];
        pl *= ((lane >> 1) & 1) ? AS[4] : AC[4];
        pl *= ( lane       & 1) ? AS[5] : AC[5];
#pragma unroll
        for (int r = 0; r < 16; ++r) {
            float p = ((r >> 3) & 1) ? AS[6] : AC[6];
            p *= ((r >> 2) & 1) ? AS[7] : AC[7];
            p *= ((r >> 1) & 1) ? AS[8] : AC[8];
            p *= ( r       & 1) ? AS[9] : AC[9];
            re[r] = pl * p; im[r] = 0.f;
        }
    }

    // ---- fused circuit ----
    const float* GC = gc[wv]; const float* GS = gs[wv];
#define G_XX1(i) g_xy<i, (i + 1) % 10, false>(re, im, GC[i], GS[i], lane);
    ALLQ(G_XX1)
#undef G_XX1
#define G_CD1(i) g_ry<i>(re, im, GC[10 + i], GS[10 + i], lane);
    ALLQ(G_CD1)
#undef G_CD1
#define G_YY1(i) g_xy<i, (i + 1) % 10, true>(re, im, GC[20 + i], GS[20 + i], lane);
    ALLQ(G_YY1)
#undef G_YY1
#define G_UB(i) g_u1<i>(re, im, &ub[wv][i * 8], lane);
    ALLQ(G_UB)
#undef G_UB
#define G_XX2(i) g_xy<i, (i + 1) % 10, false>(re, im, GC[30 + i], GS[30 + i], lane);
    ALLQ(G_XX2)
#undef G_XX2
#define G_CD2(i) g_ry<i>(re, im, GC[40 + i], GS[40 + i], lane);
    ALLQ(G_CD2)
#undef G_CD2
#define G_YY2(i) g_xy<i, (i + 1) % 10, true>(re, im, GC[50 + i], GS[50 + i], lane);
    ALLQ(G_YY2)
#undef G_YY2

    // ---- measurement: per-lane partial of sum_w (X_w u'_w + Y_w u'_{10+w} + Z_w u'_{20+w}) ----
    float n2[16], n2s = 0.f;
#pragma unroll
    for (int r = 0; r < 16; ++r) { n2[r] = fmaf(re[r], re[r], im[r] * im[r]); n2s += n2[r]; }

    const float* U = uu[wv];
    float oacc = 0.f;

#define M_LANE(w, LM_) { \
        float xa = 0.f, ya = 0.f; \
        _Pragma("unroll") \
        for (int r = 0; r < 16; ++r) { \
            float pr = lx<LM_>(re[r], lane); \
            float pi = lx<LM_>(im[r], lane); \
            xa = fmaf(re[r], pr, xa); xa = fmaf(im[r], pi, xa); \
            ya = fmaf(re[r], pi, ya); ya = fmaf(-im[r], pr, ya); \
        } \
        const float sg = ((lane >> (5 - w)) & 1) ? -1.f : 1.f; \
        oacc = fmaf(xa, U[w], oacc); \
        oacc = fmaf(sg * ya, U[10 + w], oacc); \
        oacc = fmaf(sg * n2s, U[20 + w], oacc); }
    M_LANE(0, 32) M_LANE(1, 16) M_LANE(2, 8) M_LANE(3, 4) M_LANE(4, 2) M_LANE(5, 1)
#undef M_LANE

#define M_REG(w, MK) { \
        float xa = 0.f, ya = 0.f, za = 0.f; \
        _Pragma("unroll") \
        for (int r = 0; r < 16; ++r) { \
            if ((r & MK) == 0) { \
                const int r1 = r | MK; \
                xa = fmaf(re[r], re[r1], xa); xa = fmaf(im[r], im[r1], xa); \
                ya = fmaf(re[r], im[r1], ya); ya = fmaf(-im[r], re[r1], ya); \
                za += n2[r] - n2[r1]; \
            } } \
        oacc = fmaf(2.f * xa, U[w], oacc); \
        oacc = fmaf(2.f * ya, U[10 + w], oacc); \
        oacc = fmaf(za, U[20 + w], oacc); }
    M_REG(6, 8) M_REG(7, 4) M_REG(8, 2) M_REG(9, 1)
#undef M_REG

    oacc = wred(oacc, lane);
    if (lane == 0 && b < B) ws[b] = oacc;
}

__global__ void k_out(const float* __restrict__ ws, float* __restrict__ out, int B) {
    int i = blockIdx.x * blockDim.x + threadIdx.x;
    if (i < B) out[i] = ws[i] + ws[B];
}

extern "C" void kernel_launch(void* const* d_in, const int* in_sizes, int n_in,
                              void* d_out, int out_size, void* d_ws, size_t ws_size,
                              hipStream_t stream) {
    const float* x         = (const float*)d_in[0];
    const float* W_proj    = (const float*)d_in[1];
    const float* b_proj    = (const float*)d_in[2];
    const float* qlcu_base = (const float*)d_in[3];
    const float* gate_base = (const float*)d_in[4];
    const float* skip_base = (const float*)d_in[5];
    const float* b_params  = (const float*)d_in[6];
    const float* c_params  = (const float*)d_in[7];
    const float* dt_params = (const float*)d_in[8];
    const float* W1    = (const float*)d_in[9];
    const float* b1    = (const float*)d_in[10];
    const float* W2    = (const float*)d_in[11];
    const float* b2    = (const float*)d_in[12];
    const float* W3    = (const float*)d_in[13];
    const float* b3    = (const float*)d_in[14];
    const float* w1    = (const float*)d_in[15];
    const float* w2    = (const float*)d_in[16];
    const float* w3    = (const float*)d_in[17];
    const float* W_out = (const float*)d_in[18];
    const float* b_out = (const float*)d_in[19];
    float* out = (float*)d_out;
    float* ws  = (float*)d_ws;

    const int B = in_sizes[0] / 256;   // FEATURE_DIM = 256
    const int nb = (B + 3) / 4;

    hipLaunchKernelGGL(k_main, dim3(nb + 1), dim3(TPB), 0, stream,
                       x, W_proj, b_proj, qlcu_base, b_params, c_params, dt_params,
                       gate_base, skip_base, W1, b1, W2, b2, W3, b3, w1, w2, w3,
                       W_out, b_out, ws, B);
    hipLaunchKernelGGL(k_out, dim3((B + 255) / 256), dim3(256), 0, stream, ws, out, B);
}

// Round 8
// 60.672 us; speedup vs baseline: 4.3275x; 1.1165x over previous
//
#include <hip/hip_runtime.h>
#include <math.h>

#define TPB 320
#define TWO_PI_F 6.283185307179586f

// State layout: one wave (64 lanes) holds 1024 amplitudes.
// s = (lane << 4) | r,  r = 0..15 in registers re[16], im[16].
// Qubit w -> state bit (9-w).  w <= 5: lane bit (5-w).  w >= 6: local bit (9-w).

#define ALLQ(OP) OP(0) OP(1) OP(2) OP(3) OP(4) OP(5) OP(6) OP(7) OP(8) OP(9)
#define ALLQ9(OP) OP(0) OP(1) OP(2) OP(3) OP(4) OP(5) OP(6) OP(7) OP(8)

// ---------------- cross-lane primitives ----------------
// DPP (VALU pipe): quad_perm xor1=0xB1 xor2=0x4E xor3=0x1B;
// xor4 = half_mirror(7)^3, xor6 = half_mirror(7)^1, xor8 = row_ror:8,
// xor12 = mirror(15)^3.  Masks >=16: __shfl_xor (ds pipe, proven correct).

template<int CTRL>
__device__ __forceinline__ float dppmv(float v) {
    return __builtin_bit_cast(float,
        __builtin_amdgcn_update_dpp(0, __builtin_bit_cast(int, v), CTRL, 0xF, 0xF, true));
}

template<int LM>
__device__ __forceinline__ float lx(float v, int lane) {
    (void)lane;
    if constexpr (LM == 1)       return dppmv<0xB1>(v);
    else if constexpr (LM == 2)  return dppmv<0x4E>(v);
    else if constexpr (LM == 3)  return dppmv<0x1B>(v);
    else if constexpr (LM == 4)  return dppmv<0x1B>(dppmv<0x141>(v));   // 7^3
    else if constexpr (LM == 6)  return dppmv<0xB1>(dppmv<0x141>(v));   // 7^1
    else if constexpr (LM == 8)  return dppmv<0x128>(v);                // ror 8
    else if constexpr (LM == 12) return dppmv<0x1B>(dppmv<0x140>(v));   // 15^3
    else                         return __shfl_xor(v, LM);              // 16,24,32,48
}

// ---------------- gates ----------------

template<int W>
__device__ __forceinline__ void g_ry(float (&re)[16], float (&im)[16], float c, float s, int lane) {
    if constexpr (W <= 5) {
        constexpr int LM = 1 << (5 - W);
        const float ss = ((lane >> (5 - W)) & 1) ? s : -s;
#pragma unroll
        for (int r = 0; r < 16; ++r) {
            float pr = lx<LM>(re[r], lane);
            float pi = lx<LM>(im[r], lane);
            re[r] = fmaf(ss, pr, c * re[r]);
            im[r] = fmaf(ss, pi, c * im[r]);
        }
    } else {
        constexpr int MK = 1 << (9 - W);
#pragma unroll
        for (int r = 0; r < 16; ++r) {
            if ((r & MK) == 0) {
                const int r1 = r | MK;
                float r0 = re[r], i0 = im[r], r1v = re[r1], i1 = im[r1];
                re[r]  = fmaf(-s, r1v, c * r0);
                im[r]  = fmaf(-s, i1,  c * i0);
                re[r1] = fmaf( s, r0,  c * r1v);
                im[r1] = fmaf( s, i0,  c * i1);
            }
        }
    }
}

template<int W>
__device__ __forceinline__ void g_rx(float (&re)[16], float (&im)[16], float c, float s, int lane) {
    if constexpr (W <= 5) {
        constexpr int LM = 1 << (5 - W);
#pragma unroll
        for (int r = 0; r < 16; ++r) {
            float pr = lx<LM>(re[r], lane);
            float pi = lx<LM>(im[r], lane);
            re[r] = fmaf( s, pi, c * re[r]);
            im[r] = fmaf(-s, pr, c * im[r]);
        }
    } else {
        constexpr int MK = 1 << (9 - W);
#pragma unroll
        for (int r = 0; r < 16; ++r) {
            if ((r & MK) == 0) {
                const int r1 = r | MK;
                float r0 = re[r], i0 = im[r], r1v = re[r1], i1 = im[r1];
                re[r]  = fmaf( s, i1,  c * r0);
                im[r]  = fmaf(-s, r1v, c * i0);
                re[r1] = fmaf( s, i0,  c * r1v);
                im[r1] = fmaf(-s, r0,  c * i1);
            }
        }
    }
}

template<int W>
__device__ __forceinline__ void g_rz(float (&re)[16], float (&im)[16], float c, float s, int lane) {
    if constexpr (W <= 5) {
        const float sp = ((lane >> (5 - W)) & 1) ? s : -s;
#pragma unroll
        for (int r = 0; r < 16; ++r) {
            float rr = re[r], ii = im[r];
            re[r] = rr * c - ii * sp;
            im[r] = ii * c + rr * sp;
        }
    } else {
        constexpr int MK = 1 << (9 - W);
#pragma unroll
        for (int r = 0; r < 16; ++r) {
            const float sp = (r & MK) ? s : -s;
            float rr = re[r], ii = im[r];
            re[r] = rr * c - ii * sp;
            im[r] = ii * c + rr * sp;
        }
    }
}

template<int C, int T>
__device__ __forceinline__ void g_crz(float (&re)[16], float (&im)[16], float c, float s, int lane) {
#pragma unroll
    for (int r = 0; r < 16; ++r) {
        const int cb = (C <= 5) ? ((lane >> (5 - C)) & 1) : ((r >> (9 - C)) & 1);
        const int tb = (T <= 5) ? ((lane >> (5 - T)) & 1) : ((r >> (9 - T)) & 1);
        const float cc  = cb ? c : 1.f;
        const float sp2 = cb ? (tb ? s : -s) : 0.f;
        float rr = re[r], ii = im[r];
        re[r] = cc * rr - sp2 * ii;
        im[r] = cc * ii + sp2 * rr;
    }
}

template<int A, int Bq, bool YY>
__device__ __forceinline__ void g_xy(float (&re)[16], float (&im)[16], float c, float s, int lane) {
    constexpr int bpA = 9 - A, bpB = 9 - Bq;
    constexpr int LM   = ((bpA >= 4) ? (1 << (bpA - 4)) : 0) | ((bpB >= 4) ? (1 << (bpB - 4)) : 0);
    constexpr int LOCM = ((bpA < 4) ? (1 << bpA) : 0) | ((bpB < 4) ? (1 << bpB) : 0);
    float pr[16], pi[16];
#pragma unroll
    for (int r = 0; r < 16; ++r) {
        float vr = re[r ^ LOCM], vi = im[r ^ LOCM];
        if constexpr (LM != 0) { pr[r] = lx<LM>(vr, lane); pi[r] = lx<LM>(vi, lane); }
        else                   { pr[r] = vr; pi[r] = vi; }
    }
#pragma unroll
    for (int r = 0; r < 16; ++r) {
        float sg;
        if constexpr (YY) {
            const int bA = (A  <= 5) ? ((lane >> (5 - A )) & 1) : ((r >> (9 - A )) & 1);
            const int bB = (Bq <= 5) ? ((lane >> (5 - Bq)) & 1) : ((r >> (9 - Bq)) & 1);
            sg = (bA == bB) ? -s : s;
        } else sg = s;
        float rr = re[r], ii = im[r];
        re[r] = fmaf( sg, pi[r], c * rr);
        im[r] = fmaf(-sg, pr[r], c * ii);
    }
}

// general 1-qubit gate U = [[u00,u01],[u10,u11]] complex, entries in U[0..7]
template<int W>
__device__ __forceinline__ void g_u1(float (&re)[16], float (&im)[16], const float* U, int lane) {
    const float u00r=U[0], u00i=U[1], u01r=U[2], u01i=U[3];
    const float u10r=U[4], u10i=U[5], u11r=U[6], u11i=U[7];
    if constexpr (W <= 5) {
        constexpr int LM = 1 << (5 - W);
        const int side = (lane >> (5 - W)) & 1;
        const float aR = side ? u11r : u00r, aI = side ? u11i : u00i;   // own coef
        const float bR = side ? u10r : u01r, bI = side ? u10i : u01i;   // partner coef
#pragma unroll
        for (int r = 0; r < 16; ++r) {
            float pr = lx<LM>(re[r], lane), pi = lx<LM>(im[r], lane);
            float rr = re[r], ii = im[r];
            float nr = aR * rr; nr = fmaf(-aI, ii, nr); nr = fmaf(bR, pr, nr); nr = fmaf(-bI, pi, nr);
            float ni = aR * ii; ni = fmaf( aI, rr, ni); ni = fmaf(bR, pi, ni); ni = fmaf( bI, pr, ni);
            re[r] = nr; im[r] = ni;
        }
    } else {
        constexpr int MK = 1 << (9 - W);
#pragma unroll
        for (int r = 0; r < 16; ++r) {
            if ((r & MK) == 0) {
                const int r1 = r | MK;
                float r0 = re[r], i0 = im[r], r1v = re[r1], i1 = im[r1];
                float a = u00r*r0; a = fmaf(-u00i, i0, a); a = fmaf(u01r, r1v, a); a = fmaf(-u01i, i1, a);
                float b = u00r*i0; b = fmaf( u00i, r0, b); b = fmaf(u01r, i1,  b); b = fmaf( u01i, r1v, b);
                float c = u10r*r0; c = fmaf(-u10i, i0, c); c = fmaf(u11r, r1v, c); c = fmaf(-u11i, i1, c);
                float d = u10r*i0; d = fmaf( u10i, r0, d); d = fmaf(u11r, i1,  d); d = fmaf( u11i, r1v, d);
                re[r] = a; im[r] = b; re[r1] = c; im[r1] = d;
            }
        }
    }
}

// full-wave reduce (sum)
__device__ __forceinline__ float wred(float v, int lane) {
    v += lx<1>(v, lane); v += lx<2>(v, lane); v += lx<4>(v, lane);
    v += lx<8>(v, lane); v += lx<16>(v, lane); v += lx<32>(v, lane);
    return v;
}

// broadcast-style measurement (branch circuits only)
template<int W>
__device__ __forceinline__ void meas_q(const float (&re)[16], const float (&im)[16], int lane,
                                       float& X, float& Y, float& Z) {
    float xa = 0.f, ya = 0.f, za = 0.f;
    if constexpr (W <= 5) {
        constexpr int LM = 1 << (5 - W);
        const float sg = ((lane >> (5 - W)) & 1) ? -1.f : 1.f;
#pragma unroll
        for (int r = 0; r < 16; ++r) {
            float pr = lx<LM>(re[r], lane);
            float pi = lx<LM>(im[r], lane);
            xa = fmaf(re[r], pr, xa); xa = fmaf(im[r], pi, xa);
            ya = fmaf(re[r], pi, ya); ya = fmaf(-im[r], pr, ya);
            za = fmaf(re[r], re[r], za); za = fmaf(im[r], im[r], za);
        }
        ya *= sg; za *= sg;
    } else {
        constexpr int MK = 1 << (9 - W);
#pragma unroll
        for (int r = 0; r < 16; ++r) {
            if ((r & MK) == 0) {
                const int r1 = r | MK;
                xa += 2.f * (re[r] * re[r1] + im[r] * im[r1]);
                ya += 2.f * (re[r] * im[r1] - im[r] * re[r1]);
                za += (re[r] * re[r] + im[r] * im[r]) - (re[r1] * re[r1] + im[r1] * im[r1]);
            }
        }
    }
    X = wred(xa, lane); Y = wred(ya, lane); Z = wred(za, lane);
}

__device__ __forceinline__ void init_state(float (&re)[16], float (&im)[16], int lane) {
#pragma unroll
    for (int r = 0; r < 16; ++r) { re[r] = 0.f; im[r] = 0.f; }
    if (lane == 0) re[0] = 1.f;
}

// ---------------- branch circuits, split across two waves ----------------
// gating -> ws[B]   = bout + sum_k Wout[k]*(w1*b1[k] + w2*(b2[k]+y2[k]))
// skip   -> ws[B+1] =        sum_k Wout[k]*(w3*(b3[k]+y3[k]))

__device__ void branch_gating(const float* __restrict__ gb,
                              const float* __restrict__ b1,
                              const float* __restrict__ W2, const float* __restrict__ b2,
                              const float* __restrict__ w1p, const float* __restrict__ w2p,
                              const float* __restrict__ Wout, const float* __restrict__ bout,
                              float* __restrict__ ws_c, int lane) {
    float re[16], im[16];
    const bool act = lane < 30;
    const int kk = act ? lane : 0;
    float y2 = 0.f;

    init_state(re, im, lane);
    for (int L = 0; L < 2; ++L) {
        const int g0 = L * 30;
#define G_RX(i) { float s_, c_; sincosf(0.5f * gb[g0 + i], &s_, &c_); g_rx<i>(re, im, c_, s_, lane); }
        ALLQ(G_RX)
#undef G_RX
#define G_CRZ(i) { float s_, c_; sincosf(0.5f * gb[g0 + 10 + i], &s_, &c_); g_crz<i, i + 1>(re, im, c_, s_, lane); }
        ALLQ9(G_CRZ)
#undef G_CRZ
#define G_RY(i) { float s_, c_; sincosf(0.5f * gb[g0 + 19 + i], &s_, &c_); g_ry<i>(re, im, c_, s_, lane); }
        ALLQ(G_RY)
#undef G_RY
        { float s_, c_; sincosf(0.5f * gb[g0 + 29], &s_, &c_); g_crz<9, 0>(re, im, c_, s_, lane); }
    }
#define G_M2(w) { float X, Y, Z; meas_q<w>(re, im, lane, X, Y, Z); \
        y2 = fmaf(X, W2[kk * 30 + w], y2); y2 = fmaf(Y, W2[kk * 30 + 10 + w], y2); y2 = fmaf(Z, W2[kk * 30 + 20 + w], y2); }
    ALLQ(G_M2)
#undef G_M2

    const float w1v = w1p[0], w2v = w2p[0];
    float vk = act ? Wout[kk] * (w1v * b1[kk] + w2v * (b2[kk] + y2)) : 0.f;
    vk = wred(vk, lane);
    if (lane == 0) ws_c[0] = vk + bout[0];
}

__device__ void branch_skip(const float* __restrict__ sp,
                            const float* __restrict__ W3, const float* __restrict__ b3,
                            const float* __restrict__ w3p,
                            const float* __restrict__ Wout,
                            float* __restrict__ ws_c, int lane) {
    float re[16], im[16];
    const bool act = lane < 30;
    const int kk = act ? lane : 0;
    float y3 = 0.f;

    init_state(re, im, lane);
#define G_RXS(i) { float s_, c_; sincosf(0.5f * sp[i], &s_, &c_); g_rx<i>(re, im, c_, s_, lane); }
    ALLQ(G_RXS)
#undef G_RXS
#define G_RYS(i) { float s_, c_; sincosf(0.5f * sp[10 + i], &s_, &c_); g_ry<i>(re, im, c_, s_, lane); }
    ALLQ(G_RYS)
#undef G_RYS
#define G_RZS(i) { float s_, c_; sincosf(0.5f * sp[20 + i], &s_, &c_); g_rz<i>(re, im, c_, s_, lane); }
    ALLQ(G_RZS)
#undef G_RZS
#define G_M3(w) { float X, Y, Z; meas_q<w>(re, im, lane, X, Y, Z); \
        y3 = fmaf(X, W3[kk * 30 + w], y3); y3 = fmaf(Y, W3[kk * 30 + 10 + w], y3); y3 = fmaf(Z, W3[kk * 30 + 20 + w], y3); }
    ALLQ(G_M3)
#undef G_M3

    const float w3v = w3p[0];
    float vk = act ? Wout[kk] * (w3v * (b3[kk] + y3)) : 0.f;
    vk = wred(vk, lane);
    if (lane == 0) ws_c[0] = vk;
}

// ---------------- main kernel ----------------
// grid = B/4 blocks of 5 waves. waves 0-3: one batch element each -> ws[b].
// wave 4: block 0 -> gating (ws[B]), block 1 -> skip (ws[B+1]), else exit.
// Fused circuit per element (algebraically identical to reference):
//   product-init(ry A1) ; XX(B1) ; ry(bpar+D1) ; YY(E1) ;
//   U_bnd = Ry(A2)Rx(dt)Rz(c) ; XX(B2) ; ry(bpar+D2) ; YY(E2) ;
//   measurement with u' = Bloch-rotated fold vector (absorbs final rz,rx).

__global__ void __launch_bounds__(TPB) k_main(
    const float* __restrict__ x, const float* __restrict__ Wp,
    const float* __restrict__ bp_, const float* __restrict__ qb,
    const float* __restrict__ bpar, const float* __restrict__ cpar, const float* __restrict__ dtpar,
    const float* __restrict__ gb, const float* __restrict__ sp,
    const float* __restrict__ W1, const float* __restrict__ b1,
    const float* __restrict__ W2, const float* __restrict__ b2,
    const float* __restrict__ W3, const float* __restrict__ b3,
    const float* __restrict__ w1p, const float* __restrict__ w2p, const float* __restrict__ w3p,
    const float* __restrict__ Wout, const float* __restrict__ bout,
    float* __restrict__ ws, int B) {

    const int wv = threadIdx.x >> 6, lane = threadIdx.x & 63;

    if (wv == 4) {
        if (blockIdx.x == 0) {
            branch_gating(gb, b1, W2, b2, w1p, w2p, Wout, bout, ws + B, lane);
            if (gridDim.x == 1) branch_skip(sp, W3, b3, w3p, Wout, ws + B + 1, lane);
        } else if (blockIdx.x == 1) {
            branch_skip(sp, W3, b3, w3p, Wout, ws + B + 1, lane);
        }
        return;
    }

    const int b = blockIdx.x * 4 + wv;
    const int bb = (b < B) ? b : (B - 1);

    // per-wave LDS only -> no barriers anywhere
    __shared__ float proj[4][80];
    __shared__ float ac1[4][10], as1[4][10], ac2[4][10], as2[4][10];
    __shared__ float gc[4][60], gs[4][60];          // [B1,CD1,E1, B2,CD2,E2]
    __shared__ float ub[4][80];                      // 10 qubits x 8 floats
    __shared__ float uraw[4][32], uu[4][32];

    // ---- projection (16-lane groups, 4 rows/pass) ----
    const int sub = lane & 15, grp = lane >> 4;
    float4 xv[4];
    {
        const float* xr = x + (size_t)bb * 256 + sub * 16;
#pragma unroll
        for (int j = 0; j < 4; ++j) xv[j] = reinterpret_cast<const float4*>(xr)[j];
    }
    for (int p = 0; p < 20; ++p) {
        const int row = p * 4 + grp;
        const float* wr = Wp + (size_t)row * 256 + sub * 16;
        float acc = 0.f;
#pragma unroll
        for (int j = 0; j < 4; ++j) {
            float4 w4 = reinterpret_cast<const float4*>(wr)[j];
            acc = fmaf(xv[j].x, w4.x, acc); acc = fmaf(xv[j].y, w4.y, acc);
            acc = fmaf(xv[j].z, w4.z, acc); acc = fmaf(xv[j].w, w4.w, acc);
        }
        acc += lx<1>(acc, lane); acc += lx<2>(acc, lane);
        acc += lx<4>(acc, lane); acc += lx<8>(acc, lane);
        if (sub == 0) proj[wv][row] = acc;
    }

    // ---- angle prep ----
    {
        // classify angle idx: l = idx/40, p = idx%40:
        //  p<10: A (init factors / U_bnd alpha); 10-19: B (XX); 20-29: CD (+bpar); 30-39: E (YY)
#define DO_ANGLE(IDX) { \
        const int idx = (IDX); \
        float ang = TWO_PI_F / (1.f + __expf(-(proj[wv][idx] + bp_[idx]))) + qb[idx]; \
        const int l = (idx >= 40) ? 1 : 0; \
        const int p = idx - 40 * l; \
        float s_, c_; \
        if (p < 10) { \
            __sincosf(0.5f * ang, &s_, &c_); \
            if (l == 0) { ac1[wv][p] = c_; as1[wv][p] = s_; } \
            else        { ac2[wv][p] = c_; as2[wv][p] = s_; } \
        } else if (p < 20) { \
            __sincosf(0.5f * ang, &s_, &c_); \
            gc[wv][l * 30 + p - 10] = c_; gs[wv][l * 30 + p - 10] = s_; \
        } else if (p < 30) { \
            __sincosf(0.5f * (ang + bpar[p - 20]), &s_, &c_); \
            gc[wv][l * 30 + 10 + p - 20] = c_; gs[wv][l * 30 + 10 + p - 20] = s_; \
        } else { \
            __sincosf(0.5f * ang, &s_, &c_); \
            gc[wv][l * 30 + 20 + p - 30] = c_; gs[wv][l * 30 + 20 + p - 30] = s_; \
        } }
        DO_ANGLE(lane)
        if (lane < 16) DO_ANGLE(64 + lane)
#undef DO_ANGLE

        if (lane < 30) {
            float ut = 0.f;
            for (int k = 0; k < 30; ++k) ut = fmaf(Wout[k], W1[k * 30 + lane], ut);
            uraw[wv][lane] = w1p[0] * ut;
        }
        if (lane < 10) {
            // U_bnd = Ry(alpha) Rx(dt) Rz(c), half-angle sincos
            float ca = ac2[wv][lane], sa = as2[wv][lane];
            float cg2, sg2, cd2, sd2;
            __sincosf(0.5f * cpar[lane],  &sg2, &cg2);
            __sincosf(0.5f * dtpar[lane], &sd2, &cd2);
            float A = ca * cd2, Bv = sa * sd2;
            float C = -sa * cd2, D = -ca * sd2;
            float E = sa * cd2,  F = -ca * sd2;
            float G = ca * cd2,  H = -sa * sd2;
            float* U = &ub[wv][lane * 8];
            U[0] = cg2 * A + sg2 * Bv;  U[1] = cg2 * Bv - sg2 * A;   // U00
            U[2] = cg2 * C - sg2 * D;   U[3] = sg2 * C + cg2 * D;    // U01
            U[4] = cg2 * E + sg2 * F;   U[5] = cg2 * F - sg2 * E;    // U10
            U[6] = cg2 * G - sg2 * H;   U[7] = sg2 * G + cg2 * H;    // U11

            // u' = Bloch rotation of fold vector (full angles)
            float cg, sgf, cd, sdf;
            __sincosf(cpar[lane],  &sgf, &cg);
            __sincosf(dtpar[lane], &sdf, &cd);
            float uX = uraw[wv][lane], uY = uraw[wv][10 + lane], uZ = uraw[wv][20 + lane];
            uu[wv][lane]      =  uX * cg + uY * cd * sgf + uZ * sdf * sgf;
            uu[wv][10 + lane] = -uX * sgf + uY * cd * cg + uZ * sdf * cg;
            uu[wv][20 + lane] = -uY * sdf + uZ * cd;
        }
    }

    // ---- product initial state: amp(s) = prod_i (bit_i ? sin : cos) ----
    float re[16], im[16];
    {
        const float* AC = ac1[wv]; const float* AS = as1[wv];
        float pl = ((lane >> 5) & 1) ? AS[0] : AC[0];
        pl *= ((lane >> 4) & 1) ? AS[1] : AC[1];
        pl *= ((lane >> 3) & 1) ? AS[2] : AC[2];
        pl *= ((lane >> 2) & 1) ? AS[3] : AC[3];
        pl *= ((lane >> 1) & 1) ? AS[4] : AC[4];
        pl *= ( lane       & 1) ? AS[5] : AC[5];
#pragma unroll
        for (int r = 0; r < 16; ++r) {
            float p = ((r >> 3) & 1) ? AS[6] : AC[6];
            p *= ((r >> 2) & 1) ? AS[7] : AC[7];
            p *= ((r >> 1) & 1) ? AS[8] : AC[8];
            p *= ( r       & 1) ? AS[9] : AC[9];
            re[r] = pl * p; im[r] = 0.f;
        }
    }

    // ---- fused circuit ----
    const float* GC = gc[wv]; const float* GS = gs[wv];
#define G_XX1(i) g_xy<i, (i + 1) % 10, false>(re, im, GC[i], GS[i], lane);
    ALLQ(G_XX1)
#undef G_XX1
#define G_CD1(i) g_ry<i>(re, im, GC[10 + i], GS[10 + i], lane);
    ALLQ(G_CD1)
#undef G_CD1
#define G_YY1(i) g_xy<i, (i + 1) % 10, true>(re, im, GC[20 + i], GS[20 + i], lane);
    ALLQ(G_YY1)
#undef G_YY1
#define G_UB(i) g_u1<i>(re, im, &ub[wv][i * 8], lane);
    ALLQ(G_UB)
#undef G_UB
#define G_XX2(i) g_xy<i, (i + 1) % 10, false>(re, im, GC[30 + i], GS[30 + i], lane);
    ALLQ(G_XX2)
#undef G_XX2
#define G_CD2(i) g_ry<i>(re, im, GC[40 + i], GS[40 + i], lane);
    ALLQ(G_CD2)
#undef G_CD2
#define G_YY2(i) g_xy<i, (i + 1) % 10, true>(re, im, GC[50 + i], GS[50 + i], lane);
    ALLQ(G_YY2)
#undef G_YY2

    // ---- measurement: per-lane partial of sum_w (X_w u'_w + Y_w u'_{10+w} + Z_w u'_{20+w}) ----
    float n2[16], n2s = 0.f;
#pragma unroll
    for (int r = 0; r < 16; ++r) { n2[r] = fmaf(re[r], re[r], im[r] * im[r]); n2s += n2[r]; }

    const float* U = uu[wv];
    float oacc = 0.f;

#define M_LANE(w, LM_) { \
        float xa = 0.f, ya = 0.f; \
        _Pragma("unroll") \
        for (int r = 0; r < 16; ++r) { \
            float pr = lx<LM_>(re[r], lane); \
            float pi = lx<LM_>(im[r], lane); \
            xa = fmaf(re[r], pr, xa); xa = fmaf(im[r], pi, xa); \
            ya = fmaf(re[r], pi, ya); ya = fmaf(-im[r], pr, ya); \
        } \
        const float sg = ((lane >> (5 - w)) & 1) ? -1.f : 1.f; \
        oacc = fmaf(xa, U[w], oacc); \
        oacc = fmaf(sg * ya, U[10 + w], oacc); \
        oacc = fmaf(sg * n2s, U[20 + w], oacc); }
    M_LANE(0, 32) M_LANE(1, 16) M_LANE(2, 8) M_LANE(3, 4) M_LANE(4, 2) M_LANE(5, 1)
#undef M_LANE

#define M_REG(w, MK) { \
        float xa = 0.f, ya = 0.f, za = 0.f; \
        _Pragma("unroll") \
        for (int r = 0; r < 16; ++r) { \
            if ((r & MK) == 0) { \
                const int r1 = r | MK; \
                xa = fmaf(re[r], re[r1], xa); xa = fmaf(im[r], im[r1], xa); \
                ya = fmaf(re[r], im[r1], ya); ya = fmaf(-im[r], re[r1], ya); \
                za += n2[r] - n2[r1]; \
            } } \
        oacc = fmaf(2.f * xa, U[w], oacc); \
        oacc = fmaf(2.f * ya, U[10 + w], oacc); \
        oacc = fmaf(za, U[20 + w], oacc); }
    M_REG(6, 8) M_REG(7, 4) M_REG(8, 2) M_REG(9, 1)
#undef M_REG

    oacc = wred(oacc, lane);
    if (lane == 0 && b < B) ws[b] = oacc;
}

__global__ void k_out(const float* __restrict__ ws, float* __restrict__ out, int B) {
    int i = blockIdx.x * blockDim.x + threadIdx.x;
    if (i < B) out[i] = ws[i] + ws[B] + ws[B + 1];
}

extern "C" void kernel_launch(void* const* d_in, const int* in_sizes, int n_in,
                              void* d_out, int out_size, void* d_ws, size_t ws_size,
                              hipStream_t stream) {
    const float* x         = (const float*)d_in[0];
    const float* W_proj    = (const float*)d_in[1];
    const float* b_proj    = (const float*)d_in[2];
    const float* qlcu_base = (const float*)d_in[3];
    const float* gate_base = (const float*)d_in[4];
    const float* skip_base = (const float*)d_in[5];
    const float* b_params  = (const float*)d_in[6];
    const float* c_params  = (const float*)d_in[7];
    const float* dt_params = (const float*)d_in[8];
    const float* W1    = (const float*)d_in[9];
    const float* b1    = (const float*)d_in[10];
    const float* W2    = (const float*)d_in[11];
    const float* b2    = (const float*)d_in[12];
    const float* W3    = (const float*)d_in[13];
    const float* b3    = (const float*)d_in[14];
    const float* w1    = (const float*)d_in[15];
    const float* w2    = (const float*)d_in[16];
    const float* w3    = (const float*)d_in[17];
    const float* W_out = (const float*)d_in[18];
    const float* b_out = (const float*)d_in[19];
    float* out = (float*)d_out;
    float* ws  = (float*)d_ws;

    const int B = in_sizes[0] / 256;   // FEATURE_DIM = 256
    const int nb = (B + 3) / 4;        // 512 for B=2048 (exact)

    hipLaunchKernelGGL(k_main, dim3(nb), dim3(TPB), 0, stream,
                       x, W_proj, b_proj, qlcu_base, b_params, c_params, dt_params,
                       gate_base, skip_base, W1, b1, W2, b2, W3, b3, w1, w2, w3,
                       W_out, b_out, ws, B);
    hipLaunchKernelGGL(k_out, dim3((B + 255) / 256), dim3(256), 0, stream, ws, out, B);
}

// Round 10
// 56.162 us; speedup vs baseline: 4.6751x; 1.0803x over previous
//
#include <hip/hip_runtime.h>
#include <math.h>

#define TPB 320
#define TWO_PI_F 6.283185307179586f

// State layout: one wave (64 lanes) holds 1024 amplitudes.
// s = (lane << 4) | r,  r = 0..15 in registers re[16], im[16].
// Qubit w -> state bit (9-w).  w <= 5: lane bit (5-w).  w >= 6: local bit (9-w).
// All cross-lane gates: prefetch partner arrays first (batch the 32 exchanges,
// one wait), then pure-FMA compute.  Masks 1..12: DPP (VALU).  16..48: shfl (DS).

#define ALLQ(OP) OP(0) OP(1) OP(2) OP(3) OP(4) OP(5) OP(6) OP(7) OP(8) OP(9)
#define ALLQ9(OP) OP(0) OP(1) OP(2) OP(3) OP(4) OP(5) OP(6) OP(7) OP(8)

template<int CTRL>
__device__ __forceinline__ float dppmv(float v) {
    return __builtin_bit_cast(float,
        __builtin_amdgcn_update_dpp(0, __builtin_bit_cast(int, v), CTRL, 0xF, 0xF, true));
}

template<int LM>
__device__ __forceinline__ float lx(float v, int lane) {
    (void)lane;
    if constexpr (LM == 1)       return dppmv<0xB1>(v);
    else if constexpr (LM == 2)  return dppmv<0x4E>(v);
    else if constexpr (LM == 3)  return dppmv<0x1B>(v);
    else if constexpr (LM == 4)  return dppmv<0x1B>(dppmv<0x141>(v));   // 7^3
    else if constexpr (LM == 6)  return dppmv<0xB1>(dppmv<0x141>(v));   // 7^1
    else if constexpr (LM == 8)  return dppmv<0x128>(v);                // ror 8
    else if constexpr (LM == 12) return dppmv<0x1B>(dppmv<0x140>(v));   // 15^3
    else                         return __shfl_xor(v, LM);              // 16,24,32,48
}

// ---------------- gates (prefetch-then-compute) ----------------

template<int W>
__device__ __forceinline__ void g_ry(float (&re)[16], float (&im)[16], float c, float s, int lane) {
    if constexpr (W <= 5) {
        constexpr int LM = 1 << (5 - W);
        const float ss = ((lane >> (5 - W)) & 1) ? s : -s;
        float pr[16], pi[16];
#pragma unroll
        for (int r = 0; r < 16; ++r) { pr[r] = lx<LM>(re[r], lane); pi[r] = lx<LM>(im[r], lane); }
#pragma unroll
        for (int r = 0; r < 16; ++r) {
            re[r] = fmaf(ss, pr[r], c * re[r]);
            im[r] = fmaf(ss, pi[r], c * im[r]);
        }
    } else {
        constexpr int MK = 1 << (9 - W);
#pragma unroll
        for (int r = 0; r < 16; ++r) {
            if ((r & MK) == 0) {
                const int r1 = r | MK;
                float r0 = re[r], i0 = im[r], r1v = re[r1], i1 = im[r1];
                re[r]  = fmaf(-s, r1v, c * r0);
                im[r]  = fmaf(-s, i1,  c * i0);
                re[r1] = fmaf( s, r0,  c * r1v);
                im[r1] = fmaf( s, i0,  c * i1);
            }
        }
    }
}

template<int W>
__device__ __forceinline__ void g_rx(float (&re)[16], float (&im)[16], float c, float s, int lane) {
    if constexpr (W <= 5) {
        constexpr int LM = 1 << (5 - W);
        float pr[16], pi[16];
#pragma unroll
        for (int r = 0; r < 16; ++r) { pr[r] = lx<LM>(re[r], lane); pi[r] = lx<LM>(im[r], lane); }
#pragma unroll
        for (int r = 0; r < 16; ++r) {
            re[r] = fmaf( s, pi[r], c * re[r]);
            im[r] = fmaf(-s, pr[r], c * im[r]);
        }
    } else {
        constexpr int MK = 1 << (9 - W);
#pragma unroll
        for (int r = 0; r < 16; ++r) {
            if ((r & MK) == 0) {
                const int r1 = r | MK;
                float r0 = re[r], i0 = im[r], r1v = re[r1], i1 = im[r1];
                re[r]  = fmaf( s, i1,  c * r0);
                im[r]  = fmaf(-s, r1v, c * i0);
                re[r1] = fmaf( s, i0,  c * r1v);
                im[r1] = fmaf(-s, r0,  c * i1);
            }
        }
    }
}

template<int W>
__device__ __forceinline__ void g_rz(float (&re)[16], float (&im)[16], float c, float s, int lane) {
    if constexpr (W <= 5) {
        const float sp = ((lane >> (5 - W)) & 1) ? s : -s;
#pragma unroll
        for (int r = 0; r < 16; ++r) {
            float rr = re[r], ii = im[r];
            re[r] = rr * c - ii * sp;
            im[r] = ii * c + rr * sp;
        }
    } else {
        constexpr int MK = 1 << (9 - W);
#pragma unroll
        for (int r = 0; r < 16; ++r) {
            const float sp = (r & MK) ? s : -s;
            float rr = re[r], ii = im[r];
            re[r] = rr * c - ii * sp;
            im[r] = ii * c + rr * sp;
        }
    }
}

template<int C, int T>
__device__ __forceinline__ void g_crz(float (&re)[16], float (&im)[16], float c, float s, int lane) {
#pragma unroll
    for (int r = 0; r < 16; ++r) {
        const int cb = (C <= 5) ? ((lane >> (5 - C)) & 1) : ((r >> (9 - C)) & 1);
        const int tb = (T <= 5) ? ((lane >> (5 - T)) & 1) : ((r >> (9 - T)) & 1);
        const float cc  = cb ? c : 1.f;
        const float sp2 = cb ? (tb ? s : -s) : 0.f;
        float rr = re[r], ii = im[r];
        re[r] = cc * rr - sp2 * ii;
        im[r] = cc * ii + sp2 * rr;
    }
}

template<int A, int Bq, bool YY>
__device__ __forceinline__ void g_xy(float (&re)[16], float (&im)[16], float c, float s, int lane) {
    constexpr int bpA = 9 - A, bpB = 9 - Bq;
    constexpr int LM   = ((bpA >= 4) ? (1 << (bpA - 4)) : 0) | ((bpB >= 4) ? (1 << (bpB - 4)) : 0);
    constexpr int LOCM = ((bpA < 4) ? (1 << bpA) : 0) | ((bpB < 4) ? (1 << bpB) : 0);
    float pr[16], pi[16];
#pragma unroll
    for (int r = 0; r < 16; ++r) {
        float vr = re[r ^ LOCM], vi = im[r ^ LOCM];
        if constexpr (LM != 0) { pr[r] = lx<LM>(vr, lane); pi[r] = lx<LM>(vi, lane); }
        else                   { pr[r] = vr; pi[r] = vi; }
    }
#pragma unroll
    for (int r = 0; r < 16; ++r) {
        float sg;
        if constexpr (YY) {
            const int bA = (A  <= 5) ? ((lane >> (5 - A )) & 1) : ((r >> (9 - A )) & 1);
            const int bB = (Bq <= 5) ? ((lane >> (5 - Bq)) & 1) : ((r >> (9 - Bq)) & 1);
            sg = (bA == bB) ? -s : s;
        } else sg = s;
        float rr = re[r], ii = im[r];
        re[r] = fmaf( sg, pi[r], c * rr);
        im[r] = fmaf(-sg, pr[r], c * ii);
    }
}

// general 1-qubit gate U = [[u00,u01],[u10,u11]] complex, entries in U[0..7]
template<int W>
__device__ __forceinline__ void g_u1(float (&re)[16], float (&im)[16], const float* U, int lane) {
    const float u00r=U[0], u00i=U[1], u01r=U[2], u01i=U[3];
    const float u10r=U[4], u10i=U[5], u11r=U[6], u11i=U[7];
    if constexpr (W <= 5) {
        constexpr int LM = 1 << (5 - W);
        const int side = (lane >> (5 - W)) & 1;
        const float aR = side ? u11r : u00r, aI = side ? u11i : u00i;   // own coef
        const float bR = side ? u10r : u01r, bI = side ? u10i : u01i;   // partner coef
        float pr[16], pi[16];
#pragma unroll
        for (int r = 0; r < 16; ++r) { pr[r] = lx<LM>(re[r], lane); pi[r] = lx<LM>(im[r], lane); }
#pragma unroll
        for (int r = 0; r < 16; ++r) {
            float rr = re[r], ii = im[r];
            float nr = aR * rr; nr = fmaf(-aI, ii, nr); nr = fmaf(bR, pr[r], nr); nr = fmaf(-bI, pi[r], nr);
            float ni = aR * ii; ni = fmaf( aI, rr, ni); ni = fmaf(bR, pi[r], ni); ni = fmaf( bI, pr[r], ni);
            re[r] = nr; im[r] = ni;
        }
    } else {
        constexpr int MK = 1 << (9 - W);
#pragma unroll
        for (int r = 0; r < 16; ++r) {
            if ((r & MK) == 0) {
                const int r1 = r | MK;
                float r0 = re[r], i0 = im[r], r1v = re[r1], i1 = im[r1];
                float a = u00r*r0; a = fmaf(-u00i, i0, a); a = fmaf(u01r, r1v, a); a = fmaf(-u01i, i1, a);
                float b = u00r*i0; b = fmaf( u00i, r0, b); b = fmaf(u01r, i1,  b); b = fmaf( u01i, r1v, b);
                float c = u10r*r0; c = fmaf(-u10i, i0, c); c = fmaf(u11r, r1v, c); c = fmaf(-u11i, i1, c);
                float d = u10r*i0; d = fmaf( u10i, r0, d); d = fmaf(u11r, i1,  d); d = fmaf( u11i, r1v, d);
                re[r] = a; im[r] = b; re[r1] = c; im[r1] = d;
            }
        }
    }
}

// full-wave reduce (sum)
__device__ __forceinline__ float wred(float v, int lane) {
    v += lx<1>(v, lane); v += lx<2>(v, lane); v += lx<4>(v, lane);
    v += lx<8>(v, lane); v += lx<16>(v, lane); v += lx<32>(v, lane);
    return v;
}

// broadcast-style measurement (branch circuits only), prefetch-structured
template<int W>
__device__ __forceinline__ void meas_q(const float (&re)[16], const float (&im)[16], int lane,
                                       float& X, float& Y, float& Z) {
    float xa = 0.f, ya = 0.f, za = 0.f;
    if constexpr (W <= 5) {
        constexpr int LM = 1 << (5 - W);
        const float sg = ((lane >> (5 - W)) & 1) ? -1.f : 1.f;
        float pr[16], pi[16];
#pragma unroll
        for (int r = 0; r < 16; ++r) { pr[r] = lx<LM>(re[r], lane); pi[r] = lx<LM>(im[r], lane); }
#pragma unroll
        for (int r = 0; r < 16; ++r) {
            xa = fmaf(re[r], pr[r], xa); xa = fmaf(im[r], pi[r], xa);
            ya = fmaf(re[r], pi[r], ya); ya = fmaf(-im[r], pr[r], ya);
            za = fmaf(re[r], re[r], za); za = fmaf(im[r], im[r], za);
        }
        ya *= sg; za *= sg;
    } else {
        constexpr int MK = 1 << (9 - W);
#pragma unroll
        for (int r = 0; r < 16; ++r) {
            if ((r & MK) == 0) {
                const int r1 = r | MK;
                xa += 2.f * (re[r] * re[r1] + im[r] * im[r1]);
                ya += 2.f * (re[r] * im[r1] - im[r] * re[r1]);
                za += (re[r] * re[r] + im[r] * im[r]) - (re[r1] * re[r1] + im[r1] * im[r1]);
            }
        }
    }
    X = wred(xa, lane); Y = wred(ya, lane); Z = wred(za, lane);
}

__device__ __forceinline__ void init_state(float (&re)[16], float (&im)[16], int lane) {
#pragma unroll
    for (int r = 0; r < 16; ++r) { re[r] = 0.f; im[r] = 0.f; }
    if (lane == 0) re[0] = 1.f;
}

// ---------------- branch circuits, split across two waves ----------------

__device__ void branch_gating(const float* __restrict__ gb,
                              const float* __restrict__ b1,
                              const float* __restrict__ W2, const float* __restrict__ b2,
                              const float* __restrict__ w1p, const float* __restrict__ w2p,
                              const float* __restrict__ Wout, const float* __restrict__ bout,
                              float* __restrict__ ws_c, int lane) {
    float re[16], im[16];
    const bool act = lane < 30;
    const int kk = act ? lane : 0;
    float y2 = 0.f;

    init_state(re, im, lane);
    for (int L = 0; L < 2; ++L) {
        const int g0 = L * 30;
#define G_RX(i) { float s_, c_; __sincosf(0.5f * gb[g0 + i], &s_, &c_); g_rx<i>(re, im, c_, s_, lane); }
        ALLQ(G_RX)
#undef G_RX
#define G_CRZ(i) { float s_, c_; __sincosf(0.5f * gb[g0 + 10 + i], &s_, &c_); g_crz<i, i + 1>(re, im, c_, s_, lane); }
        ALLQ9(G_CRZ)
#undef G_CRZ
#define G_RY(i) { float s_, c_; __sincosf(0.5f * gb[g0 + 19 + i], &s_, &c_); g_ry<i>(re, im, c_, s_, lane); }
        ALLQ(G_RY)
#undef G_RY
        { float s_, c_; __sincosf(0.5f * gb[g0 + 29], &s_, &c_); g_crz<9, 0>(re, im, c_, s_, lane); }
    }
#define G_M2(w) { float X, Y, Z; meas_q<w>(re, im, lane, X, Y, Z); \
        y2 = fmaf(X, W2[kk * 30 + w], y2); y2 = fmaf(Y, W2[kk * 30 + 10 + w], y2); y2 = fmaf(Z, W2[kk * 30 + 20 + w], y2); }
    ALLQ(G_M2)
#undef G_M2

    const float w1v = w1p[0], w2v = w2p[0];
    float vk = act ? Wout[kk] * (w1v * b1[kk] + w2v * (b2[kk] + y2)) : 0.f;
    vk = wred(vk, lane);
    if (lane == 0) ws_c[0] = vk + bout[0];
}

__device__ void branch_skip(const float* __restrict__ sp,
                            const float* __restrict__ W3, const float* __restrict__ b3,
                            const float* __restrict__ w3p,
                            const float* __restrict__ Wout,
                            float* __restrict__ ws_c, int lane) {
    float re[16], im[16];
    const bool act = lane < 30;
    const int kk = act ? lane : 0;
    float y3 = 0.f;

    init_state(re, im, lane);
#define G_RXS(i) { float s_, c_; __sincosf(0.5f * sp[i], &s_, &c_); g_rx<i>(re, im, c_, s_, lane); }
    ALLQ(G_RXS)
#undef G_RXS
#define G_RYS(i) { float s_, c_; __sincosf(0.5f * sp[10 + i], &s_, &c_); g_ry<i>(re, im, c_, s_, lane); }
    ALLQ(G_RYS)
#undef G_RYS
#define G_RZS(i) { float s_, c_; __sincosf(0.5f * sp[20 + i], &s_, &c_); g_rz<i>(re, im, c_, s_, lane); }
    ALLQ(G_RZS)
#undef G_RZS
#define G_M3(w) { float X, Y, Z; meas_q<w>(re, im, lane, X, Y, Z); \
        y3 = fmaf(X, W3[kk * 30 + w], y3); y3 = fmaf(Y, W3[kk * 30 + 10 + w], y3); y3 = fmaf(Z, W3[kk * 30 + 20 + w], y3); }
    ALLQ(G_M3)
#undef G_M3

    const float w3v = w3p[0];
    float vk = act ? Wout[kk] * (w3v * (b3[kk] + y3)) : 0.f;
    vk = wred(vk, lane);
    if (lane == 0) ws_c[0] = vk;
}

// ---------------- main kernel ----------------
// grid = B/4 blocks of 5 waves. waves 0-3: one batch element each -> ws[b].
// wave 4: block 0 -> gating (ws[B]), block 1 -> skip (ws[B+1]), else exit.

__global__ void __launch_bounds__(TPB) k_main(
    const float* __restrict__ x, const float* __restrict__ Wp,
    const float* __restrict__ bp_, const float* __restrict__ qb,
    const float* __restrict__ bpar, const float* __restrict__ cpar, const float* __restrict__ dtpar,
    const float* __restrict__ gb, const float* __restrict__ sp,
    const float* __restrict__ W1, const float* __restrict__ b1,
    const float* __restrict__ W2, const float* __restrict__ b2,
    const float* __restrict__ W3, const float* __restrict__ b3,
    const float* __restrict__ w1p, const float* __restrict__ w2p, const float* __restrict__ w3p,
    const float* __restrict__ Wout, const float* __restrict__ bout,
    float* __restrict__ ws, int B) {

    const int wv = threadIdx.x >> 6, lane = threadIdx.x & 63;

    if (wv == 4) {
        if (blockIdx.x == 0) {
            branch_gating(gb, b1, W2, b2, w1p, w2p, Wout, bout, ws + B, lane);
            if (gridDim.x == 1) branch_skip(sp, W3, b3, w3p, Wout, ws + B + 1, lane);
        } else if (blockIdx.x == 1) {
            branch_skip(sp, W3, b3, w3p, Wout, ws + B + 1, lane);
        }
        return;
    }

    const int b = blockIdx.x * 4 + wv;
    const int bb = (b < B) ? b : (B - 1);

    // per-wave LDS only -> no barriers anywhere
    __shared__ float proj[4][80];
    __shared__ float ac1[4][10], as1[4][10], ac2[4][10], as2[4][10];
    __shared__ float gc[4][60], gs[4][60];          // [B1,CD1,E1, B2,CD2,E2]
    __shared__ float ub[4][80];                      // 10 qubits x 8 floats
    __shared__ float uraw[4][32], uu[4][32];

    // ---- projection (16-lane groups, 4 rows/pass) ----
    const int sub = lane & 15, grp = lane >> 4;
    float4 xv[4];
    {
        const float* xr = x + (size_t)bb * 256 + sub * 16;
#pragma unroll
        for (int j = 0; j < 4; ++j) xv[j] = reinterpret_cast<const float4*>(xr)[j];
    }
#pragma unroll 4
    for (int p = 0; p < 20; ++p) {
        const int row = p * 4 + grp;
        const float* wr = Wp + (size_t)row * 256 + sub * 16;
        float acc = 0.f;
#pragma unroll
        for (int j = 0; j < 4; ++j) {
            float4 w4 = reinterpret_cast<const float4*>(wr)[j];
            acc = fmaf(xv[j].x, w4.x, acc); acc = fmaf(xv[j].y, w4.y, acc);
            acc = fmaf(xv[j].z, w4.z, acc); acc = fmaf(xv[j].w, w4.w, acc);
        }
        acc += lx<1>(acc, lane); acc += lx<2>(acc, lane);
        acc += lx<4>(acc, lane); acc += lx<8>(acc, lane);
        if (sub == 0) proj[wv][row] = acc;
    }

    // ---- angle prep ----
    {
#define DO_ANGLE(IDX) { \
        const int idx = (IDX); \
        float ang = TWO_PI_F / (1.f + __expf(-(proj[wv][idx] + bp_[idx]))) + qb[idx]; \
        const int l = (idx >= 40) ? 1 : 0; \
        const int p = idx - 40 * l; \
        float s_, c_; \
        if (p < 10) { \
            __sincosf(0.5f * ang, &s_, &c_); \
            if (l == 0) { ac1[wv][p] = c_; as1[wv][p] = s_; } \
            else        { ac2[wv][p] = c_; as2[wv][p] = s_; } \
        } else if (p < 20) { \
            __sincosf(0.5f * ang, &s_, &c_); \
            gc[wv][l * 30 + p - 10] = c_; gs[wv][l * 30 + p - 10] = s_; \
        } else if (p < 30) { \
            __sincosf(0.5f * (ang + bpar[p - 20]), &s_, &c_); \
            gc[wv][l * 30 + 10 + p - 20] = c_; gs[wv][l * 30 + 10 + p - 20] = s_; \
        } else { \
            __sincosf(0.5f * ang, &s_, &c_); \
            gc[wv][l * 30 + 20 + p - 30] = c_; gs[wv][l * 30 + 20 + p - 30] = s_; \
        } }
        DO_ANGLE(lane)
        if (lane < 16) DO_ANGLE(64 + lane)
#undef DO_ANGLE

        if (lane < 30) {
            float ut = 0.f;
            for (int k = 0; k < 30; ++k) ut = fmaf(Wout[k], W1[k * 30 + lane], ut);
            uraw[wv][lane] = w1p[0] * ut;
        }
        if (lane < 10) {
            // U_bnd = Ry(alpha) Rx(dt) Rz(c), half-angle sincos
            float ca = ac2[wv][lane], sa = as2[wv][lane];
            float cg2, sg2, cd2, sd2;
            __sincosf(0.5f * cpar[lane],  &sg2, &cg2);
            __sincosf(0.5f * dtpar[lane], &sd2, &cd2);
            float A = ca * cd2, Bv = sa * sd2;
            float C = -sa * cd2, D = -ca * sd2;
            float E = sa * cd2,  F = -ca * sd2;
            float G = ca * cd2,  H = -sa * sd2;
            float* U = &ub[wv][lane * 8];
            U[0] = cg2 * A + sg2 * Bv;  U[1] = cg2 * Bv - sg2 * A;   // U00
            U[2] = cg2 * C - sg2 * D;   U[3] = sg2 * C + cg2 * D;    // U01
            U[4] = cg2 * E + sg2 * F;   U[5] = cg2 * F - sg2 * E;    // U10
            U[6] = cg2 * G - sg2 * H;   U[7] = sg2 * G + cg2 * H;    // U11

            // u' = Bloch rotation of fold vector (full angles)
            float cg, sgf, cd, sdf;
            __sincosf(cpar[lane],  &sgf, &cg);
            __sincosf(dtpar[lane], &sdf, &cd);
            float uX = uraw[wv][lane], uY = uraw[wv][10 + lane], uZ = uraw[wv][20 + lane];
            uu[wv][lane]      =  uX * cg + uY * cd * sgf + uZ * sdf * sgf;
            uu[wv][10 + lane] = -uX * sgf + uY * cd * cg + uZ * sdf * cg;
            uu[wv][20 + lane] = -uY * sdf + uZ * cd;
        }
    }

    // ---- product initial state: amp(s) = prod_i (bit_i ? sin : cos) ----
    float re[16], im[16];
    {
        const float* AC = ac1[wv]; const float* AS = as1[wv];
        float pl = ((lane >> 5) & 1) ? AS[0] : AC[0];
        pl *= ((lane >> 4) & 1) ? AS[1] : AC[1];
        pl *= ((lane >> 3) & 1) ? AS[2] : AC[2];
        pl *= ((lane >> 2) & 1) ? AS[3] : AC[3];
        pl *= ((lane >> 1) & 1) ? AS[4] : AC[4];
        pl *= ( lane       & 1) ? AS[5] : AC[5];
#pragma unroll
        for (int r = 0; r < 16; ++r) {
            float p = ((r >> 3) & 1) ? AS[6] : AC[6];
            p *= ((r >> 2) & 1) ? AS[7] : AC[7];
            p *= ((r >> 1) & 1) ? AS[8] : AC[8];
            p *= ( r       & 1) ? AS[9] : AC[9];
            re[r] = pl * p; im[r] = 0.f;
        }
    }

    // ---- fused circuit ----
    const float* GC = gc[wv]; const float* GS = gs[wv];
#define G_XX1(i) g_xy<i, (i + 1) % 10, false>(re, im, GC[i], GS[i], lane);
    ALLQ(G_XX1)
#undef G_XX1
#define G_CD1(i) g_ry<i>(re, im, GC[10 + i], GS[10 + i], lane);
    ALLQ(G_CD1)
#undef G_CD1
#define G_YY1(i) g_xy<i, (i + 1) % 10, true>(re, im, GC[20 + i], GS[20 + i], lane);
    ALLQ(G_YY1)
#undef G_YY1
#define G_UB(i) g_u1<i>(re, im, &ub[wv][i * 8], lane);
    ALLQ(G_UB)
#undef G_UB
#define G_XX2(i) g_xy<i, (i + 1) % 10, false>(re, im, GC[30 + i], GS[30 + i], lane);
    ALLQ(G_XX2)
#undef G_XX2
#define G_CD2(i) g_ry<i>(re, im, GC[40 + i], GS[40 + i], lane);
    ALLQ(G_CD2)
#undef G_CD2
#define G_YY2(i) g_xy<i, (i + 1) % 10, true>(re, im, GC[50 + i], GS[50 + i], lane);
    ALLQ(G_YY2)
#undef G_YY2

    // ---- measurement: per-lane partial of sum_w (X_w u'_w + Y_w u'_{10+w} + Z_w u'_{20+w}) ----
    float n2[16], n2s = 0.f;
#pragma unroll
    for (int r = 0; r < 16; ++r) { n2[r] = fmaf(re[r], re[r], im[r] * im[r]); n2s += n2[r]; }

    const float* U = uu[wv];
    float oacc = 0.f;

#define M_LANE(w, LM_) { \
        float pr[16], pi[16]; \
        _Pragma("unroll") \
        for (int r = 0; r < 16; ++r) { pr[r] = lx<LM_>(re[r], lane); pi[r] = lx<LM_>(im[r], lane); } \
        float xa = 0.f, ya = 0.f; \
        _Pragma("unroll") \
        for (int r = 0; r < 16; ++r) { \
            xa = fmaf(re[r], pr[r], xa); xa = fmaf(im[r], pi[r], xa); \
            ya = fmaf(re[r], pi[r], ya); ya = fmaf(-im[r], pr[r], ya); \
        } \
        const float sg = ((lane >> (5 - w)) & 1) ? -1.f : 1.f; \
        oacc = fmaf(xa, U[w], oacc); \
        oacc = fmaf(sg * ya, U[10 + w], oacc); \
        oacc = fmaf(sg * n2s, U[20 + w], oacc); }
    M_LANE(0, 32) M_LANE(1, 16) M_LANE(2, 8) M_LANE(3, 4) M_LANE(4, 2) M_LANE(5, 1)
#undef M_LANE

#define M_REG(w, MK) { \
        float xa = 0.f, ya = 0.f, za = 0.f; \
        _Pragma("unroll") \
        for (int r = 0; r < 16; ++r) { \
            if ((r & MK) == 0) { \
                const int r1 = r | MK; \
                xa = fmaf(re[r], re[r1], xa); xa = fmaf(im[r], im[r1], xa); \
                ya = fmaf(re[r], im[r1], ya); ya = fmaf(-im[r], re[r1], ya); \
                za += n2[r] - n2[r1]; \
            } } \
        oacc = fmaf(2.f * xa, U[w], oacc); \
        oacc = fmaf(2.f * ya, U[10 + w], oacc); \
        oacc = fmaf(za, U[20 + w], oacc); }
    M_REG(6, 8) M_REG(7, 4) M_REG(8, 2) M_REG(9, 1)
#undef M_REG

    oacc = wred(oacc, lane);
    if (lane == 0 && b < B) ws[b] = oacc;
}

__global__ void k_out(const float* __restrict__ ws, float* __restrict__ out, int B) {
    int i = blockIdx.x * blockDim.x + threadIdx.x;
    if (i < B) out[i] = ws[i] + ws[B] + ws[B + 1];
}

extern "C" void kernel_launch(void* const* d_in, const int* in_sizes, int n_in,
                              void* d_out, int out_size, void* d_ws, size_t ws_size,
                              hipStream_t stream) {
    const float* x         = (const float*)d_in[0];
    const float* W_proj    = (const float*)d_in[1];
    const float* b_proj    = (const float*)d_in[2];
    const float* qlcu_base = (const float*)d_in[3];
    const float* gate_base = (const float*)d_in[4];
    const float* skip_base = (const float*)d_in[5];
    const float* b_params  = (const float*)d_in[6];
    const float* c_params  = (const float*)d_in[7];
    const float* dt_params = (const float*)d_in[8];
    const float* W1    = (const float*)d_in[9];
    const float* b1    = (const float*)d_in[10];
    const float* W2    = (const float*)d_in[11];
    const float* b2    = (const float*)d_in[12];
    const float* W3    = (const float*)d_in[13];
    const float* b3    = (const float*)d_in[14];
    const float* w1    = (const float*)d_in[15];
    const float* w2    = (const float*)d_in[16];
    const float* w3    = (const float*)d_in[17];
    const float* W_out = (const float*)d_in[18];
    const float* b_out = (const float*)d_in[19];
    float* out = (float*)d_out;
    float* ws  = (float*)d_ws;

    const int B = in_sizes[0] / 256;   // FEATURE_DIM = 256
    const int nb = (B + 3) / 4;        // 512 for B=2048 (exact)

    hipLaunchKernelGGL(k_main, dim3(nb), dim3(TPB), 0, stream,
                       x, W_proj, b_proj, qlcu_base, b_params, c_params, dt_params,
                       gate_base, skip_base, W1, b1, W2, b2, W3, b3, w1, w2, w3,
                       W_out, b_out, ws, B);
    hipLaunchKernelGGL(k_out, dim3((B + 255) / 256), dim3(256), 0, stream, ws, out, B);
}

// Round 11
// 55.865 us; speedup vs baseline: 4.6999x; 1.0053x over previous
//
#include <hip/hip_runtime.h>
#include <math.h>

#define TPB 320
#define TWO_PI_F 6.283185307179586f

// State layout: one wave (64 lanes) holds 1024 amplitudes.
// s = (lane << 4) | r,  r = 0..15 in registers re[16], im[16].
// Qubit w -> state bit (9-w).  w <= 5: lane bit (5-w).  w >= 6: local bit (9-w).
// DS-heavy qubits 0,1 (lane masks 32,16): their gates are pair-FUSED so each
// layer has ONE batched DS phase instead of two/three serialized ones.

#define ALLQ(OP) OP(0) OP(1) OP(2) OP(3) OP(4) OP(5) OP(6) OP(7) OP(8) OP(9)
#define ALLQ9(OP) OP(0) OP(1) OP(2) OP(3) OP(4) OP(5) OP(6) OP(7) OP(8)

template<int CTRL>
__device__ __forceinline__ float dppmv(float v) {
    return __builtin_bit_cast(float,
        __builtin_amdgcn_update_dpp(0, __builtin_bit_cast(int, v), CTRL, 0xF, 0xF, true));
}

template<int LM>
__device__ __forceinline__ float lx(float v, int lane) {
    (void)lane;
    if constexpr (LM == 1)       return dppmv<0xB1>(v);
    else if constexpr (LM == 2)  return dppmv<0x4E>(v);
    else if constexpr (LM == 3)  return dppmv<0x1B>(v);
    else if constexpr (LM == 4)  return dppmv<0x1B>(dppmv<0x141>(v));   // 7^3
    else if constexpr (LM == 6)  return dppmv<0xB1>(dppmv<0x141>(v));   // 7^1
    else if constexpr (LM == 8)  return dppmv<0x128>(v);                // ror 8
    else if constexpr (LM == 12) return dppmv<0x1B>(dppmv<0x140>(v));   // 15^3
    else                         return __shfl_xor(v, LM);              // 16,24,32,48,56
}

// ---------------- single gates (prefetch-then-compute) ----------------

template<int W>
__device__ __forceinline__ void g_ry(float (&re)[16], float (&im)[16], float c, float s, int lane) {
    if constexpr (W <= 5) {
        constexpr int LM = 1 << (5 - W);
        const float ss = ((lane >> (5 - W)) & 1) ? s : -s;
        float pr[16], pi[16];
#pragma unroll
        for (int r = 0; r < 16; ++r) { pr[r] = lx<LM>(re[r], lane); pi[r] = lx<LM>(im[r], lane); }
#pragma unroll
        for (int r = 0; r < 16; ++r) {
            re[r] = fmaf(ss, pr[r], c * re[r]);
            im[r] = fmaf(ss, pi[r], c * im[r]);
        }
    } else {
        constexpr int MK = 1 << (9 - W);
#pragma unroll
        for (int r = 0; r < 16; ++r) {
            if ((r & MK) == 0) {
                const int r1 = r | MK;
                float r0 = re[r], i0 = im[r], r1v = re[r1], i1 = im[r1];
                re[r]  = fmaf(-s, r1v, c * r0);
                im[r]  = fmaf(-s, i1,  c * i0);
                re[r1] = fmaf( s, r0,  c * r1v);
                im[r1] = fmaf( s, i0,  c * i1);
            }
        }
    }
}

template<int W>
__device__ __forceinline__ void g_rx(float (&re)[16], float (&im)[16], float c, float s, int lane) {
    if constexpr (W <= 5) {
        constexpr int LM = 1 << (5 - W);
        float pr[16], pi[16];
#pragma unroll
        for (int r = 0; r < 16; ++r) { pr[r] = lx<LM>(re[r], lane); pi[r] = lx<LM>(im[r], lane); }
#pragma unroll
        for (int r = 0; r < 16; ++r) {
            re[r] = fmaf( s, pi[r], c * re[r]);
            im[r] = fmaf(-s, pr[r], c * im[r]);
        }
    } else {
        constexpr int MK = 1 << (9 - W);
#pragma unroll
        for (int r = 0; r < 16; ++r) {
            if ((r & MK) == 0) {
                const int r1 = r | MK;
                float r0 = re[r], i0 = im[r], r1v = re[r1], i1 = im[r1];
                re[r]  = fmaf( s, i1,  c * r0);
                im[r]  = fmaf(-s, r1v, c * i0);
                re[r1] = fmaf( s, i0,  c * r1v);
                im[r1] = fmaf(-s, r0,  c * i1);
            }
        }
    }
}

template<int W>
__device__ __forceinline__ void g_rz(float (&re)[16], float (&im)[16], float c, float s, int lane) {
    if constexpr (W <= 5) {
        const float sp = ((lane >> (5 - W)) & 1) ? s : -s;
#pragma unroll
        for (int r = 0; r < 16; ++r) {
            float rr = re[r], ii = im[r];
            re[r] = rr * c - ii * sp;
            im[r] = ii * c + rr * sp;
        }
    } else {
        constexpr int MK = 1 << (9 - W);
#pragma unroll
        for (int r = 0; r < 16; ++r) {
            const float sp = (r & MK) ? s : -s;
            float rr = re[r], ii = im[r];
            re[r] = rr * c - ii * sp;
            im[r] = ii * c + rr * sp;
        }
    }
}

template<int C, int T>
__device__ __forceinline__ void g_crz(float (&re)[16], float (&im)[16], float c, float s, int lane) {
#pragma unroll
    for (int r = 0; r < 16; ++r) {
        const int cb = (C <= 5) ? ((lane >> (5 - C)) & 1) : ((r >> (9 - C)) & 1);
        const int tb = (T <= 5) ? ((lane >> (5 - T)) & 1) : ((r >> (9 - T)) & 1);
        const float cc  = cb ? c : 1.f;
        const float sp2 = cb ? (tb ? s : -s) : 0.f;
        float rr = re[r], ii = im[r];
        re[r] = cc * rr - sp2 * ii;
        im[r] = cc * ii + sp2 * rr;
    }
}

template<int A, int Bq, bool YY>
__device__ __forceinline__ void g_xy(float (&re)[16], float (&im)[16], float c, float s, int lane) {
    constexpr int bpA = 9 - A, bpB = 9 - Bq;
    constexpr int LM   = ((bpA >= 4) ? (1 << (bpA - 4)) : 0) | ((bpB >= 4) ? (1 << (bpB - 4)) : 0);
    constexpr int LOCM = ((bpA < 4) ? (1 << bpA) : 0) | ((bpB < 4) ? (1 << bpB) : 0);
    float pr[16], pi[16];
#pragma unroll
    for (int r = 0; r < 16; ++r) {
        float vr = re[r ^ LOCM], vi = im[r ^ LOCM];
        if constexpr (LM != 0) { pr[r] = lx<LM>(vr, lane); pi[r] = lx<LM>(vi, lane); }
        else                   { pr[r] = vr; pi[r] = vi; }
    }
#pragma unroll
    for (int r = 0; r < 16; ++r) {
        float sg;
        if constexpr (YY) {
            const int bA = (A  <= 5) ? ((lane >> (5 - A )) & 1) : ((r >> (9 - A )) & 1);
            const int bB = (Bq <= 5) ? ((lane >> (5 - Bq)) & 1) : ((r >> (9 - Bq)) & 1);
            sg = (bA == bB) ? -s : s;
        } else sg = s;
        float rr = re[r], ii = im[r];
        re[r] = fmaf( sg, pi[r], c * rr);
        im[r] = fmaf(-sg, pr[r], c * ii);
    }
}

// general 1-qubit gate U = [[u00,u01],[u10,u11]] complex, entries in U[0..7]
template<int W>
__device__ __forceinline__ void g_u1(float (&re)[16], float (&im)[16], const float* U, int lane) {
    const float u00r=U[0], u00i=U[1], u01r=U[2], u01i=U[3];
    const float u10r=U[4], u10i=U[5], u11r=U[6], u11i=U[7];
    if constexpr (W <= 5) {
        constexpr int LM = 1 << (5 - W);
        const int side = (lane >> (5 - W)) & 1;
        const float aR = side ? u11r : u00r, aI = side ? u11i : u00i;
        const float bR = side ? u10r : u01r, bI = side ? u10i : u01i;
        float pr[16], pi[16];
#pragma unroll
        for (int r = 0; r < 16; ++r) { pr[r] = lx<LM>(re[r], lane); pi[r] = lx<LM>(im[r], lane); }
#pragma unroll
        for (int r = 0; r < 16; ++r) {
            float rr = re[r], ii = im[r];
            float nr = aR * rr; nr = fmaf(-aI, ii, nr); nr = fmaf(bR, pr[r], nr); nr = fmaf(-bI, pi[r], nr);
            float ni = aR * ii; ni = fmaf( aI, rr, ni); ni = fmaf(bR, pi[r], ni); ni = fmaf( bI, pr[r], ni);
            re[r] = nr; im[r] = ni;
        }
    } else {
        constexpr int MK = 1 << (9 - W);
#pragma unroll
        for (int r = 0; r < 16; ++r) {
            if ((r & MK) == 0) {
                const int r1 = r | MK;
                float r0 = re[r], i0 = im[r], r1v = re[r1], i1 = im[r1];
                float a = u00r*r0; a = fmaf(-u00i, i0, a); a = fmaf(u01r, r1v, a); a = fmaf(-u01i, i1, a);
                float b = u00r*i0; b = fmaf( u00i, r0, b); b = fmaf(u01r, i1,  b); b = fmaf( u01i, r1v, b);
                float c = u10r*r0; c = fmaf(-u10i, i0, c); c = fmaf(u11r, r1v, c); c = fmaf(-u11i, i1, c);
                float d = u10r*i0; d = fmaf( u10i, r0, d); d = fmaf(u11r, i1,  d); d = fmaf( u11i, r1v, d);
                re[r] = a; im[r] = b; re[r1] = c; im[r1] = d;
            }
        }
    }
}

// ---------------- fused pair gates (single batched DS phase) ----------------

// ry(q0) ⊗ ry(q1): masks 32, 16, 48 (all lane, LOCM 0). Real coefficients.
__device__ __forceinline__ void g_ry2_01(float (&re)[16], float (&im)[16],
                                         float c0, float s0, float c1, float s1, int lane) {
    float ar[16], ai[16], br[16], bi[16], cr2[16], ci2[16];
#pragma unroll
    for (int r = 0; r < 16; ++r) { ar[r] = lx<32>(re[r], lane); ai[r] = lx<32>(im[r], lane); }
#pragma unroll
    for (int r = 0; r < 16; ++r) { br[r] = lx<16>(re[r], lane); bi[r] = lx<16>(im[r], lane); }
#pragma unroll
    for (int r = 0; r < 16; ++r) { cr2[r] = lx<48>(re[r], lane); ci2[r] = lx<48>(im[r], lane); }
    const float sg0 = ((lane >> 5) & 1) ? s0 : -s0;
    const float sg1 = ((lane >> 4) & 1) ? s1 : -s1;
    const float k0 = c0 * c1, k1 = c1 * sg0, k2 = c0 * sg1, k3 = sg0 * sg1;
#pragma unroll
    for (int r = 0; r < 16; ++r) {
        float o_r = k0 * re[r];
        o_r = fmaf(k1, ar[r], o_r); o_r = fmaf(k2, br[r], o_r); o_r = fmaf(k3, cr2[r], o_r);
        float o_i = k0 * im[r];
        o_i = fmaf(k1, ai[r], o_i); o_i = fmaf(k2, bi[r], o_i); o_i = fmaf(k3, ci2[r], o_i);
        re[r] = o_r; im[r] = o_i;
    }
}

// U0(q0) ⊗ U1(q1), complex general gates; masks 16, 32, 48.
__device__ __forceinline__ void g_u2_01(float (&re)[16], float (&im)[16],
                                        const float* U0, const float* U1, int lane) {
    const int b0 = (lane >> 5) & 1, b1 = (lane >> 4) & 1;
    const float u0o_r = U0[(b0*2+b0)*2],       u0o_i = U0[(b0*2+b0)*2+1];
    const float u0f_r = U0[(b0*2+(b0^1))*2],   u0f_i = U0[(b0*2+(b0^1))*2+1];
    const float u1o_r = U1[(b1*2+b1)*2],       u1o_i = U1[(b1*2+b1)*2+1];
    const float u1f_r = U1[(b1*2+(b1^1))*2],   u1f_i = U1[(b1*2+(b1^1))*2+1];
    const float K00r = u0o_r*u1o_r - u0o_i*u1o_i, K00i = u0o_r*u1o_i + u0o_i*u1o_r;
    const float K01r = u0o_r*u1f_r - u0o_i*u1f_i, K01i = u0o_r*u1f_i + u0o_i*u1f_r;
    const float K10r = u0f_r*u1o_r - u0f_i*u1o_i, K10i = u0f_r*u1o_i + u0f_i*u1o_r;
    const float K11r = u0f_r*u1f_r - u0f_i*u1f_i, K11i = u0f_r*u1f_i + u0f_i*u1f_r;
    float ar[16], ai[16], br[16], bi[16], cr2[16], ci2[16];
#pragma unroll
    for (int r = 0; r < 16; ++r) { ar[r] = lx<32>(re[r], lane); ai[r] = lx<32>(im[r], lane); }
#pragma unroll
    for (int r = 0; r < 16; ++r) { br[r] = lx<16>(re[r], lane); bi[r] = lx<16>(im[r], lane); }
#pragma unroll
    for (int r = 0; r < 16; ++r) { cr2[r] = lx<48>(re[r], lane); ci2[r] = lx<48>(im[r], lane); }
#pragma unroll
    for (int r = 0; r < 16; ++r) {
        float rr = re[r], ii = im[r];
        float o_r = K00r * rr;         o_r = fmaf(-K00i, ii, o_r);
        o_r = fmaf(K01r, br[r], o_r);  o_r = fmaf(-K01i, bi[r], o_r);
        o_r = fmaf(K10r, ar[r], o_r);  o_r = fmaf(-K10i, ai[r], o_r);
        o_r = fmaf(K11r, cr2[r], o_r); o_r = fmaf(-K11i, ci2[r], o_r);
        float o_i = K00r * ii;         o_i = fmaf(K00i, rr, o_i);
        o_i = fmaf(K01r, bi[r], o_i);  o_i = fmaf(K01i, br[r], o_i);
        o_i = fmaf(K10r, ai[r], o_i);  o_i = fmaf(K10i, ar[r], o_i);
        o_i = fmaf(K11r, ci2[r], o_i); o_i = fmaf(K11i, cr2[r], o_i);
        re[r] = o_r; im[r] = o_i;
    }
}

// fused ring pair: gate a = XY(1,2) [LM 24], gate b = XY(9,0) [LM 32, LOCM 1].
// (G_b G_a v)[s] = ca cb v - i cb sa σa p_a - i ca sb σb p_b - sa sb σa σb p_ab
__device__ __forceinline__ void g_ring2(float (&re)[16], float (&im)[16],
                                        float ca, float sa, float cb, float sb,
                                        bool yy, int lane) {
    float ar[16], ai[16], br[16], bi[16], cr2[16], ci2[16];
#pragma unroll
    for (int r = 0; r < 16; ++r) { ar[r] = lx<24>(re[r], lane); ai[r] = lx<24>(im[r], lane); }
#pragma unroll
    for (int r = 0; r < 16; ++r) { br[r] = lx<32>(re[r ^ 1], lane); bi[r] = lx<32>(im[r ^ 1], lane); }
#pragma unroll
    for (int r = 0; r < 16; ++r) { cr2[r] = lx<56>(re[r ^ 1], lane); ci2[r] = lx<56>(im[r ^ 1], lane); }
    float ka, kb0, kb1, kab0, kab1;
    if (yy) {
        const bool ea = (((lane >> 4) & 1) == ((lane >> 3) & 1));
        const float sga = ea ? -sa : sa;
        const int b0l = (lane >> 5) & 1;
        const float sgb0 = (0 == b0l) ? -sb : sb;   // r&1 == 0
        const float sgb1 = (1 == b0l) ? -sb : sb;   // r&1 == 1
        ka = cb * sga; kb0 = ca * sgb0; kb1 = ca * sgb1;
        kab0 = sga * sgb0; kab1 = sga * sgb1;
    } else {
        ka = cb * sa; kb0 = kb1 = ca * sb; kab0 = kab1 = sa * sb;
    }
    const float k0 = ca * cb;
#pragma unroll
    for (int r = 0; r < 16; ++r) {
        const float kb  = (r & 1) ? kb1  : kb0;
        const float kab = (r & 1) ? kab1 : kab0;
        float rr = re[r], ii = im[r];
        float o_r = k0 * rr;
        o_r = fmaf(ka, ai[r], o_r); o_r = fmaf(kb, bi[r], o_r); o_r = fmaf(-kab, cr2[r], o_r);
        float o_i = k0 * ii;
        o_i = fmaf(-ka, ar[r], o_i); o_i = fmaf(-kb, br[r], o_i); o_i = fmaf(-kab, ci2[r], o_i);
        re[r] = o_r; im[r] = o_i;
    }
}

// full-wave reduce (sum)
__device__ __forceinline__ float wred(float v, int lane) {
    v += lx<1>(v, lane); v += lx<2>(v, lane); v += lx<4>(v, lane);
    v += lx<8>(v, lane); v += lx<16>(v, lane); v += lx<32>(v, lane);
    return v;
}

// broadcast-style measurement (branch circuits only)
template<int W>
__device__ __forceinline__ void meas_q(const float (&re)[16], const float (&im)[16], int lane,
                                       float& X, float& Y, float& Z) {
    float xa = 0.f, ya = 0.f, za = 0.f;
    if constexpr (W <= 5) {
        constexpr int LM = 1 << (5 - W);
        const float sg = ((lane >> (5 - W)) & 1) ? -1.f : 1.f;
        float pr[16], pi[16];
#pragma unroll
        for (int r = 0; r < 16; ++r) { pr[r] = lx<LM>(re[r], lane); pi[r] = lx<LM>(im[r], lane); }
#pragma unroll
        for (int r = 0; r < 16; ++r) {
            xa = fmaf(re[r], pr[r], xa); xa = fmaf(im[r], pi[r], xa);
            ya = fmaf(re[r], pi[r], ya); ya = fmaf(-im[r], pr[r], ya);
            za = fmaf(re[r], re[r], za); za = fmaf(im[r], im[r], za);
        }
        ya *= sg; za *= sg;
    } else {
        constexpr int MK = 1 << (9 - W);
#pragma unroll
        for (int r = 0; r < 16; ++r) {
            if ((r & MK) == 0) {
                const int r1 = r | MK;
                xa += 2.f * (re[r] * re[r1] + im[r] * im[r1]);
                ya += 2.f * (re[r] * im[r1] - im[r] * re[r1]);
                za += (re[r] * re[r] + im[r] * im[r]) - (re[r1] * re[r1] + im[r1] * im[r1]);
            }
        }
    }
    X = wred(xa, lane); Y = wred(ya, lane); Z = wred(za, lane);
}

__device__ __forceinline__ void init_state(float (&re)[16], float (&im)[16], int lane) {
#pragma unroll
    for (int r = 0; r < 16; ++r) { re[r] = 0.f; im[r] = 0.f; }
    if (lane == 0) re[0] = 1.f;
}

// ---------------- branch circuits, split across two waves ----------------

__device__ void branch_gating(const float* __restrict__ gb,
                              const float* __restrict__ b1,
                              const float* __restrict__ W2, const float* __restrict__ b2,
                              const float* __restrict__ w1p, const float* __restrict__ w2p,
                              const float* __restrict__ Wout, const float* __restrict__ bout,
                              float* __restrict__ ws_c, int lane) {
    float re[16], im[16];
    const bool act = lane < 30;
    const int kk = act ? lane : 0;
    float y2 = 0.f;

    init_state(re, im, lane);
    for (int L = 0; L < 2; ++L) {
        const int g0 = L * 30;
#define G_RX(i) { float s_, c_; __sincosf(0.5f * gb[g0 + i], &s_, &c_); g_rx<i>(re, im, c_, s_, lane); }
        ALLQ(G_RX)
#undef G_RX
#define G_CRZ(i) { float s_, c_; __sincosf(0.5f * gb[g0 + 10 + i], &s_, &c_); g_crz<i, i + 1>(re, im, c_, s_, lane); }
        ALLQ9(G_CRZ)
#undef G_CRZ
#define G_RY(i) { float s_, c_; __sincosf(0.5f * gb[g0 + 19 + i], &s_, &c_); g_ry<i>(re, im, c_, s_, lane); }
        ALLQ(G_RY)
#undef G_RY
        { float s_, c_; __sincosf(0.5f * gb[g0 + 29], &s_, &c_); g_crz<9, 0>(re, im, c_, s_, lane); }
    }
#define G_M2(w) { float X, Y, Z; meas_q<w>(re, im, lane, X, Y, Z); \
        y2 = fmaf(X, W2[kk * 30 + w], y2); y2 = fmaf(Y, W2[kk * 30 + 10 + w], y2); y2 = fmaf(Z, W2[kk * 30 + 20 + w], y2); }
    ALLQ(G_M2)
#undef G_M2

    const float w1v = w1p[0], w2v = w2p[0];
    float vk = act ? Wout[kk] * (w1v * b1[kk] + w2v * (b2[kk] + y2)) : 0.f;
    vk = wred(vk, lane);
    if (lane == 0) ws_c[0] = vk + bout[0];
}

__device__ void branch_skip(const float* __restrict__ sp,
                            const float* __restrict__ W3, const float* __restrict__ b3,
                            const float* __restrict__ w3p,
                            const float* __restrict__ Wout,
                            float* __restrict__ ws_c, int lane) {
    float re[16], im[16];
    const bool act = lane < 30;
    const int kk = act ? lane : 0;
    float y3 = 0.f;

    init_state(re, im, lane);
#define G_RXS(i) { float s_, c_; __sincosf(0.5f * sp[i], &s_, &c_); g_rx<i>(re, im, c_, s_, lane); }
    ALLQ(G_RXS)
#undef G_RXS
#define G_RYS(i) { float s_, c_; __sincosf(0.5f * sp[10 + i], &s_, &c_); g_ry<i>(re, im, c_, s_, lane); }
    ALLQ(G_RYS)
#undef G_RYS
#define G_RZS(i) { float s_, c_; __sincosf(0.5f * sp[20 + i], &s_, &c_); g_rz<i>(re, im, c_, s_, lane); }
    ALLQ(G_RZS)
#undef G_RZS
#define G_M3(w) { float X, Y, Z; meas_q<w>(re, im, lane, X, Y, Z); \
        y3 = fmaf(X, W3[kk * 30 + w], y3); y3 = fmaf(Y, W3[kk * 30 + 10 + w], y3); y3 = fmaf(Z, W3[kk * 30 + 20 + w], y3); }
    ALLQ(G_M3)
#undef G_M3

    const float w3v = w3p[0];
    float vk = act ? Wout[kk] * (w3v * (b3[kk] + y3)) : 0.f;
    vk = wred(vk, lane);
    if (lane == 0) ws_c[0] = vk;
}

// ---------------- main kernel ----------------

__global__ void __launch_bounds__(TPB) k_main(
    const float* __restrict__ x, const float* __restrict__ Wp,
    const float* __restrict__ bp_, const float* __restrict__ qb,
    const float* __restrict__ bpar, const float* __restrict__ cpar, const float* __restrict__ dtpar,
    const float* __restrict__ gb, const float* __restrict__ sp,
    const float* __restrict__ W1, const float* __restrict__ b1,
    const float* __restrict__ W2, const float* __restrict__ b2,
    const float* __restrict__ W3, const float* __restrict__ b3,
    const float* __restrict__ w1p, const float* __restrict__ w2p, const float* __restrict__ w3p,
    const float* __restrict__ Wout, const float* __restrict__ bout,
    float* __restrict__ ws, int B) {

    const int wv = threadIdx.x >> 6, lane = threadIdx.x & 63;

    if (wv == 4) {
        if (blockIdx.x == 0) {
            branch_gating(gb, b1, W2, b2, w1p, w2p, Wout, bout, ws + B, lane);
            if (gridDim.x == 1) branch_skip(sp, W3, b3, w3p, Wout, ws + B + 1, lane);
        } else if (blockIdx.x == 1) {
            branch_skip(sp, W3, b3, w3p, Wout, ws + B + 1, lane);
        }
        return;
    }

    const int b = blockIdx.x * 4 + wv;
    const int bb = (b < B) ? b : (B - 1);

    __shared__ float proj[4][80];
    __shared__ float ac1[4][10], as1[4][10], ac2[4][10], as2[4][10];
    __shared__ float gc[4][60], gs[4][60];          // [B1,CD1,E1, B2,CD2,E2]
    __shared__ float ub[4][80];                      // 10 qubits x 8 floats
    __shared__ float uraw[4][32], uu[4][32];

    // ---- projection (16-lane groups, 4 rows/pass) ----
    const int sub = lane & 15, grp = lane >> 4;
    float4 xv[4];
    {
        const float* xr = x + (size_t)bb * 256 + sub * 16;
#pragma unroll
        for (int j = 0; j < 4; ++j) xv[j] = reinterpret_cast<const float4*>(xr)[j];
    }
#pragma unroll 4
    for (int p = 0; p < 20; ++p) {
        const int row = p * 4 + grp;
        const float* wr = Wp + (size_t)row * 256 + sub * 16;
        float acc = 0.f;
#pragma unroll
        for (int j = 0; j < 4; ++j) {
            float4 w4 = reinterpret_cast<const float4*>(wr)[j];
            acc = fmaf(xv[j].x, w4.x, acc); acc = fmaf(xv[j].y, w4.y, acc);
            acc = fmaf(xv[j].z, w4.z, acc); acc = fmaf(xv[j].w, w4.w, acc);
        }
        acc += lx<1>(acc, lane); acc += lx<2>(acc, lane);
        acc += lx<4>(acc, lane); acc += lx<8>(acc, lane);
        if (sub == 0) proj[wv][row] = acc;
    }

    // ---- angle prep ----
    {
#define DO_ANGLE(IDX) { \
        const int idx = (IDX); \
        float ang = TWO_PI_F / (1.f + __expf(-(proj[wv][idx] + bp_[idx]))) + qb[idx]; \
        const int l = (idx >= 40) ? 1 : 0; \
        const int p = idx - 40 * l; \
        float s_, c_; \
        if (p < 10) { \
            __sincosf(0.5f * ang, &s_, &c_); \
            if (l == 0) { ac1[wv][p] = c_; as1[wv][p] = s_; } \
            else        { ac2[wv][p] = c_; as2[wv][p] = s_; } \
        } else if (p < 20) { \
            __sincosf(0.5f * ang, &s_, &c_); \
            gc[wv][l * 30 + p - 10] = c_; gs[wv][l * 30 + p - 10] = s_; \
        } else if (p < 30) { \
            __sincosf(0.5f * (ang + bpar[p - 20]), &s_, &c_); \
            gc[wv][l * 30 + 10 + p - 20] = c_; gs[wv][l * 30 + 10 + p - 20] = s_; \
        } else { \
            __sincosf(0.5f * ang, &s_, &c_); \
            gc[wv][l * 30 + 20 + p - 30] = c_; gs[wv][l * 30 + 20 + p - 30] = s_; \
        } }
        DO_ANGLE(lane)
        if (lane < 16) DO_ANGLE(64 + lane)
#undef DO_ANGLE

        if (lane < 30) {
            float ut = 0.f;
            for (int k = 0; k < 30; ++k) ut = fmaf(Wout[k], W1[k * 30 + lane], ut);
            uraw[wv][lane] = w1p[0] * ut;
        }
        if (lane < 10) {
            float ca = ac2[wv][lane], sa = as2[wv][lane];
            float cg2, sg2, cd2, sd2;
            __sincosf(0.5f * cpar[lane],  &sg2, &cg2);
            __sincosf(0.5f * dtpar[lane], &sd2, &cd2);
            float A = ca * cd2, Bv = sa * sd2;
            float C = -sa * cd2, D = -ca * sd2;
            float E = sa * cd2,  F = -ca * sd2;
            float G = ca * cd2,  H = -sa * sd2;
            float* U = &ub[wv][lane * 8];
            U[0] = cg2 * A + sg2 * Bv;  U[1] = cg2 * Bv - sg2 * A;
            U[2] = cg2 * C - sg2 * D;   U[3] = sg2 * C + cg2 * D;
            U[4] = cg2 * E + sg2 * F;   U[5] = cg2 * F - sg2 * E;
            U[6] = cg2 * G - sg2 * H;   U[7] = sg2 * G + cg2 * H;

            float cg, sgf, cd, sdf;
            __sincosf(cpar[lane],  &sgf, &cg);
            __sincosf(dtpar[lane], &sdf, &cd);
            float uX = uraw[wv][lane], uY = uraw[wv][10 + lane], uZ = uraw[wv][20 + lane];
            uu[wv][lane]      =  uX * cg + uY * cd * sgf + uZ * sdf * sgf;
            uu[wv][10 + lane] = -uX * sgf + uY * cd * cg + uZ * sdf * cg;
            uu[wv][20 + lane] = -uY * sdf + uZ * cd;
        }
    }

    // ---- product initial state ----
    float re[16], im[16];
    {
        const float* AC = ac1[wv]; const float* AS = as1[wv];
        float pl = ((lane >> 5) & 1) ? AS[0] : AC[0];
        pl *= ((lane >> 4) & 1) ? AS[1] : AC[1];
        pl *= ((lane >> 3) & 1) ? AS[2] : AC[2];
        pl *= ((lane >> 2) & 1) ? AS[3] : AC[3];
        pl *= ((lane >> 1) & 1) ? AS[4] : AC[4];
        pl *= ( lane       & 1) ? AS[5] : AC[5];
#pragma unroll
        for (int r = 0; r < 16; ++r) {
            float p = ((r >> 3) & 1) ? AS[6] : AC[6];
            p *= ((r >> 2) & 1) ? AS[7] : AC[7];
            p *= ((r >> 1) & 1) ? AS[8] : AC[8];
            p *= ( r       & 1) ? AS[9] : AC[9];
            re[r] = pl * p; im[r] = 0.f;
        }
    }

    // ---- fused circuit ----
    // Ring layers: all XX (resp. YY) gates commute -> reorder exactly:
    // fused{(1,2),(9,0)} first (one DS phase), cheap middles, then (0,1).
    const float* GC = gc[wv]; const float* GS = gs[wv];

#define RING(base, YYf) \
    g_ring2(re, im, GC[(base)+1], GS[(base)+1], GC[(base)+9], GS[(base)+9], YYf, lane); \
    g_xy<2, 3, YYf>(re, im, GC[(base)+2], GS[(base)+2], lane); \
    g_xy<3, 4, YYf>(re, im, GC[(base)+3], GS[(base)+3], lane); \
    g_xy<4, 5, YYf>(re, im, GC[(base)+4], GS[(base)+4], lane); \
    g_xy<5, 6, YYf>(re, im, GC[(base)+5], GS[(base)+5], lane); \
    g_xy<6, 7, YYf>(re, im, GC[(base)+6], GS[(base)+6], lane); \
    g_xy<7, 8, YYf>(re, im, GC[(base)+7], GS[(base)+7], lane); \
    g_xy<8, 9, YYf>(re, im, GC[(base)+8], GS[(base)+8], lane); \
    g_xy<0, 1, YYf>(re, im, GC[(base)+0], GS[(base)+0], lane);

    // layer 1
    RING(0, false)                                        // XX1
    g_ry2_01(re, im, GC[10], GS[10], GC[11], GS[11], lane);  // CD1 q0,q1 fused
#define G_CD1(i) g_ry<i>(re, im, GC[10 + i], GS[10 + i], lane);
    G_CD1(2) G_CD1(3) G_CD1(4) G_CD1(5) G_CD1(6) G_CD1(7) G_CD1(8) G_CD1(9)
#undef G_CD1
    RING(20, true)                                        // YY1
    // boundary U layer: q0,q1 fused, rest single
    g_u2_01(re, im, &ub[wv][0], &ub[wv][8], lane);
#define G_UB(i) g_u1<i>(re, im, &ub[wv][i * 8], lane);
    G_UB(2) G_UB(3) G_UB(4) G_UB(5) G_UB(6) G_UB(7) G_UB(8) G_UB(9)
#undef G_UB
    // layer 2
    RING(30, false)                                       // XX2
    g_ry2_01(re, im, GC[40], GS[40], GC[41], GS[41], lane);  // CD2 q0,q1 fused
#define G_CD2(i) g_ry<i>(re, im, GC[40 + i], GS[40 + i], lane);
    G_CD2(2) G_CD2(3) G_CD2(4) G_CD2(5) G_CD2(6) G_CD2(7) G_CD2(8) G_CD2(9)
#undef G_CD2
    RING(50, true)                                        // YY2
#undef RING

    // ---- measurement ----
    const float* U = uu[wv];
    float oacc = 0.f;

    // prefetch the two DS-heavy measurement exchanges first (state is read-only)
    float q0r[16], q0i[16], q1r[16], q1i[16];
#pragma unroll
    for (int r = 0; r < 16; ++r) { q0r[r] = lx<32>(re[r], lane); q0i[r] = lx<32>(im[r], lane); }
#pragma unroll
    for (int r = 0; r < 16; ++r) { q1r[r] = lx<16>(re[r], lane); q1i[r] = lx<16>(im[r], lane); }

    float n2[16], n2s = 0.f;
#pragma unroll
    for (int r = 0; r < 16; ++r) { n2[r] = fmaf(re[r], re[r], im[r] * im[r]); n2s += n2[r]; }

#define M_LANE(w, LM_) { \
        float pr[16], pi[16]; \
        _Pragma("unroll") \
        for (int r = 0; r < 16; ++r) { pr[r] = lx<LM_>(re[r], lane); pi[r] = lx<LM_>(im[r], lane); } \
        float xa = 0.f, ya = 0.f; \
        _Pragma("unroll") \
        for (int r = 0; r < 16; ++r) { \
            xa = fmaf(re[r], pr[r], xa); xa = fmaf(im[r], pi[r], xa); \
            ya = fmaf(re[r], pi[r], ya); ya = fmaf(-im[r], pr[r], ya); \
        } \
        const float sg = ((lane >> (5 - w)) & 1) ? -1.f : 1.f; \
        oacc = fmaf(xa, U[w], oacc); \
        oacc = fmaf(sg * ya, U[10 + w], oacc); \
        oacc = fmaf(sg * n2s, U[20 + w], oacc); }
    M_LANE(2, 8) M_LANE(3, 4) M_LANE(4, 2) M_LANE(5, 1)
#undef M_LANE

#define M_REG(w, MK) { \
        float xa = 0.f, ya = 0.f, za = 0.f; \
        _Pragma("unroll") \
        for (int r = 0; r < 16; ++r) { \
            if ((r & MK) == 0) { \
                const int r1 = r | MK; \
                xa = fmaf(re[r], re[r1], xa); xa = fmaf(im[r], im[r1], xa); \
                ya = fmaf(re[r], im[r1], ya); ya = fmaf(-im[r], re[r1], ya); \
                za += n2[r] - n2[r1]; \
            } } \
        oacc = fmaf(2.f * xa, U[w], oacc); \
        oacc = fmaf(2.f * ya, U[10 + w], oacc); \
        oacc = fmaf(za, U[20 + w], oacc); }
    M_REG(6, 8) M_REG(7, 4) M_REG(8, 2) M_REG(9, 1)
#undef M_REG

    // consume the prefetched w=0 (mask 32, sign bit5) and w=1 (mask 16, sign bit4)
    {
        float xa = 0.f, ya = 0.f;
#pragma unroll
        for (int r = 0; r < 16; ++r) {
            xa = fmaf(re[r], q0r[r], xa); xa = fmaf(im[r], q0i[r], xa);
            ya = fmaf(re[r], q0i[r], ya); ya = fmaf(-im[r], q0r[r], ya);
        }
        const float sg = ((lane >> 5) & 1) ? -1.f : 1.f;
        oacc = fmaf(xa, U[0], oacc);
        oacc = fmaf(sg * ya, U[10], oacc);
        oacc = fmaf(sg * n2s, U[20], oacc);
    }
    {
        float xa = 0.f, ya = 0.f;
#pragma unroll
        for (int r = 0; r < 16; ++r) {
            xa = fmaf(re[r], q1r[r], xa); xa = fmaf(im[r], q1i[r], xa);
            ya = fmaf(re[r], q1i[r], ya); ya = fmaf(-im[r], q1r[r], ya);
        }
        const float sg = ((lane >> 4) & 1) ? -1.f : 1.f;
        oacc = fmaf(xa, U[1], oacc);
        oacc = fmaf(sg * ya, U[11], oacc);
        oacc = fmaf(sg * n2s, U[21], oacc);
    }

    oacc = wred(oacc, lane);
    if (lane == 0 && b < B) ws[b] = oacc;
}

__global__ void k_out(const float* __restrict__ ws, float* __restrict__ out, int B) {
    int i = blockIdx.x * blockDim.x + threadIdx.x;
    if (i < B) out[i] = ws[i] + ws[B] + ws[B + 1];
}

extern "C" void kernel_launch(void* const* d_in, const int* in_sizes, int n_in,
                              void* d_out, int out_size, void* d_ws, size_t ws_size,
                              hipStream_t stream) {
    const float* x         = (const float*)d_in[0];
    const float* W_proj    = (const float*)d_in[1];
    const float* b_proj    = (const float*)d_in[2];
    const float* qlcu_base = (const float*)d_in[3];
    const float* gate_base = (const float*)d_in[4];
    const float* skip_base = (const float*)d_in[5];
    const float* b_params  = (const float*)d_in[6];
    const float* c_params  = (const float*)d_in[7];
    const float* dt_params = (const float*)d_in[8];
    const float* W1    = (const float*)d_in[9];
    const float* b1    = (const float*)d_in[10];
    const float* W2    = (const float*)d_in[11];
    const float* b2    = (const float*)d_in[12];
    const float* W3    = (const float*)d_in[13];
    const float* b3    = (const float*)d_in[14];
    const float* w1    = (const float*)d_in[15];
    const float* w2    = (const float*)d_in[16];
    const float* w3    = (const float*)d_in[17];
    const float* W_out = (const float*)d_in[18];
    const float* b_out = (const float*)d_in[19];
    float* out = (float*)d_out;
    float* ws  = (float*)d_ws;

    const int B = in_sizes[0] / 256;   // FEATURE_DIM = 256
    const int nb = (B + 3) / 4;        // 512 for B=2048 (exact)

    hipLaunchKernelGGL(k_main, dim3(nb), dim3(TPB), 0, stream,
                       x, W_proj, b_proj, qlcu_base, b_params, c_params, dt_params,
                       gate_base, skip_base, W1, b1, W2, b2, W3, b3, w1, w2, w3,
                       W_out, b_out, ws, B);
    hipLaunchKernelGGL(k_out, dim3((B + 255) / 256), dim3(256), 0, stream, ws, out, B);
}

// Round 12
// 48.594 us; speedup vs baseline: 5.4032x; 1.1496x over previous
//
#include <hip/hip_runtime.h>
#include <math.h>

#define TPB 320
#define TWO_PI_F 6.283185307179586f

// State layout: one wave (64 lanes) holds 1024 amplitudes.
// s = (lane << 4) | r,  r = 0..15 in registers re[16], im[16].
// Qubit w -> state bit (9-w).  w <= 5: lane bit (5-w).  w >= 6: local bit (9-w).

#define ALLQ(OP) OP(0) OP(1) OP(2) OP(3) OP(4) OP(5) OP(6) OP(7) OP(8) OP(9)
#define ALLQ9(OP) OP(0) OP(1) OP(2) OP(3) OP(4) OP(5) OP(6) OP(7) OP(8)

template<int CTRL>
__device__ __forceinline__ float dppmv(float v) {
    return __builtin_bit_cast(float,
        __builtin_amdgcn_update_dpp(0, __builtin_bit_cast(int, v), CTRL, 0xF, 0xF, true));
}

template<int LM>
__device__ __forceinline__ float lx(float v, int lane) {
    (void)lane;
    if constexpr (LM == 1)       return dppmv<0xB1>(v);
    else if constexpr (LM == 2)  return dppmv<0x4E>(v);
    else if constexpr (LM == 3)  return dppmv<0x1B>(v);
    else if constexpr (LM == 4)  return dppmv<0x1B>(dppmv<0x141>(v));   // 7^3
    else if constexpr (LM == 6)  return dppmv<0xB1>(dppmv<0x141>(v));   // 7^1
    else if constexpr (LM == 8)  return dppmv<0x128>(v);                // ror 8
    else if constexpr (LM == 12) return dppmv<0x1B>(dppmv<0x140>(v));   // 15^3
    else                         return __shfl_xor(v, LM);              // 16,24,32,48,56
}

// ---------------- single gates (prefetch-then-compute) ----------------

template<int W>
__device__ __forceinline__ void g_ry(float (&re)[16], float (&im)[16], float c, float s, int lane) {
    if constexpr (W <= 5) {
        constexpr int LM = 1 << (5 - W);
        const float ss = ((lane >> (5 - W)) & 1) ? s : -s;
        float pr[16], pi[16];
#pragma unroll
        for (int r = 0; r < 16; ++r) { pr[r] = lx<LM>(re[r], lane); pi[r] = lx<LM>(im[r], lane); }
#pragma unroll
        for (int r = 0; r < 16; ++r) {
            re[r] = fmaf(ss, pr[r], c * re[r]);
            im[r] = fmaf(ss, pi[r], c * im[r]);
        }
    } else {
        constexpr int MK = 1 << (9 - W);
#pragma unroll
        for (int r = 0; r < 16; ++r) {
            if ((r & MK) == 0) {
                const int r1 = r | MK;
                float r0 = re[r], i0 = im[r], r1v = re[r1], i1 = im[r1];
                re[r]  = fmaf(-s, r1v, c * r0);
                im[r]  = fmaf(-s, i1,  c * i0);
                re[r1] = fmaf( s, r0,  c * r1v);
                im[r1] = fmaf( s, i0,  c * i1);
            }
        }
    }
}

template<int W>
__device__ __forceinline__ void g_rx(float (&re)[16], float (&im)[16], float c, float s, int lane) {
    if constexpr (W <= 5) {
        constexpr int LM = 1 << (5 - W);
        float pr[16], pi[16];
#pragma unroll
        for (int r = 0; r < 16; ++r) { pr[r] = lx<LM>(re[r], lane); pi[r] = lx<LM>(im[r], lane); }
#pragma unroll
        for (int r = 0; r < 16; ++r) {
            re[r] = fmaf( s, pi[r], c * re[r]);
            im[r] = fmaf(-s, pr[r], c * im[r]);
        }
    } else {
        constexpr int MK = 1 << (9 - W);
#pragma unroll
        for (int r = 0; r < 16; ++r) {
            if ((r & MK) == 0) {
                const int r1 = r | MK;
                float r0 = re[r], i0 = im[r], r1v = re[r1], i1 = im[r1];
                re[r]  = fmaf( s, i1,  c * r0);
                im[r]  = fmaf(-s, r1v, c * i0);
                re[r1] = fmaf( s, i0,  c * r1v);
                im[r1] = fmaf(-s, r0,  c * i1);
            }
        }
    }
}

template<int W>
__device__ __forceinline__ void g_rz(float (&re)[16], float (&im)[16], float c, float s, int lane) {
    if constexpr (W <= 5) {
        const float sp = ((lane >> (5 - W)) & 1) ? s : -s;
#pragma unroll
        for (int r = 0; r < 16; ++r) {
            float rr = re[r], ii = im[r];
            re[r] = rr * c - ii * sp;
            im[r] = ii * c + rr * sp;
        }
    } else {
        constexpr int MK = 1 << (9 - W);
#pragma unroll
        for (int r = 0; r < 16; ++r) {
            const float sp = (r & MK) ? s : -s;
            float rr = re[r], ii = im[r];
            re[r] = rr * c - ii * sp;
            im[r] = ii * c + rr * sp;
        }
    }
}

template<int C, int T>
__device__ __forceinline__ void g_crz(float (&re)[16], float (&im)[16], float c, float s, int lane) {
#pragma unroll
    for (int r = 0; r < 16; ++r) {
        const int cb = (C <= 5) ? ((lane >> (5 - C)) & 1) : ((r >> (9 - C)) & 1);
        const int tb = (T <= 5) ? ((lane >> (5 - T)) & 1) : ((r >> (9 - T)) & 1);
        const float cc  = cb ? c : 1.f;
        const float sp2 = cb ? (tb ? s : -s) : 0.f;
        float rr = re[r], ii = im[r];
        re[r] = cc * rr - sp2 * ii;
        im[r] = cc * ii + sp2 * rr;
    }
}

template<int A, int Bq, bool YY>
__device__ __forceinline__ void g_xy(float (&re)[16], float (&im)[16], float c, float s, int lane) {
    constexpr int bpA = 9 - A, bpB = 9 - Bq;
    constexpr int LM   = ((bpA >= 4) ? (1 << (bpA - 4)) : 0) | ((bpB >= 4) ? (1 << (bpB - 4)) : 0);
    constexpr int LOCM = ((bpA < 4) ? (1 << bpA) : 0) | ((bpB < 4) ? (1 << bpB) : 0);
    float pr[16], pi[16];
#pragma unroll
    for (int r = 0; r < 16; ++r) {
        float vr = re[r ^ LOCM], vi = im[r ^ LOCM];
        if constexpr (LM != 0) { pr[r] = lx<LM>(vr, lane); pi[r] = lx<LM>(vi, lane); }
        else                   { pr[r] = vr; pi[r] = vi; }
    }
#pragma unroll
    for (int r = 0; r < 16; ++r) {
        float sg;
        if constexpr (YY) {
            const int bA = (A  <= 5) ? ((lane >> (5 - A )) & 1) : ((r >> (9 - A )) & 1);
            const int bB = (Bq <= 5) ? ((lane >> (5 - Bq)) & 1) : ((r >> (9 - Bq)) & 1);
            sg = (bA == bB) ? -s : s;
        } else sg = s;
        float rr = re[r], ii = im[r];
        re[r] = fmaf( sg, pi[r], c * rr);
        im[r] = fmaf(-sg, pr[r], c * ii);
    }
}

// general 1-qubit gate U = [[u00,u01],[u10,u11]] complex, entries in U[0..7]
template<int W>
__device__ __forceinline__ void g_u1(float (&re)[16], float (&im)[16], const float* U, int lane) {
    const float u00r=U[0], u00i=U[1], u01r=U[2], u01i=U[3];
    const float u10r=U[4], u10i=U[5], u11r=U[6], u11i=U[7];
    if constexpr (W <= 5) {
        constexpr int LM = 1 << (5 - W);
        const int side = (lane >> (5 - W)) & 1;
        const float aR = side ? u11r : u00r, aI = side ? u11i : u00i;
        const float bR = side ? u10r : u01r, bI = side ? u10i : u01i;
        float pr[16], pi[16];
#pragma unroll
        for (int r = 0; r < 16; ++r) { pr[r] = lx<LM>(re[r], lane); pi[r] = lx<LM>(im[r], lane); }
#pragma unroll
        for (int r = 0; r < 16; ++r) {
            float rr = re[r], ii = im[r];
            float nr = aR * rr; nr = fmaf(-aI, ii, nr); nr = fmaf(bR, pr[r], nr); nr = fmaf(-bI, pi[r], nr);
            float ni = aR * ii; ni = fmaf( aI, rr, ni); ni = fmaf(bR, pi[r], ni); ni = fmaf( bI, pr[r], ni);
            re[r] = nr; im[r] = ni;
        }
    } else {
        constexpr int MK = 1 << (9 - W);
#pragma unroll
        for (int r = 0; r < 16; ++r) {
            if ((r & MK) == 0) {
                const int r1 = r | MK;
                float r0 = re[r], i0 = im[r], r1v = re[r1], i1 = im[r1];
                float a = u00r*r0; a = fmaf(-u00i, i0, a); a = fmaf(u01r, r1v, a); a = fmaf(-u01i, i1, a);
                float b = u00r*i0; b = fmaf( u00i, r0, b); b = fmaf(u01r, i1,  b); b = fmaf( u01i, r1v, b);
                float c = u10r*r0; c = fmaf(-u10i, i0, c); c = fmaf(u11r, r1v, c); c = fmaf(-u11i, i1, c);
                float d = u10r*i0; d = fmaf( u10i, r0, d); d = fmaf(u11r, i1,  d); d = fmaf( u11i, r1v, d);
                re[r] = a; im[r] = b; re[r1] = c; im[r1] = d;
            }
        }
    }
}

// ---------------- fused pair gates ----------------

// ry(q0) ⊗ ry(q1): masks 32, 16, 48. Real coefficients.
__device__ __forceinline__ void g_ry2_01(float (&re)[16], float (&im)[16],
                                         float c0, float s0, float c1, float s1, int lane) {
    float ar[16], ai[16], br[16], bi[16], cr2[16], ci2[16];
#pragma unroll
    for (int r = 0; r < 16; ++r) { ar[r] = lx<32>(re[r], lane); ai[r] = lx<32>(im[r], lane); }
#pragma unroll
    for (int r = 0; r < 16; ++r) { br[r] = lx<16>(re[r], lane); bi[r] = lx<16>(im[r], lane); }
#pragma unroll
    for (int r = 0; r < 16; ++r) { cr2[r] = lx<48>(re[r], lane); ci2[r] = lx<48>(im[r], lane); }
    const float sg0 = ((lane >> 5) & 1) ? s0 : -s0;
    const float sg1 = ((lane >> 4) & 1) ? s1 : -s1;
    const float k0 = c0 * c1, k1 = c1 * sg0, k2 = c0 * sg1, k3 = sg0 * sg1;
#pragma unroll
    for (int r = 0; r < 16; ++r) {
        float o_r = k0 * re[r];
        o_r = fmaf(k1, ar[r], o_r); o_r = fmaf(k2, br[r], o_r); o_r = fmaf(k3, cr2[r], o_r);
        float o_i = k0 * im[r];
        o_i = fmaf(k1, ai[r], o_i); o_i = fmaf(k2, bi[r], o_i); o_i = fmaf(k3, ci2[r], o_i);
        re[r] = o_r; im[r] = o_i;
    }
}

// rx(q0) ⊗ rx(q1): v'' = c0c1 v - i c1 s0 p32 - i c0 s1 p16 - s0 s1 p48
__device__ __forceinline__ void g_rx2_01(float (&re)[16], float (&im)[16],
                                         float c0, float s0, float c1, float s1, int lane) {
    float ar[16], ai[16], br[16], bi[16], cr2[16], ci2[16];
#pragma unroll
    for (int r = 0; r < 16; ++r) { ar[r] = lx<32>(re[r], lane); ai[r] = lx<32>(im[r], lane); }
#pragma unroll
    for (int r = 0; r < 16; ++r) { br[r] = lx<16>(re[r], lane); bi[r] = lx<16>(im[r], lane); }
#pragma unroll
    for (int r = 0; r < 16; ++r) { cr2[r] = lx<48>(re[r], lane); ci2[r] = lx<48>(im[r], lane); }
    const float k0 = c0 * c1, kA = c1 * s0, kB = c0 * s1, kC = s0 * s1;
#pragma unroll
    for (int r = 0; r < 16; ++r) {
        float rr = re[r], ii = im[r];
        float o_r = k0 * rr;
        o_r = fmaf(kA, ai[r], o_r); o_r = fmaf(kB, bi[r], o_r); o_r = fmaf(-kC, cr2[r], o_r);
        float o_i = k0 * ii;
        o_i = fmaf(-kA, ar[r], o_i); o_i = fmaf(-kB, br[r], o_i); o_i = fmaf(-kC, ci2[r], o_i);
        re[r] = o_r; im[r] = o_i;
    }
}

// U0(q0) ⊗ U1(q1), complex general gates; masks 16, 32, 48.
__device__ __forceinline__ void g_u2_01(float (&re)[16], float (&im)[16],
                                        const float* U0, const float* U1, int lane) {
    const int b0 = (lane >> 5) & 1, b1 = (lane >> 4) & 1;
    const float u0o_r = U0[(b0*2+b0)*2],       u0o_i = U0[(b0*2+b0)*2+1];
    const float u0f_r = U0[(b0*2+(b0^1))*2],   u0f_i = U0[(b0*2+(b0^1))*2+1];
    const float u1o_r = U1[(b1*2+b1)*2],       u1o_i = U1[(b1*2+b1)*2+1];
    const float u1f_r = U1[(b1*2+(b1^1))*2],   u1f_i = U1[(b1*2+(b1^1))*2+1];
    const float K00r = u0o_r*u1o_r - u0o_i*u1o_i, K00i = u0o_r*u1o_i + u0o_i*u1o_r;
    const float K01r = u0o_r*u1f_r - u0o_i*u1f_i, K01i = u0o_r*u1f_i + u0o_i*u1f_r;
    const float K10r = u0f_r*u1o_r - u0f_i*u1o_i, K10i = u0f_r*u1o_i + u0f_i*u1o_r;
    const float K11r = u0f_r*u1f_r - u0f_i*u1f_i, K11i = u0f_r*u1f_i + u0f_i*u1f_r;
    float ar[16], ai[16], br[16], bi[16], cr2[16], ci2[16];
#pragma unroll
    for (int r = 0; r < 16; ++r) { ar[r] = lx<32>(re[r], lane); ai[r] = lx<32>(im[r], lane); }
#pragma unroll
    for (int r = 0; r < 16; ++r) { br[r] = lx<16>(re[r], lane); bi[r] = lx<16>(im[r], lane); }
#pragma unroll
    for (int r = 0; r < 16; ++r) { cr2[r] = lx<48>(re[r], lane); ci2[r] = lx<48>(im[r], lane); }
#pragma unroll
    for (int r = 0; r < 16; ++r) {
        float rr = re[r], ii = im[r];
        float o_r = K00r * rr;         o_r = fmaf(-K00i, ii, o_r);
        o_r = fmaf(K01r, br[r], o_r);  o_r = fmaf(-K01i, bi[r], o_r);
        o_r = fmaf(K10r, ar[r], o_r);  o_r = fmaf(-K10i, ai[r], o_r);
        o_r = fmaf(K11r, cr2[r], o_r); o_r = fmaf(-K11i, ci2[r], o_r);
        float o_i = K00r * ii;         o_i = fmaf(K00i, rr, o_i);
        o_i = fmaf(K01r, bi[r], o_i);  o_i = fmaf(K01i, br[r], o_i);
        o_i = fmaf(K10r, ai[r], o_i);  o_i = fmaf(K10i, ar[r], o_i);
        o_i = fmaf(K11r, ci2[r], o_i); o_i = fmaf(K11i, cr2[r], o_i);
        re[r] = o_r; im[r] = o_i;
    }
}

// fused ring pair: gate a = XY(1,2) [LM 24], gate b = XY(9,0) [LM 32, LOCM 1].
__device__ __forceinline__ void g_ring2(float (&re)[16], float (&im)[16],
                                        float ca, float sa, float cb, float sb,
                                        bool yy, int lane) {
    float ar[16], ai[16], br[16], bi[16], cr2[16], ci2[16];
#pragma unroll
    for (int r = 0; r < 16; ++r) { ar[r] = lx<24>(re[r], lane); ai[r] = lx<24>(im[r], lane); }
#pragma unroll
    for (int r = 0; r < 16; ++r) { br[r] = lx<32>(re[r ^ 1], lane); bi[r] = lx<32>(im[r ^ 1], lane); }
#pragma unroll
    for (int r = 0; r < 16; ++r) { cr2[r] = lx<56>(re[r ^ 1], lane); ci2[r] = lx<56>(im[r ^ 1], lane); }
    float ka, kb0, kb1, kab0, kab1;
    if (yy) {
        const bool ea = (((lane >> 4) & 1) == ((lane >> 3) & 1));
        const float sga = ea ? -sa : sa;
        const int b0l = (lane >> 5) & 1;
        const float sgb0 = (0 == b0l) ? -sb : sb;
        const float sgb1 = (1 == b0l) ? -sb : sb;
        ka = cb * sga; kb0 = ca * sgb0; kb1 = ca * sgb1;
        kab0 = sga * sgb0; kab1 = sga * sgb1;
    } else {
        ka = cb * sa; kb0 = kb1 = ca * sb; kab0 = kab1 = sa * sb;
    }
    const float k0 = ca * cb;
#pragma unroll
    for (int r = 0; r < 16; ++r) {
        const float kb  = (r & 1) ? kb1  : kb0;
        const float kab = (r & 1) ? kab1 : kab0;
        float rr = re[r], ii = im[r];
        float o_r = k0 * rr;
        o_r = fmaf(ka, ai[r], o_r); o_r = fmaf(kb, bi[r], o_r); o_r = fmaf(-kab, cr2[r], o_r);
        float o_i = k0 * ii;
        o_i = fmaf(-ka, ar[r], o_i); o_i = fmaf(-kb, br[r], o_i); o_i = fmaf(-kab, ci2[r], o_i);
        re[r] = o_r; im[r] = o_i;
    }
}

// full-wave reduce (sum)
__device__ __forceinline__ float wred(float v, int lane) {
    v += lx<1>(v, lane); v += lx<2>(v, lane); v += lx<4>(v, lane);
    v += lx<8>(v, lane); v += lx<16>(v, lane); v += lx<32>(v, lane);
    return v;
}

// ---------------- folded measurement (shared by main + gating) ----------------
// returns per-lane partial of sum_w (X_w V[w] + Y_w V[10+w] + Z_w V[20+w]);
// caller wreds.
__device__ float meas_fold(const float (&re)[16], const float (&im)[16],
                           const float* __restrict__ V, int lane) {
    float oacc = 0.f;
    float q0r[16], q0i[16], q1r[16], q1i[16];
#pragma unroll
    for (int r = 0; r < 16; ++r) { q0r[r] = lx<32>(re[r], lane); q0i[r] = lx<32>(im[r], lane); }
#pragma unroll
    for (int r = 0; r < 16; ++r) { q1r[r] = lx<16>(re[r], lane); q1i[r] = lx<16>(im[r], lane); }

    float n2[16], n2s = 0.f;
#pragma unroll
    for (int r = 0; r < 16; ++r) { n2[r] = fmaf(re[r], re[r], im[r] * im[r]); n2s += n2[r]; }

#define M_LANE(w, LM_) { \
        float pr[16], pi[16]; \
        _Pragma("unroll") \
        for (int r = 0; r < 16; ++r) { pr[r] = lx<LM_>(re[r], lane); pi[r] = lx<LM_>(im[r], lane); } \
        float xa = 0.f, ya = 0.f; \
        _Pragma("unroll") \
        for (int r = 0; r < 16; ++r) { \
            xa = fmaf(re[r], pr[r], xa); xa = fmaf(im[r], pi[r], xa); \
            ya = fmaf(re[r], pi[r], ya); ya = fmaf(-im[r], pr[r], ya); \
        } \
        const float sg = ((lane >> (5 - w)) & 1) ? -1.f : 1.f; \
        oacc = fmaf(xa, V[w], oacc); \
        oacc = fmaf(sg * ya, V[10 + w], oacc); \
        oacc = fmaf(sg * n2s, V[20 + w], oacc); }
    M_LANE(2, 8) M_LANE(3, 4) M_LANE(4, 2) M_LANE(5, 1)
#undef M_LANE

#define M_REG(w, MK) { \
        float xa = 0.f, ya = 0.f, za = 0.f; \
        _Pragma("unroll") \
        for (int r = 0; r < 16; ++r) { \
            if ((r & MK) == 0) { \
                const int r1 = r | MK; \
                xa = fmaf(re[r], re[r1], xa); xa = fmaf(im[r], im[r1], xa); \
                ya = fmaf(re[r], im[r1], ya); ya = fmaf(-im[r], re[r1], ya); \
                za += n2[r] - n2[r1]; \
            } } \
        oacc = fmaf(2.f * xa, V[w], oacc); \
        oacc = fmaf(2.f * ya, V[10 + w], oacc); \
        oacc = fmaf(za, V[20 + w], oacc); }
    M_REG(6, 8) M_REG(7, 4) M_REG(8, 2) M_REG(9, 1)
#undef M_REG

    {
        float xa = 0.f, ya = 0.f;
#pragma unroll
        for (int r = 0; r < 16; ++r) {
            xa = fmaf(re[r], q0r[r], xa); xa = fmaf(im[r], q0i[r], xa);
            ya = fmaf(re[r], q0i[r], ya); ya = fmaf(-im[r], q0r[r], ya);
        }
        const float sg = ((lane >> 5) & 1) ? -1.f : 1.f;
        oacc = fmaf(xa, V[0], oacc);
        oacc = fmaf(sg * ya, V[10], oacc);
        oacc = fmaf(sg * n2s, V[20], oacc);
    }
    {
        float xa = 0.f, ya = 0.f;
#pragma unroll
        for (int r = 0; r < 16; ++r) {
            xa = fmaf(re[r], q1r[r], xa); xa = fmaf(im[r], q1i[r], xa);
            ya = fmaf(re[r], q1i[r], ya); ya = fmaf(-im[r], q1r[r], ya);
        }
        const float sg = ((lane >> 4) & 1) ? -1.f : 1.f;
        oacc = fmaf(xa, V[1], oacc);
        oacc = fmaf(sg * ya, V[11], oacc);
        oacc = fmaf(sg * n2s, V[21], oacc);
    }
    return oacc;
}

__device__ __forceinline__ void init_state(float (&re)[16], float (&im)[16], int lane) {
#pragma unroll
    for (int r = 0; r < 16; ++r) { re[r] = 0.f; im[r] = 0.f; }
    if (lane == 0) re[0] = 1.f;
}

// ---------------- branch circuits ----------------
// gating: state sim (fused q0/q1 pairs) + folded measurement, ONE wred.
__device__ void branch_gating(const float* __restrict__ gb,
                              const float* __restrict__ b1,
                              const float* __restrict__ W2, const float* __restrict__ b2,
                              const float* __restrict__ w1p, const float* __restrict__ w2p,
                              const float* __restrict__ Wout, const float* __restrict__ bout,
                              float* __restrict__ vbr, float* __restrict__ ws_c, int lane) {
    const float w1v = w1p[0], w2v = w2p[0];
    float bias = 0.f;
    if (lane < 30) {
        float v = 0.f;
        for (int k = 0; k < 30; ++k) v = fmaf(Wout[k], W2[k * 30 + lane], v);
        vbr[lane] = w2v * v;
        bias = Wout[lane] * (w1v * b1[lane] + w2v * b2[lane]);
    }

    float re[16], im[16];
    init_state(re, im, lane);
    for (int L = 0; L < 2; ++L) {
        const int g0 = L * 30;
        {
            float c0_, s0_, c1_, s1_;
            __sincosf(0.5f * gb[g0 + 0], &s0_, &c0_);
            __sincosf(0.5f * gb[g0 + 1], &s1_, &c1_);
            g_rx2_01(re, im, c0_, s0_, c1_, s1_, lane);
        }
#define BRX(i) { float s_, c_; __sincosf(0.5f * gb[g0 + i], &s_, &c_); g_rx<i>(re, im, c_, s_, lane); }
        BRX(2) BRX(3) BRX(4) BRX(5) BRX(6) BRX(7) BRX(8) BRX(9)
#undef BRX
#define BCRZ(i) { float s_, c_; __sincosf(0.5f * gb[g0 + 10 + i], &s_, &c_); g_crz<i, i + 1>(re, im, c_, s_, lane); }
        ALLQ9(BCRZ)
#undef BCRZ
        {
            float c0_, s0_, c1_, s1_;
            __sincosf(0.5f * gb[g0 + 19 + 0], &s0_, &c0_);
            __sincosf(0.5f * gb[g0 + 19 + 1], &s1_, &c1_);
            g_ry2_01(re, im, c0_, s0_, c1_, s1_, lane);
        }
#define BRY(i) { float s_, c_; __sincosf(0.5f * gb[g0 + 19 + i], &s_, &c_); g_ry<i>(re, im, c_, s_, lane); }
        BRY(2) BRY(3) BRY(4) BRY(5) BRY(6) BRY(7) BRY(8) BRY(9)
#undef BRY
        { float s_, c_; __sincosf(0.5f * gb[g0 + 29], &s_, &c_); g_crz<9, 0>(re, im, c_, s_, lane); }
    }

    float oacc = meas_fold(re, im, vbr, lane) + bias;
    oacc = wred(oacc, lane);
    if (lane == 0) ws_c[0] = oacc + bout[0];
}

// skip circuit: rx-ry-rz only -> PRODUCT STATE, closed form per qubit.
__device__ void branch_skip(const float* __restrict__ sp,
                            const float* __restrict__ W3, const float* __restrict__ b3v,
                            const float* __restrict__ w3p,
                            const float* __restrict__ Wout,
                            float* __restrict__ ws_c, int lane) {
    float vk = 0.f;
    if (lane < 30) {
        const int q = (lane < 10) ? lane : ((lane < 20) ? lane - 10 : lane - 20);
        float c1, s1, c2, s2, c3, s3;
        __sincosf(0.5f * sp[q],      &s1, &c1);
        __sincosf(0.5f * sp[10 + q], &s2, &c2);
        __sincosf(0.5f * sp[20 + q], &s3, &c3);
        // rx: a=(c1,0), b=(0,-s1); ry: a2=(c2c1, s2s1), b2=(s2c1, -c2s1); rz below
        float a2r = c2 * c1, a2i = s2 * s1, b2r = s2 * c1, b2i = -c2 * s1;
        float a3r = fmaf(a2i,  s3, a2r * c3), a3i = fmaf(-a2r, s3, a2i * c3);
        float b3r = fmaf(-b2i, s3, b2r * c3), b3i = fmaf( b2r, s3, b2i * c3);
        float m;
        if (lane < 10)      m = 2.f * (a3r * b3r + a3i * b3i);            // X
        else if (lane < 20) m = 2.f * (a3r * b3i - a3i * b3r);            // Y
        else                m = (a3r * a3r + a3i * a3i) - (b3r * b3r + b3i * b3i); // Z
        float v = 0.f;
        for (int k = 0; k < 30; ++k) v = fmaf(Wout[k], W3[k * 30 + lane], v);
        vk = w3p[0] * fmaf(m, v, Wout[lane] * b3v[lane]);
    }
    vk = wred(vk, lane);
    if (lane == 0) ws_c[0] = vk;
}

// ---------------- main kernel ----------------

__global__ void __launch_bounds__(TPB) k_main(
    const float* __restrict__ x, const float* __restrict__ Wp,
    const float* __restrict__ bp_, const float* __restrict__ qb,
    const float* __restrict__ bpar, const float* __restrict__ cpar, const float* __restrict__ dtpar,
    const float* __restrict__ gb, const float* __restrict__ sp,
    const float* __restrict__ W1, const float* __restrict__ b1,
    const float* __restrict__ W2, const float* __restrict__ b2,
    const float* __restrict__ W3, const float* __restrict__ b3,
    const float* __restrict__ w1p, const float* __restrict__ w2p, const float* __restrict__ w3p,
    const float* __restrict__ Wout, const float* __restrict__ bout,
    float* __restrict__ ws, int B) {

    const int wv = threadIdx.x >> 6, lane = threadIdx.x & 63;

    __shared__ float vbr[32];

    if (wv == 4) {
        if (blockIdx.x == 0) {
            branch_gating(gb, b1, W2, b2, w1p, w2p, Wout, bout, vbr, ws + B, lane);
            if (gridDim.x == 1) branch_skip(sp, W3, b3, w3p, Wout, ws + B + 1, lane);
        } else if (blockIdx.x == 1) {
            branch_skip(sp, W3, b3, w3p, Wout, ws + B + 1, lane);
        }
        return;
    }

    const int b = blockIdx.x * 4 + wv;
    const int bb = (b < B) ? b : (B - 1);

    __shared__ float proj[4][80];
    __shared__ float ac1[4][10], as1[4][10], ac2[4][10], as2[4][10];
    __shared__ float gc[4][60], gs[4][60];          // [B1,CD1,E1, B2,CD2,E2]
    __shared__ float ub[4][80];                      // 10 qubits x 8 floats
    __shared__ float uraw[4][32], uu[4][32];

    // ---- projection (16-lane groups, 4 rows/pass) ----
    const int sub = lane & 15, grp = lane >> 4;
    float4 xv[4];
    {
        const float* xr = x + (size_t)bb * 256 + sub * 16;
#pragma unroll
        for (int j = 0; j < 4; ++j) xv[j] = reinterpret_cast<const float4*>(xr)[j];
    }
#pragma unroll 4
    for (int p = 0; p < 20; ++p) {
        const int row = p * 4 + grp;
        const float* wr = Wp + (size_t)row * 256 + sub * 16;
        float acc = 0.f;
#pragma unroll
        for (int j = 0; j < 4; ++j) {
            float4 w4 = reinterpret_cast<const float4*>(wr)[j];
            acc = fmaf(xv[j].x, w4.x, acc); acc = fmaf(xv[j].y, w4.y, acc);
            acc = fmaf(xv[j].z, w4.z, acc); acc = fmaf(xv[j].w, w4.w, acc);
        }
        acc += lx<1>(acc, lane); acc += lx<2>(acc, lane);
        acc += lx<4>(acc, lane); acc += lx<8>(acc, lane);
        if (sub == 0) proj[wv][row] = acc;
    }

    // ---- angle prep ----
    {
#define DO_ANGLE(IDX) { \
        const int idx = (IDX); \
        float ang = TWO_PI_F / (1.f + __expf(-(proj[wv][idx] + bp_[idx]))) + qb[idx]; \
        const int l = (idx >= 40) ? 1 : 0; \
        const int p = idx - 40 * l; \
        float s_, c_; \
        if (p < 10) { \
            __sincosf(0.5f * ang, &s_, &c_); \
            if (l == 0) { ac1[wv][p] = c_; as1[wv][p] = s_; } \
            else        { ac2[wv][p] = c_; as2[wv][p] = s_; } \
        } else if (p < 20) { \
            __sincosf(0.5f * ang, &s_, &c_); \
            gc[wv][l * 30 + p - 10] = c_; gs[wv][l * 30 + p - 10] = s_; \
        } else if (p < 30) { \
            __sincosf(0.5f * (ang + bpar[p - 20]), &s_, &c_); \
            gc[wv][l * 30 + 10 + p - 20] = c_; gs[wv][l * 30 + 10 + p - 20] = s_; \
        } else { \
            __sincosf(0.5f * ang, &s_, &c_); \
            gc[wv][l * 30 + 20 + p - 30] = c_; gs[wv][l * 30 + 20 + p - 30] = s_; \
        } }
        DO_ANGLE(lane)
        if (lane < 16) DO_ANGLE(64 + lane)
#undef DO_ANGLE

        if (lane < 30) {
            float ut = 0.f;
            for (int k = 0; k < 30; ++k) ut = fmaf(Wout[k], W1[k * 30 + lane], ut);
            uraw[wv][lane] = w1p[0] * ut;
        }
        if (lane < 10) {
            float ca = ac2[wv][lane], sa = as2[wv][lane];
            float cg2, sg2, cd2, sd2;
            __sincosf(0.5f * cpar[lane],  &sg2, &cg2);
            __sincosf(0.5f * dtpar[lane], &sd2, &cd2);
            float A = ca * cd2, Bv = sa * sd2;
            float C = -sa * cd2, D = -ca * sd2;
            float E = sa * cd2,  F = -ca * sd2;
            float G = ca * cd2,  H = -sa * sd2;
            float* U = &ub[wv][lane * 8];
            U[0] = cg2 * A + sg2 * Bv;  U[1] = cg2 * Bv - sg2 * A;
            U[2] = cg2 * C - sg2 * D;   U[3] = sg2 * C + cg2 * D;
            U[4] = cg2 * E + sg2 * F;   U[5] = cg2 * F - sg2 * E;
            U[6] = cg2 * G - sg2 * H;   U[7] = sg2 * G + cg2 * H;

            float cg, sgf, cd, sdf;
            __sincosf(cpar[lane],  &sgf, &cg);
            __sincosf(dtpar[lane], &sdf, &cd);
            float uX = uraw[wv][lane], uY = uraw[wv][10 + lane], uZ = uraw[wv][20 + lane];
            uu[wv][lane]      =  uX * cg + uY * cd * sgf + uZ * sdf * sgf;
            uu[wv][10 + lane] = -uX * sgf + uY * cd * cg + uZ * sdf * cg;
            uu[wv][20 + lane] = -uY * sdf + uZ * cd;
        }
    }

    // ---- product initial state ----
    float re[16], im[16];
    {
        const float* AC = ac1[wv]; const float* AS = as1[wv];
        float pl = ((lane >> 5) & 1) ? AS[0] : AC[0];
        pl *= ((lane >> 4) & 1) ? AS[1] : AC[1];
        pl *= ((lane >> 3) & 1) ? AS[2] : AC[2];
        pl *= ((lane >> 2) & 1) ? AS[3] : AC[3];
        pl *= ((lane >> 1) & 1) ? AS[4] : AC[4];
        pl *= ( lane       & 1) ? AS[5] : AC[5];
#pragma unroll
        for (int r = 0; r < 16; ++r) {
            float p = ((r >> 3) & 1) ? AS[6] : AC[6];
            p *= ((r >> 2) & 1) ? AS[7] : AC[7];
            p *= ((r >> 1) & 1) ? AS[8] : AC[8];
            p *= ( r       & 1) ? AS[9] : AC[9];
            re[r] = pl * p; im[r] = 0.f;
        }
    }

    // ---- fused circuit ----
    const float* GC = gc[wv]; const float* GS = gs[wv];

#define RING(base, YYf) \
    g_ring2(re, im, GC[(base)+1], GS[(base)+1], GC[(base)+9], GS[(base)+9], YYf, lane); \
    g_xy<2, 3, YYf>(re, im, GC[(base)+2], GS[(base)+2], lane); \
    g_xy<3, 4, YYf>(re, im, GC[(base)+3], GS[(base)+3], lane); \
    g_xy<4, 5, YYf>(re, im, GC[(base)+4], GS[(base)+4], lane); \
    g_xy<5, 6, YYf>(re, im, GC[(base)+5], GS[(base)+5], lane); \
    g_xy<6, 7, YYf>(re, im, GC[(base)+6], GS[(base)+6], lane); \
    g_xy<7, 8, YYf>(re, im, GC[(base)+7], GS[(base)+7], lane); \
    g_xy<8, 9, YYf>(re, im, GC[(base)+8], GS[(base)+8], lane); \
    g_xy<0, 1, YYf>(re, im, GC[(base)+0], GS[(base)+0], lane);

    RING(0, false)
    g_ry2_01(re, im, GC[10], GS[10], GC[11], GS[11], lane);
#define G_CD1(i) g_ry<i>(re, im, GC[10 + i], GS[10 + i], lane);
    G_CD1(2) G_CD1(3) G_CD1(4) G_CD1(5) G_CD1(6) G_CD1(7) G_CD1(8) G_CD1(9)
#undef G_CD1
    RING(20, true)
    g_u2_01(re, im, &ub[wv][0], &ub[wv][8], lane);
#define G_UB(i) g_u1<i>(re, im, &ub[wv][i * 8], lane);
    G_UB(2) G_UB(3) G_UB(4) G_UB(5) G_UB(6) G_UB(7) G_UB(8) G_UB(9)
#undef G_UB
    RING(30, false)
    g_ry2_01(re, im, GC[40], GS[40], GC[41], GS[41], lane);
#define G_CD2(i) g_ry<i>(re, im, GC[40 + i], GS[40 + i], lane);
    G_CD2(2) G_CD2(3) G_CD2(4) G_CD2(5) G_CD2(6) G_CD2(7) G_CD2(8) G_CD2(9)
#undef G_CD2
    RING(50, true)
#undef RING

    // ---- folded measurement ----
    float oacc = meas_fold(re, im, uu[wv], lane);
    oacc = wred(oacc, lane);
    if (lane == 0 && b < B) ws[b] = oacc;
}

__global__ void k_out(const float* __restrict__ ws, float* __restrict__ out, int B) {
    int i = blockIdx.x * blockDim.x + threadIdx.x;
    if (i < B) out[i] = ws[i] + ws[B] + ws[B + 1];
}

extern "C" void kernel_launch(void* const* d_in, const int* in_sizes, int n_in,
                              void* d_out, int out_size, void* d_ws, size_t ws_size,
                              hipStream_t stream) {
    const float* x         = (const float*)d_in[0];
    const float* W_proj    = (const float*)d_in[1];
    const float* b_proj    = (const float*)d_in[2];
    const float* qlcu_base = (const float*)d_in[3];
    const float* gate_base = (const float*)d_in[4];
    const float* skip_base = (const float*)d_in[5];
    const float* b_params  = (const float*)d_in[6];
    const float* c_params  = (const float*)d_in[7];
    const float* dt_params = (const float*)d_in[8];
    const float* W1    = (const float*)d_in[9];
    const float* b1    = (const float*)d_in[10];
    const float* W2    = (const float*)d_in[11];
    const float* b2    = (const float*)d_in[12];
    const float* W3    = (const float*)d_in[13];
    const float* b3    = (const float*)d_in[14];
    const float* w1    = (const float*)d_in[15];
    const float* w2    = (const float*)d_in[16];
    const float* w3    = (const float*)d_in[17];
    const float* W_out = (const float*)d_in[18];
    const float* b_out = (const float*)d_in[19];
    float* out = (float*)d_out;
    float* ws  = (float*)d_ws;

    const int B = in_sizes[0] / 256;   // FEATURE_DIM = 256
    const int nb = (B + 3) / 4;        // 512 for B=2048 (exact)

    hipLaunchKernelGGL(k_main, dim3(nb), dim3(TPB), 0, stream,
                       x, W_proj, b_proj, qlcu_base, b_params, c_params, dt_params,
                       gate_base, skip_base, W1, b1, W2, b2, W3, b3, w1, w2, w3,
                       W_out, b_out, ws, B);
    hipLaunchKernelGGL(k_out, dim3((B + 255) / 256), dim3(256), 0, stream, ws, out, B);
}